// Round 7
// baseline (492.089 us; speedup 1.0000x reference)
//
#include <hip/hip_runtime.h>
#include <hip/hip_bf16.h>

#define U_N 100000
#define I_N 50000
#define E_N 2000000
#define R_N 5
#define C_N (I_N*R_N)   // 250000 combos
#define NBLK_U 391      // ceil(100000/256); NBLK_U*256 = 100096
#define NBLK_E 7813     // ceil(2000000/256)
#define NBLK_C 1954     // ceil(250000/128)
#define NBUCK 782       // ceil(100000/128) user buckets
#define SUBB 8          // sub-buckets (one per XCD via blockIdx&7)
#define CAPB 512        // capacity per (bucket,sub)

typedef __hip_bfloat16 bf16_t;
typedef unsigned short u16;
typedef __attribute__((ext_vector_type(8))) short bf16x8;
typedef __attribute__((ext_vector_type(4))) float f32x4;

__device__ __forceinline__ float blo(unsigned u){ return __uint_as_float(u<<16); }
__device__ __forceinline__ float bhi(unsigned u){ return __uint_as_float(u & 0xffff0000u); }
__device__ __forceinline__ unsigned pkbf(float a, float b){
  __hip_bfloat162 t = __float22bfloat162_rn(float2{a,b});
  union { __hip_bfloat162 h; unsigned u; } cv; cv.h = t; return cv.u;
}
__device__ __forceinline__ u16 f2b(float v){
  union { __hip_bfloat16 h; u16 u; } cv; cv.h = __float2bfloat16(v); return cv.u;
}

// ---------------- CSR build: bucketed two-pass ----------------
__global__ __launch_bounds__(256) void k_zero_tails(int* tails){
  int i = blockIdx.x*256 + threadIdx.x;
  if(i < NBUCK*SUBB) tails[i] = 0;
}

__global__ __launch_bounds__(256) void k_binA(const int* __restrict__ rows, const int* __restrict__ cols,
                                              const int* __restrict__ rats,
                                              int* __restrict__ tails, int2* __restrict__ uc){
  int e = blockIdx.x*256 + threadIdx.x; if(e >= E_N) return;
  int u = cols[e];
  int c = rows[e]*5 + rats[e];
  int b = u >> 7;
  int sb = b*SUBB + (blockIdx.x & 7);
  int slot = atomicAdd(tails + sb, 1);
  if(slot < CAPB) uc[(size_t)sb*CAPB + slot] = make_int2(u, c);
}

__global__ __launch_bounds__(256) void k_binB1(const int* __restrict__ tails, const int2* __restrict__ uc,
                                               int* __restrict__ cnt){
  __shared__ int hist[128];
  int t = threadIdx.x, b = blockIdx.x;
  if(t < 128) hist[t] = 0;
  __syncthreads();
  for(int sub=0; sub<SUBB; ++sub){
    int sb = b*SUBB + sub;
    int n = tails[sb]; if(n > CAPB) n = CAPB;
    const int2* p = uc + (size_t)sb*CAPB;
    for(int j=t; j<n; j+=256) atomicAdd(&hist[p[j].x & 127], 1);
  }
  __syncthreads();
  if(t < 128) cnt[b*128 + t] = hist[t];
}

__global__ __launch_bounds__(256) void k_scanA(const int* __restrict__ cnt, int* __restrict__ start,
                                               int* __restrict__ bsum){
  __shared__ int s[256];
  int t = threadIdx.x, i = blockIdx.x*256 + t;
  int v = (i < U_N) ? cnt[i] : 0;
  s[t] = v; __syncthreads();
  for(int off=1; off<256; off<<=1){
    int x = (t>=off) ? s[t-off] : 0;
    __syncthreads();
    s[t] += x;
    __syncthreads();
  }
  start[i] = s[t] - v;
  if(t == 255) bsum[blockIdx.x] = s[255];
}

__global__ void k_scanB(int* bsum, int n){
  __shared__ int s[512];
  int t = threadIdx.x;
  int v = (t < n) ? bsum[t] : 0;
  s[t] = v; __syncthreads();
  for(int off=1; off<512; off<<=1){
    int x = (t>=off) ? s[t-off] : 0;
    __syncthreads();
    s[t] += x;
    __syncthreads();
  }
  if(t < n) bsum[t] = s[t] - v;
}

__global__ __launch_bounds__(256) void k_scanC(int* start, const int* __restrict__ bsum){
  int i = blockIdx.x*256 + threadIdx.x;
  start[i] += bsum[blockIdx.x];
}

__global__ __launch_bounds__(256) void k_binB2(const int* __restrict__ tails, const int2* __restrict__ uc,
                                               const int* __restrict__ start,
                                               int* __restrict__ u_s, int* __restrict__ c_s){
  __shared__ int fillb[128];
  __shared__ int startb[128];
  int t = threadIdx.x, b = blockIdx.x;
  if(t < 128){
    fillb[t] = 0;
    startb[t] = start[b*128 + t];
  }
  __syncthreads();
  for(int sub=0; sub<SUBB; ++sub){
    int sb = b*SUBB + sub;
    int n = tails[sb]; if(n > CAPB) n = CAPB;
    const int2* p = uc + (size_t)sb*CAPB;
    for(int j=t; j<n; j+=256){
      int2 e = p[j];
      int ul = e.x & 127;
      int off = atomicAdd(&fillb[ul], 1);
      int pos = startb[ul] + off;
      u_s[pos] = e.x;
      c_s[pos] = e.y;
    }
  }
}

// ---------------- tiny precompute ----------------
__global__ void k_ratpart(const float* __restrict__ rf, const float* __restrict__ w1,
                          const float* __restrict__ b1, float* __restrict__ out){
  int t = threadIdx.x; if(t >= R_N*64) return;
  int r = t>>6, d = t&63;
  float acc = b1[d];
  for(int k=0;k<64;k++) acc += rf[r*64 + k] * w1[(64+k)*64 + d];
  out[t] = acc;
}

// 6 transposed bf16 weight tables: dst[d*64+k] = bf16(src[(ko+k)*64+d])
__global__ __launch_bounds__(256) void k_prepw6(const float* __restrict__ w1, const float* __restrict__ a1,
                                                const float* __restrict__ w2, const float* __restrict__ a2,
                                                const float* __restrict__ ww,
                                                u16* w1t, u16* u1t, u16* w2t, u16* a1t, u16* a2t, u16* wwt){
  int idx = (blockIdx.x & 15)*256 + threadIdx.x;
  int sec = blockIdx.x >> 4;
  int d = idx >> 6, k = idx & 63;
  const float* src; u16* dst; int ko = 0;
  switch(sec){
    case 0: src=w1; dst=w1t; break;
    case 1: src=a1; dst=u1t; ko=64; break;
    case 2: src=w2; dst=w2t; break;
    case 3: src=a1; dst=a1t; break;
    case 4: src=a2; dst=a2t; break;
    default: src=ww; dst=wwt; break;
  }
  dst[idx] = f2b(src[(size_t)(ko+k)*64 + d]);
}

// ---------------- MFMA row-GEMM: out[n][64](bf16) = in[n][64](f32) @ W (+bias) ----------------
template<bool BIAS>
__global__ __launch_bounds__(256) void k_rowgemm(const float4* __restrict__ in,
                                                 const uint4* __restrict__ wt,
                                                 const float* __restrict__ bias,
                                                 uint4* __restrict__ outp, int n){
  __shared__ uint4 A_u4[2048];
  __shared__ uint4 W_u4[512];
  __shared__ float bsh[64];
  u16* A16 = (u16*)A_u4;
  const int tid = threadIdx.x;
  for(int cid = tid; cid < 512; cid += 256){
    int dd = cid >> 3, ch = cid & 7;
    W_u4[dd*8 + (ch ^ (dd&7))] = wt[cid];
  }
  if(BIAS && tid < 64) bsh[tid] = bias[tid];
  const int base = blockIdx.x*256;
  const int ch = tid & 7;
#pragma unroll
  for(int it=0; it<8; ++it){
    int s = it*32 + (tid>>3);
    int r = base + s;
    uint4 o = {0,0,0,0};
    if(r < n){
      const float4* p = in + (size_t)r*16 + ch*2;
      float4 v0 = p[0], v1 = p[1];
      o.x = pkbf(v0.x, v0.y); o.y = pkbf(v0.z, v0.w);
      o.z = pkbf(v1.x, v1.y); o.w = pkbf(v1.z, v1.w);
    }
    A_u4[s*8 + (ch ^ (s&7))] = o;
  }
  __syncthreads();
  const int l = tid & 63, w = tid >> 6;
  const int lr = l & 15, g = l >> 4;
  bf16x8 bfr[4][2];
#pragma unroll
  for(int nt=0; nt<4; ++nt)
#pragma unroll
    for(int kk=0; kk<2; ++kk){
      int d = nt*16 + lr;
      bfr[nt][kk] = *(const bf16x8*)&W_u4[d*8 + ((kk*4+g) ^ (d&7))];
    }
  float bv[4];
#pragma unroll
  for(int nt=0; nt<4; ++nt) bv[nt] = BIAS ? bsh[nt*16 + lr] : 0.f;
#pragma unroll
  for(int t=0; t<4; ++t){
    int s = w*64 + t*16 + lr;
    bf16x8 af0 = *(const bf16x8*)&A_u4[s*8 + ((0*4+g) ^ (s&7))];
    bf16x8 af1 = *(const bf16x8*)&A_u4[s*8 + ((1*4+g) ^ (s&7))];
    f32x4 acc[4];
#pragma unroll
    for(int nt=0; nt<4; ++nt){
      f32x4 c0 = { bv[nt], bv[nt], bv[nt], bv[nt] };
      c0 = __builtin_amdgcn_mfma_f32_16x16x32_bf16(af0, bfr[nt][0], c0, 0, 0, 0);
      c0 = __builtin_amdgcn_mfma_f32_16x16x32_bf16(af1, bfr[nt][1], c0, 0, 0, 0);
      acc[nt] = c0;
    }
#pragma unroll
    for(int nt=0; nt<4; ++nt){
      int d = nt*16 + lr;
#pragma unroll
      for(int reg=0; reg<4; ++reg){
        int srow = w*64 + t*16 + g*4 + reg;
        A16[srow*64 + ((d>>3)^(srow&7))*8 + (d&7)] = f2b(acc[nt][reg]);
      }
    }
  }
#pragma unroll
  for(int it=0; it<8; ++it){
    int s = w*64 + it*8 + (l>>3);
    int c2 = l & 7;
    int r = base + s;
    if(r < n) outp[(size_t)r*8 + c2] = A_u4[s*8 + (c2 ^ (s&7))];
  }
}

// ---------------- combo: h1=relu(itemp+ratp); x_ia=relu(h1@W2+b2); xa1=x_ia@A1top; Y=x_ia@WW ----------------
__global__ __launch_bounds__(256) void k_combo_mfma(const uint4* __restrict__ itemp,
                                                    const float4* __restrict__ ratp,
                                                    const uint4* __restrict__ w2t_g, const uint4* __restrict__ a1t_g,
                                                    const uint4* __restrict__ wwt_g,
                                                    const float* __restrict__ b2,
                                                    uint4* __restrict__ y_o, uint4* __restrict__ xa1_o){
  __shared__ uint4 A_u4[1024];    // 128 rows: h1 -> xa1
  __shared__ uint4 X_u4[1024];    // 128 rows: x_ia -> Y
  __shared__ uint4 W2_u4[512];
  __shared__ uint4 A1_u4[512];
  __shared__ uint4 WW_u4[512];
  __shared__ float4 rsh4[80];
  __shared__ float b2sh[64];
  u16* A16 = (u16*)A_u4;
  u16* X16 = (u16*)X_u4;
  const int tid = threadIdx.x;
  for(int cid = tid; cid < 512; cid += 256){
    int dd = cid >> 3, ch = cid & 7;
    W2_u4[dd*8 + (ch ^ (dd&7))] = w2t_g[cid];
    A1_u4[dd*8 + (ch ^ (dd&7))] = a1t_g[cid];
    WW_u4[dd*8 + (ch ^ (dd&7))] = wwt_g[cid];
  }
  if(tid < 80) rsh4[tid] = ratp[tid];
  if(tid < 64) b2sh[tid] = b2[tid];
  __syncthreads();

  const int base = blockIdx.x*128;
  const int ch = tid & 7;
#pragma unroll
  for(int it=0; it<4; ++it){
    int s = it*32 + (tid>>3);
    int cidx = base + s;
    uint4 o = {0,0,0,0};
    if(cidx < C_N){
      int i = cidx/5, r = cidx - i*5;
      uint4 iv = itemp[(size_t)i*8 + ch];
      float4 r0 = rsh4[r*16 + ch*2], r1 = rsh4[r*16 + ch*2 + 1];
      o.x = pkbf(fmaxf(blo(iv.x)+r0.x,0.f), fmaxf(bhi(iv.x)+r0.y,0.f));
      o.y = pkbf(fmaxf(blo(iv.y)+r0.z,0.f), fmaxf(bhi(iv.y)+r0.w,0.f));
      o.z = pkbf(fmaxf(blo(iv.z)+r1.x,0.f), fmaxf(bhi(iv.z)+r1.y,0.f));
      o.w = pkbf(fmaxf(blo(iv.w)+r1.z,0.f), fmaxf(bhi(iv.w)+r1.w,0.f));
    }
    A_u4[s*8 + (ch ^ (s&7))] = o;
  }
  __syncthreads();

  const int l = tid & 63, w = tid >> 6;
  const int lr = l & 15, g = l >> 4;
  bf16x8 w2f[4][2], a1f[4][2], wwf[4][2];
#pragma unroll
  for(int nt=0; nt<4; ++nt)
#pragma unroll
    for(int kk=0; kk<2; ++kk){
      int d = nt*16 + lr;
      w2f[nt][kk] = *(const bf16x8*)&W2_u4[d*8 + ((kk*4+g) ^ (d&7))];
      a1f[nt][kk] = *(const bf16x8*)&A1_u4[d*8 + ((kk*4+g) ^ (d&7))];
      wwf[nt][kk] = *(const bf16x8*)&WW_u4[d*8 + ((kk*4+g) ^ (d&7))];
    }
  float b2v[4];
#pragma unroll
  for(int nt=0; nt<4; ++nt) b2v[nt] = b2sh[nt*16 + lr];

#pragma unroll
  for(int t=0; t<2; ++t){
    int s = w*32 + t*16 + lr;
    bf16x8 af0 = *(const bf16x8*)&A_u4[s*8 + ((0*4+g) ^ (s&7))];
    bf16x8 af1 = *(const bf16x8*)&A_u4[s*8 + ((1*4+g) ^ (s&7))];
    // GEMM1: x_ia
#pragma unroll
    for(int nt=0; nt<4; ++nt){
      f32x4 c0 = { b2v[nt], b2v[nt], b2v[nt], b2v[nt] };
      c0 = __builtin_amdgcn_mfma_f32_16x16x32_bf16(af0, w2f[nt][0], c0, 0, 0, 0);
      c0 = __builtin_amdgcn_mfma_f32_16x16x32_bf16(af1, w2f[nt][1], c0, 0, 0, 0);
      int d = nt*16 + lr;
#pragma unroll
      for(int reg=0; reg<4; ++reg){
        int srow = w*32 + t*16 + g*4 + reg;
        X16[srow*64 + ((d>>3)^(srow&7))*8 + (d&7)] = f2b(fmaxf(c0[reg], 0.f));
      }
    }
    bf16x8 xf0 = *(const bf16x8*)&X_u4[s*8 + ((0*4+g) ^ (s&7))];
    bf16x8 xf1 = *(const bf16x8*)&X_u4[s*8 + ((1*4+g) ^ (s&7))];
    // GEMM2: xa1 -> A16 rows (h1 dead)
#pragma unroll
    for(int nt=0; nt<4; ++nt){
      f32x4 c0 = { 0.f, 0.f, 0.f, 0.f };
      c0 = __builtin_amdgcn_mfma_f32_16x16x32_bf16(xf0, a1f[nt][0], c0, 0, 0, 0);
      c0 = __builtin_amdgcn_mfma_f32_16x16x32_bf16(xf1, a1f[nt][1], c0, 0, 0, 0);
      int d = nt*16 + lr;
#pragma unroll
      for(int reg=0; reg<4; ++reg){
        int srow = w*32 + t*16 + g*4 + reg;
        A16[srow*64 + ((d>>3)^(srow&7))*8 + (d&7)] = f2b(c0[reg]);
      }
    }
    // GEMM3: Y = x_ia @ WW -> X16 rows (x_ia consumed)
#pragma unroll
    for(int nt=0; nt<4; ++nt){
      f32x4 c0 = { 0.f, 0.f, 0.f, 0.f };
      c0 = __builtin_amdgcn_mfma_f32_16x16x32_bf16(xf0, wwf[nt][0], c0, 0, 0, 0);
      c0 = __builtin_amdgcn_mfma_f32_16x16x32_bf16(xf1, wwf[nt][1], c0, 0, 0, 0);
      int d = nt*16 + lr;
#pragma unroll
      for(int reg=0; reg<4; ++reg){
        int srow = w*32 + t*16 + g*4 + reg;
        X16[srow*64 + ((d>>3)^(srow&7))*8 + (d&7)] = f2b(c0[reg]);
      }
    }
  }
#pragma unroll
  for(int it=0; it<4; ++it){
    int s = w*32 + it*8 + (l>>3);
    int c2 = l & 7;
    int r = base + s;
    if(r < C_N){
      y_o  [(size_t)r*8 + c2] = X_u4[s*8 + (c2 ^ (s&7))];
      xa1_o[(size_t)r*8 + c2] = A_u4[s*8 + (c2 ^ (s&7))];
    }
  }
}

// ---------------- MFMA edge-logit kernel ----------------
__global__ __launch_bounds__(256) void k_edge_mfma(const int* __restrict__ u_s, const int* __restrict__ c_s,
                                                   const uint4* __restrict__ xa1p, const uint4* __restrict__ userp,
                                                   const uint4* __restrict__ a2t_g,
                                                   const float* __restrict__ a2b,
                                                   const float* __restrict__ a3w, const float* __restrict__ a3b,
                                                   float* __restrict__ wlog){
  __shared__ uint4 A_u4[2048];
  __shared__ uint4 W_u4[512];
  __shared__ float b2s[64];
  __shared__ float a3s[64];
  const int tid = threadIdx.x;
  for(int cid = tid; cid < 512; cid += 256){
    int d = cid >> 3, ch = cid & 7;
    W_u4[d*8 + (ch ^ (d&7))] = a2t_g[cid];
  }
  if(tid < 64){ b2s[tid] = a2b[tid]; a3s[tid] = a3w[tid]; }
  const int base = blockIdx.x*256;
  const int ch = tid & 7;
#pragma unroll
  for(int it=0; it<8; ++it){
    int s = it*32 + (tid>>3);
    int e = base + s;
    uint4 xv = {0,0,0,0}, uv = {0,0,0,0};
    if(e < E_N){
      int c = c_s[e], u = u_s[e];
      xv = xa1p[(size_t)c*8 + ch];
      uv = userp[(size_t)u*8 + ch];
    }
    uint4 o;
    o.x = pkbf(fmaxf(blo(xv.x)+blo(uv.x),0.f), fmaxf(bhi(xv.x)+bhi(uv.x),0.f));
    o.y = pkbf(fmaxf(blo(xv.y)+blo(uv.y),0.f), fmaxf(bhi(xv.y)+bhi(uv.y),0.f));
    o.z = pkbf(fmaxf(blo(xv.z)+blo(uv.z),0.f), fmaxf(bhi(xv.z)+bhi(uv.z),0.f));
    o.w = pkbf(fmaxf(blo(xv.w)+blo(uv.w),0.f), fmaxf(bhi(xv.w)+bhi(uv.w),0.f));
    A_u4[s*8 + (ch ^ (s&7))] = o;
  }
  __syncthreads();
  const int l = tid & 63, w = tid >> 6;
  const int lr = l & 15;
  const int g  = l >> 4;
  bf16x8 bf[4][2];
#pragma unroll
  for(int nt=0; nt<4; ++nt)
#pragma unroll
    for(int kk=0; kk<2; ++kk){
      int d = nt*16 + lr;
      bf[nt][kk] = *(const bf16x8*)&W_u4[d*8 + ((kk*4 + g) ^ (d&7))];
    }
  float b2v[4], a3v[4];
#pragma unroll
  for(int nt=0; nt<4; ++nt){ b2v[nt] = b2s[nt*16 + lr]; a3v[nt] = a3s[nt*16 + lr]; }
  const float a3b0 = a3b[0];
#pragma unroll
  for(int t=0; t<4; ++t){
    int s = w*64 + t*16 + lr;
    bf16x8 af0 = *(const bf16x8*)&A_u4[s*8 + ((0*4 + g) ^ (s&7))];
    bf16x8 af1 = *(const bf16x8*)&A_u4[s*8 + ((1*4 + g) ^ (s&7))];
    f32x4 acc[4];
#pragma unroll
    for(int nt=0; nt<4; ++nt){
      f32x4 c0 = { b2v[nt], b2v[nt], b2v[nt], b2v[nt] };
      c0 = __builtin_amdgcn_mfma_f32_16x16x32_bf16(af0, bf[nt][0], c0, 0, 0, 0);
      c0 = __builtin_amdgcn_mfma_f32_16x16x32_bf16(af1, bf[nt][1], c0, 0, 0, 0);
      acc[nt] = c0;
    }
    float s0=0.f, s1=0.f, s2=0.f, s3=0.f;
#pragma unroll
    for(int nt=0; nt<4; ++nt){
      s0 += fmaxf(acc[nt][0], 0.f) * a3v[nt];
      s1 += fmaxf(acc[nt][1], 0.f) * a3v[nt];
      s2 += fmaxf(acc[nt][2], 0.f) * a3v[nt];
      s3 += fmaxf(acc[nt][3], 0.f) * a3v[nt];
    }
#pragma unroll
    for(int mask=1; mask<16; mask<<=1){
      s0 += __shfl_xor(s0, mask);
      s1 += __shfl_xor(s1, mask);
      s2 += __shfl_xor(s2, mask);
      s3 += __shfl_xor(s3, mask);
    }
    if(lr == 0){
      int e0 = base + w*64 + t*16 + g*4;
      if(e0+0 < E_N) wlog[e0+0] = s0 + a3b0;
      if(e0+1 < E_N) wlog[e0+1] = s1 + a3b0;
      if(e0+2 < E_N) wlog[e0+2] = s2 + a3b0;
      if(e0+3 < E_N) wlog[e0+3] = s3 + a3b0;
    }
  }
}

// ---------------- softmax normalize: pval[e] = bf16(exp(wlog-m)/sum) ----------------
__global__ __launch_bounds__(256) void k_smax(const int* __restrict__ start,
                                              const float* __restrict__ wlog,
                                              u16* __restrict__ pval){
  int w = threadIdx.x >> 6, lane = threadIdx.x & 63;
  int u = blockIdx.x*4 + w;
  int s0 = start[u], n = start[u+1] - s0;
  int nq = (n + 63) >> 6;
  float tq[4];
  float m = -1e30f;
  for(int q=0; q<nq; ++q){
    int j = q*64 + lane;
    float t = (j<n) ? wlog[s0+j] : -1e30f;
    if(q<4) tq[q] = t;
    m = fmaxf(m, t);
  }
#pragma unroll
  for(int off=32; off>=1; off>>=1) m = fmaxf(m, __shfl_xor(m, off));
  float ssum = 0.f;
  for(int q=0; q<nq; ++q){
    int j = q*64 + lane;
    float t = (q<4) ? tq[q] : ((j<n) ? wlog[s0+j] : -1e30f);
    float e = (j<n) ? __expf(t - m) : 0.f;
    if(q<4) tq[q] = e;
    ssum += e;
  }
#pragma unroll
  for(int off=32; off>=1; off>>=1) ssum += __shfl_xor(ssum, off);
  float inv = (n>0) ? (1.f/ssum) : 0.f;
  for(int q=0; q<nq; ++q){
    int j = q*64 + lane;
    float e = (q<4) ? tq[q] : ((j<n) ? __expf(wlog[s0+j] - m) : 0.f);
    if(j<n) pval[s0+j] = f2b(e * inv);
  }
}

// ---------------- MFMA aggregate: out[16 users][64] = P-mask @ Y-rows + w_b ----------------
__global__ __launch_bounds__(256) void k_agg(const int* __restrict__ start,
                                             const int* __restrict__ u_s, const int* __restrict__ c_s,
                                             const u16* __restrict__ pval,
                                             const u16* __restrict__ Y,
                                             const float* __restrict__ wb,
                                             float* __restrict__ out){
  int w = threadIdx.x >> 6, l = threadIdx.x & 63;
  int lr = l & 15, g = l >> 4;
  int base = (blockIdx.x*4 + w) * 16;
  if(base >= U_N) return;
  int s0g = start[base];
  int s1g = start[base+16];          // start[] valid to 100096; start[i>=U_N]==E_N
  int myu = base + lr;               // A-row m = lr corresponds to this user
  float wbv[4];
#pragma unroll
  for(int nt=0; nt<4; ++nt) wbv[nt] = wb[nt*16 + lr];
  f32x4 acc[4];
#pragma unroll
  for(int nt=0; nt<4; ++nt) acc[nt] = f32x4{ wbv[nt], wbv[nt], wbv[nt], wbv[nt] };

  int sA = s0g & ~31;                // 32-aligned window; extra edges self-mask via u-compare
  int nch = (s1g - sA + 31) >> 5;
  for(int ch=0; ch<nch; ++ch){
    int e0 = sA + ch*32;             // 32-aligned; e0+31 <= E_N-1 (E_N % 32 == 0)
    int kb = g*8;
    bf16x8 pv = *(const bf16x8*)(pval + e0 + kb);
    int4 u0 = *(const int4*)(u_s + e0 + kb);
    int4 u1 = *(const int4*)(u_s + e0 + kb + 4);
    int4 cA = *(const int4*)(c_s + e0 + kb);
    int4 cB = *(const int4*)(c_s + e0 + kb + 4);
    bf16x8 af;
    af[0] = (u0.x == myu) ? pv[0] : (short)0;
    af[1] = (u0.y == myu) ? pv[1] : (short)0;
    af[2] = (u0.z == myu) ? pv[2] : (short)0;
    af[3] = (u0.w == myu) ? pv[3] : (short)0;
    af[4] = (u1.x == myu) ? pv[4] : (short)0;
    af[5] = (u1.y == myu) ? pv[5] : (short)0;
    af[6] = (u1.z == myu) ? pv[6] : (short)0;
    af[7] = (u1.w == myu) ? pv[7] : (short)0;
    int cj[8] = {cA.x, cA.y, cA.z, cA.w, cB.x, cB.y, cB.z, cB.w};
    bf16x8 b0, b1, b2, b3;
#pragma unroll
    for(int j=0; j<8; ++j){
      const u16* yr = Y + (size_t)cj[j]*64 + lr;
      b0[j] = (short)yr[0];
      b1[j] = (short)yr[16];
      b2[j] = (short)yr[32];
      b3[j] = (short)yr[48];
    }
    acc[0] = __builtin_amdgcn_mfma_f32_16x16x32_bf16(af, b0, acc[0], 0, 0, 0);
    acc[1] = __builtin_amdgcn_mfma_f32_16x16x32_bf16(af, b1, acc[1], 0, 0, 0);
    acc[2] = __builtin_amdgcn_mfma_f32_16x16x32_bf16(af, b2, acc[2], 0, 0, 0);
    acc[3] = __builtin_amdgcn_mfma_f32_16x16x32_bf16(af, b3, acc[3], 0, 0, 0);
  }
  // D[row = g*4+reg][col = lr] per nt -> out[base+row][nt*16+lr]
#pragma unroll
  for(int nt=0; nt<4; ++nt){
#pragma unroll
    for(int reg=0; reg<4; ++reg){
      int u = base + g*4 + reg;
      out[(size_t)u*64 + nt*16 + lr] = acc[nt][reg];
    }
  }
}

extern "C" void kernel_launch(void* const* d_in, const int* in_sizes, int n_in,
                              void* d_out, int out_size, void* d_ws, size_t ws_size,
                              hipStream_t stream){
  (void)in_sizes; (void)n_in; (void)out_size; (void)ws_size;
  const float4* user_feat  = (const float4*)d_in[0];
  const float4* item_feat  = (const float4*)d_in[1];
  const float*  rating_feat= (const float*)d_in[2];
  const int*    rows       = (const int*)d_in[3];
  const int*    cols       = (const int*)d_in[4];
  const int*    rats       = (const int*)d_in[5];
  const float* gv_w1 = (const float*)d_in[6];
  const float* gv_b1 = (const float*)d_in[7];
  const float* gv_w2 = (const float*)d_in[8];
  const float* gv_b2 = (const float*)d_in[9];
  const float* att_w1= (const float*)d_in[10];
  const float* att_b1= (const float*)d_in[11];
  const float* att_w2= (const float*)d_in[12];
  const float* att_b2= (const float*)d_in[13];
  const float* att_w3= (const float*)d_in[14];
  const float* att_b3= (const float*)d_in[15];
  const float* w_w   = (const float*)d_in[16];
  const float* w_b   = (const float*)d_in[17];
  float* out = (float*)d_out;

  char* ws = (char*)d_ws; size_t off = 0;
  auto take = [&](size_t b)->char*{ char* p = ws + off; off = (off + b + 255) & ~(size_t)255; return p; };
  bf16_t* item_part  = (bf16_t*)take((size_t)I_N*64*2);       // 6.4 MB
  bf16_t* user_part  = (bf16_t*)take((size_t)U_N*64*2);       // 12.8 MB
  float*  rating_part= (float*) take((size_t)R_N*64*4);
  bf16_t* y_t        = (bf16_t*)take((size_t)C_N*64*2);       // 32 MB  (Y = x_ia @ w_w)
  bf16_t* xa1_t      = (bf16_t*)take((size_t)C_N*64*2);       // 32 MB
  float*  wlog_s     = (float*) take((size_t)E_N*4);          // 8 MB
  int*    c_s        = (int*)   take((size_t)E_N*4);          // 8 MB
  int*    u_s        = (int*)   take((size_t)E_N*4);          // 8 MB
  u16*    pval       = (u16*)   take((size_t)E_N*2);          // 4 MB
  int2*   uc         = (int2*)  take((size_t)NBUCK*SUBB*CAPB*8); // 25.6 MB
  int*    tails      = (int*)   take((size_t)NBUCK*SUBB*4);
  int*    cnt        = (int*)   take((size_t)(NBLK_U*256)*4);
  int*    start      = (int*)   take((size_t)(NBLK_U*256)*4);
  int*    bsum       = (int*)   take((size_t)512*4);
  u16*    w1t        = (u16*)   take((size_t)4096*2);
  u16*    u1t        = (u16*)   take((size_t)4096*2);
  u16*    w2t        = (u16*)   take((size_t)4096*2);
  u16*    a1t        = (u16*)   take((size_t)4096*2);
  u16*    a2t        = (u16*)   take((size_t)4096*2);
  u16*    wwt        = (u16*)   take((size_t)4096*2);

  // CSR build (bucketed)
  k_zero_tails<<<(NBUCK*SUBB+255)/256, 256, 0, stream>>>(tails);
  k_binA <<<NBLK_E, 256, 0, stream>>>(rows, cols, rats, tails, uc);
  k_binB1<<<NBUCK, 256, 0, stream>>>(tails, uc, cnt);
  k_scanA<<<NBLK_U, 256, 0, stream>>>(cnt, start, bsum);
  k_scanB<<<1, 512, 0, stream>>>(bsum, NBLK_U);
  k_scanC<<<NBLK_U, 256, 0, stream>>>(start, bsum);
  k_binB2<<<NBUCK, 256, 0, stream>>>(tails, uc, start, u_s, c_s);
  // weights + tiny GEMV
  k_ratpart <<<1, 320, 0, stream>>>(rating_feat, gv_w1, gv_b1, rating_part);
  k_prepw6  <<<96, 256, 0, stream>>>(gv_w1, att_w1, gv_w2, att_w2, w_w, w1t, u1t, w2t, a1t, a2t, wwt);
  // dense precompute (MFMA)
  k_rowgemm<false><<<(I_N+255)/256, 256, 0, stream>>>(item_feat, (const uint4*)w1t, nullptr,
                                                      (uint4*)item_part, I_N);
  k_rowgemm<true> <<<NBLK_U, 256, 0, stream>>>(user_feat, (const uint4*)u1t, att_b1,
                                               (uint4*)user_part, U_N);
  k_combo_mfma<<<NBLK_C, 256, 0, stream>>>((const uint4*)item_part, (const float4*)rating_part,
                                           (const uint4*)w2t, (const uint4*)a1t, (const uint4*)wwt, gv_b2,
                                           (uint4*)y_t, (uint4*)xa1_t);
  // per-edge logits (MFMA)
  k_edge_mfma<<<NBLK_E, 256, 0, stream>>>(u_s, c_s, (const uint4*)xa1_t, (const uint4*)user_part,
                                          (const uint4*)a2t, att_b2, att_w3, att_b3, wlog_s);
  // softmax normalize + MFMA aggregate (out = P @ Y + w_b)
  k_smax <<<U_N/4, 256, 0, stream>>>(start, wlog_s, pval);
  k_agg  <<<(U_N/64)+1, 256, 0, stream>>>(start, u_s, c_s, pval, (const u16*)y_t, w_b, out);
}

// Round 8
// 490.854 us; speedup vs baseline: 1.0025x; 1.0025x over previous
//
#include <hip/hip_runtime.h>
#include <hip/hip_bf16.h>

#define U_N 100000
#define I_N 50000
#define E_N 2000000
#define R_N 5
#define C_N (I_N*R_N)   // 250000 combos
#define NBLK_U 391      // ceil(100000/256); NBLK_U*256 = 100096
#define NBLK_E 7813     // ceil(2000000/256)
#define NBLK_C 1954     // ceil(250000/128)
#define NBUCK 782       // ceil(100000/128) user buckets
#define SUBB 8          // sub-buckets: one per XCD (real XCC_ID)
#define CAPB 1024       // capacity per (bucket,sub); mean fill 320

typedef __hip_bfloat16 bf16_t;
typedef unsigned short u16;
typedef __attribute__((ext_vector_type(8))) short bf16x8;
typedef __attribute__((ext_vector_type(4))) float f32x4;

__device__ __forceinline__ float blo(unsigned u){ return __uint_as_float(u<<16); }
__device__ __forceinline__ float bhi(unsigned u){ return __uint_as_float(u & 0xffff0000u); }
__device__ __forceinline__ unsigned pkbf(float a, float b){
  __hip_bfloat162 t = __float22bfloat162_rn(float2{a,b});
  union { __hip_bfloat162 h; unsigned u; } cv; cv.h = t; return cv.u;
}
__device__ __forceinline__ u16 f2b(float v){
  union { __hip_bfloat16 h; u16 u; } cv; cv.h = __float2bfloat16(v); return cv.u;
}

// ---------------- CSR build: bucketed two-pass (XCD-local append streams) ----------------
__global__ __launch_bounds__(256) void k_zero_tails(int* tails){
  int i = blockIdx.x*256 + threadIdx.x;
  if(i < NBUCK*SUBB) tails[i] = 0;
}

// pass A: append packed (u&127)<<18 | c to bucket (u>>7), sub-bucket = REAL XCD id.
// All writers of one (bucket,sub) stream live on one XCD -> its L2 keeps the open
// line until full (64B line = 16 packed entries) -> ~1x write amplification.
__global__ __launch_bounds__(256) void k_binA(const int* __restrict__ rows, const int* __restrict__ cols,
                                              const int* __restrict__ rats,
                                              int* __restrict__ tails, unsigned* __restrict__ uc){
  int e = blockIdx.x*256 + threadIdx.x; if(e >= E_N) return;
  unsigned xcc;
  asm volatile("s_getreg_b32 %0, hwreg(HW_REG_XCC_ID, 0, 4)" : "=s"(xcc));
  int u = cols[e];
  int c = rows[e]*5 + rats[e];
  int b = u >> 7;
  int sb = b*SUBB + (int)(xcc & 7u);
  int slot = atomicAdd(tails + sb, 1);
  if(slot < CAPB) uc[(size_t)sb*CAPB + slot] = ((unsigned)(u & 127) << 18) | (unsigned)c;
}

// pass B1: per-bucket LDS histogram -> cnt
__global__ __launch_bounds__(256) void k_binB1(const int* __restrict__ tails, const unsigned* __restrict__ uc,
                                               int* __restrict__ cnt){
  __shared__ int hist[128];
  int t = threadIdx.x, b = blockIdx.x;
  if(t < 128) hist[t] = 0;
  __syncthreads();
  for(int sub=0; sub<SUBB; ++sub){
    int sb = b*SUBB + sub;
    int n = tails[sb]; if(n > CAPB) n = CAPB;
    const unsigned* p = uc + (size_t)sb*CAPB;
    for(int j=t; j<n; j+=256) atomicAdd(&hist[(p[j]>>18) & 127], 1);
  }
  __syncthreads();
  if(t < 128) cnt[b*128 + t] = hist[t];
}

__global__ __launch_bounds__(256) void k_scanA(const int* __restrict__ cnt, int* __restrict__ start,
                                               int* __restrict__ bsum){
  __shared__ int s[256];
  int t = threadIdx.x, i = blockIdx.x*256 + t;
  int v = (i < U_N) ? cnt[i] : 0;
  s[t] = v; __syncthreads();
  for(int off=1; off<256; off<<=1){
    int x = (t>=off) ? s[t-off] : 0;
    __syncthreads();
    s[t] += x;
    __syncthreads();
  }
  start[i] = s[t] - v;
  if(t == 255) bsum[blockIdx.x] = s[255];
}

__global__ void k_scanB(int* bsum, int n){
  __shared__ int s[512];
  int t = threadIdx.x;
  int v = (t < n) ? bsum[t] : 0;
  s[t] = v; __syncthreads();
  for(int off=1; off<512; off<<=1){
    int x = (t>=off) ? s[t-off] : 0;
    __syncthreads();
    s[t] += x;
    __syncthreads();
  }
  if(t < n) bsum[t] = s[t] - v;
}

__global__ __launch_bounds__(256) void k_scanC(int* start, const int* __restrict__ bsum){
  int i = blockIdx.x*256 + threadIdx.x;
  start[i] += bsum[blockIdx.x];
}

// pass B2: per-bucket placement into L2-resident final windows
__global__ __launch_bounds__(256) void k_binB2(const int* __restrict__ tails, const unsigned* __restrict__ uc,
                                               const int* __restrict__ start,
                                               int* __restrict__ u_s, int* __restrict__ c_s){
  __shared__ int fillb[128];
  __shared__ int startb[128];
  int t = threadIdx.x, b = blockIdx.x;
  if(t < 128){
    fillb[t] = 0;
    startb[t] = start[b*128 + t];
  }
  __syncthreads();
  for(int sub=0; sub<SUBB; ++sub){
    int sb = b*SUBB + sub;
    int n = tails[sb]; if(n > CAPB) n = CAPB;
    const unsigned* p = uc + (size_t)sb*CAPB;
    for(int j=t; j<n; j+=256){
      unsigned v = p[j];
      int ul = (int)(v >> 18);
      int c  = (int)(v & 0x3FFFFu);
      int off = atomicAdd(&fillb[ul], 1);
      int pos = startb[ul] + off;
      u_s[pos] = (b << 7) | ul;
      c_s[pos] = c;
    }
  }
}

// ---------------- tiny precompute ----------------
__global__ void k_ratpart(const float* __restrict__ rf, const float* __restrict__ w1,
                          const float* __restrict__ b1, float* __restrict__ out){
  int t = threadIdx.x; if(t >= R_N*64) return;
  int r = t>>6, d = t&63;
  float acc = b1[d];
  for(int k=0;k<64;k++) acc += rf[r*64 + k] * w1[(64+k)*64 + d];
  out[t] = acc;
}

__global__ __launch_bounds__(256) void k_prepw6(const float* __restrict__ w1, const float* __restrict__ a1,
                                                const float* __restrict__ w2, const float* __restrict__ a2,
                                                const float* __restrict__ ww,
                                                u16* w1t, u16* u1t, u16* w2t, u16* a1t, u16* a2t, u16* wwt){
  int idx = (blockIdx.x & 15)*256 + threadIdx.x;
  int sec = blockIdx.x >> 4;
  int d = idx >> 6, k = idx & 63;
  const float* src; u16* dst; int ko = 0;
  switch(sec){
    case 0: src=w1; dst=w1t; break;
    case 1: src=a1; dst=u1t; ko=64; break;
    case 2: src=w2; dst=w2t; break;
    case 3: src=a1; dst=a1t; break;
    case 4: src=a2; dst=a2t; break;
    default: src=ww; dst=wwt; break;
  }
  dst[idx] = f2b(src[(size_t)(ko+k)*64 + d]);
}

// ---------------- MFMA row-GEMM: out[n][64](bf16) = in[n][64](f32) @ W (+bias) ----------------
template<bool BIAS>
__global__ __launch_bounds__(256) void k_rowgemm(const float4* __restrict__ in,
                                                 const uint4* __restrict__ wt,
                                                 const float* __restrict__ bias,
                                                 uint4* __restrict__ outp, int n){
  __shared__ uint4 A_u4[2048];
  __shared__ uint4 W_u4[512];
  __shared__ float bsh[64];
  u16* A16 = (u16*)A_u4;
  const int tid = threadIdx.x;
  for(int cid = tid; cid < 512; cid += 256){
    int dd = cid >> 3, ch = cid & 7;
    W_u4[dd*8 + (ch ^ (dd&7))] = wt[cid];
  }
  if(BIAS && tid < 64) bsh[tid] = bias[tid];
  const int base = blockIdx.x*256;
  const int ch = tid & 7;
#pragma unroll
  for(int it=0; it<8; ++it){
    int s = it*32 + (tid>>3);
    int r = base + s;
    uint4 o = {0,0,0,0};
    if(r < n){
      const float4* p = in + (size_t)r*16 + ch*2;
      float4 v0 = p[0], v1 = p[1];
      o.x = pkbf(v0.x, v0.y); o.y = pkbf(v0.z, v0.w);
      o.z = pkbf(v1.x, v1.y); o.w = pkbf(v1.z, v1.w);
    }
    A_u4[s*8 + (ch ^ (s&7))] = o;
  }
  __syncthreads();
  const int l = tid & 63, w = tid >> 6;
  const int lr = l & 15, g = l >> 4;
  bf16x8 bfr[4][2];
#pragma unroll
  for(int nt=0; nt<4; ++nt)
#pragma unroll
    for(int kk=0; kk<2; ++kk){
      int d = nt*16 + lr;
      bfr[nt][kk] = *(const bf16x8*)&W_u4[d*8 + ((kk*4+g) ^ (d&7))];
    }
  float bv[4];
#pragma unroll
  for(int nt=0; nt<4; ++nt) bv[nt] = BIAS ? bsh[nt*16 + lr] : 0.f;
#pragma unroll
  for(int t=0; t<4; ++t){
    int s = w*64 + t*16 + lr;
    bf16x8 af0 = *(const bf16x8*)&A_u4[s*8 + ((0*4+g) ^ (s&7))];
    bf16x8 af1 = *(const bf16x8*)&A_u4[s*8 + ((1*4+g) ^ (s&7))];
    f32x4 acc[4];
#pragma unroll
    for(int nt=0; nt<4; ++nt){
      f32x4 c0 = { bv[nt], bv[nt], bv[nt], bv[nt] };
      c0 = __builtin_amdgcn_mfma_f32_16x16x32_bf16(af0, bfr[nt][0], c0, 0, 0, 0);
      c0 = __builtin_amdgcn_mfma_f32_16x16x32_bf16(af1, bfr[nt][1], c0, 0, 0, 0);
      acc[nt] = c0;
    }
#pragma unroll
    for(int nt=0; nt<4; ++nt){
      int d = nt*16 + lr;
#pragma unroll
      for(int reg=0; reg<4; ++reg){
        int srow = w*64 + t*16 + g*4 + reg;
        A16[srow*64 + ((d>>3)^(srow&7))*8 + (d&7)] = f2b(acc[nt][reg]);
      }
    }
  }
#pragma unroll
  for(int it=0; it<8; ++it){
    int s = w*64 + it*8 + (l>>3);
    int c2 = l & 7;
    int r = base + s;
    if(r < n) outp[(size_t)r*8 + c2] = A_u4[s*8 + (c2 ^ (s&7))];
  }
}

// ---------------- combo: h1=relu(itemp+ratp); x_ia=relu(h1@W2+b2); xa1=x_ia@A1top; Y=x_ia@WW ----------------
__global__ __launch_bounds__(256) void k_combo_mfma(const uint4* __restrict__ itemp,
                                                    const float4* __restrict__ ratp,
                                                    const uint4* __restrict__ w2t_g, const uint4* __restrict__ a1t_g,
                                                    const uint4* __restrict__ wwt_g,
                                                    const float* __restrict__ b2,
                                                    uint4* __restrict__ y_o, uint4* __restrict__ xa1_o){
  __shared__ uint4 A_u4[1024];    // 128 rows: h1 -> xa1
  __shared__ uint4 X_u4[1024];    // 128 rows: x_ia -> Y
  __shared__ uint4 W2_u4[512];
  __shared__ uint4 A1_u4[512];
  __shared__ uint4 WW_u4[512];
  __shared__ float4 rsh4[80];
  __shared__ float b2sh[64];
  u16* A16 = (u16*)A_u4;
  u16* X16 = (u16*)X_u4;
  const int tid = threadIdx.x;
  for(int cid = tid; cid < 512; cid += 256){
    int dd = cid >> 3, ch = cid & 7;
    W2_u4[dd*8 + (ch ^ (dd&7))] = w2t_g[cid];
    A1_u4[dd*8 + (ch ^ (dd&7))] = a1t_g[cid];
    WW_u4[dd*8 + (ch ^ (dd&7))] = wwt_g[cid];
  }
  if(tid < 80) rsh4[tid] = ratp[tid];
  if(tid < 64) b2sh[tid] = b2[tid];
  __syncthreads();

  const int base = blockIdx.x*128;
  const int ch = tid & 7;
#pragma unroll
  for(int it=0; it<4; ++it){
    int s = it*32 + (tid>>3);
    int cidx = base + s;
    uint4 o = {0,0,0,0};
    if(cidx < C_N){
      int i = cidx/5, r = cidx - i*5;
      uint4 iv = itemp[(size_t)i*8 + ch];
      float4 r0 = rsh4[r*16 + ch*2], r1 = rsh4[r*16 + ch*2 + 1];
      o.x = pkbf(fmaxf(blo(iv.x)+r0.x,0.f), fmaxf(bhi(iv.x)+r0.y,0.f));
      o.y = pkbf(fmaxf(blo(iv.y)+r0.z,0.f), fmaxf(bhi(iv.y)+r0.w,0.f));
      o.z = pkbf(fmaxf(blo(iv.z)+r1.x,0.f), fmaxf(bhi(iv.z)+r1.y,0.f));
      o.w = pkbf(fmaxf(blo(iv.w)+r1.z,0.f), fmaxf(bhi(iv.w)+r1.w,0.f));
    }
    A_u4[s*8 + (ch ^ (s&7))] = o;
  }
  __syncthreads();

  const int l = tid & 63, w = tid >> 6;
  const int lr = l & 15, g = l >> 4;
  bf16x8 w2f[4][2], a1f[4][2], wwf[4][2];
#pragma unroll
  for(int nt=0; nt<4; ++nt)
#pragma unroll
    for(int kk=0; kk<2; ++kk){
      int d = nt*16 + lr;
      w2f[nt][kk] = *(const bf16x8*)&W2_u4[d*8 + ((kk*4+g) ^ (d&7))];
      a1f[nt][kk] = *(const bf16x8*)&A1_u4[d*8 + ((kk*4+g) ^ (d&7))];
      wwf[nt][kk] = *(const bf16x8*)&WW_u4[d*8 + ((kk*4+g) ^ (d&7))];
    }
  float b2v[4];
#pragma unroll
  for(int nt=0; nt<4; ++nt) b2v[nt] = b2sh[nt*16 + lr];

#pragma unroll
  for(int t=0; t<2; ++t){
    int s = w*32 + t*16 + lr;
    bf16x8 af0 = *(const bf16x8*)&A_u4[s*8 + ((0*4+g) ^ (s&7))];
    bf16x8 af1 = *(const bf16x8*)&A_u4[s*8 + ((1*4+g) ^ (s&7))];
    // GEMM1: x_ia
#pragma unroll
    for(int nt=0; nt<4; ++nt){
      f32x4 c0 = { b2v[nt], b2v[nt], b2v[nt], b2v[nt] };
      c0 = __builtin_amdgcn_mfma_f32_16x16x32_bf16(af0, w2f[nt][0], c0, 0, 0, 0);
      c0 = __builtin_amdgcn_mfma_f32_16x16x32_bf16(af1, w2f[nt][1], c0, 0, 0, 0);
      int d = nt*16 + lr;
#pragma unroll
      for(int reg=0; reg<4; ++reg){
        int srow = w*32 + t*16 + g*4 + reg;
        X16[srow*64 + ((d>>3)^(srow&7))*8 + (d&7)] = f2b(fmaxf(c0[reg], 0.f));
      }
    }
    bf16x8 xf0 = *(const bf16x8*)&X_u4[s*8 + ((0*4+g) ^ (s&7))];
    bf16x8 xf1 = *(const bf16x8*)&X_u4[s*8 + ((1*4+g) ^ (s&7))];
    // GEMM2: xa1 -> A16 rows (h1 dead)
#pragma unroll
    for(int nt=0; nt<4; ++nt){
      f32x4 c0 = { 0.f, 0.f, 0.f, 0.f };
      c0 = __builtin_amdgcn_mfma_f32_16x16x32_bf16(xf0, a1f[nt][0], c0, 0, 0, 0);
      c0 = __builtin_amdgcn_mfma_f32_16x16x32_bf16(xf1, a1f[nt][1], c0, 0, 0, 0);
      int d = nt*16 + lr;
#pragma unroll
      for(int reg=0; reg<4; ++reg){
        int srow = w*32 + t*16 + g*4 + reg;
        A16[srow*64 + ((d>>3)^(srow&7))*8 + (d&7)] = f2b(c0[reg]);
      }
    }
    // GEMM3: Y = x_ia @ WW -> X16 rows (x_ia consumed)
#pragma unroll
    for(int nt=0; nt<4; ++nt){
      f32x4 c0 = { 0.f, 0.f, 0.f, 0.f };
      c0 = __builtin_amdgcn_mfma_f32_16x16x32_bf16(xf0, wwf[nt][0], c0, 0, 0, 0);
      c0 = __builtin_amdgcn_mfma_f32_16x16x32_bf16(xf1, wwf[nt][1], c0, 0, 0, 0);
      int d = nt*16 + lr;
#pragma unroll
      for(int reg=0; reg<4; ++reg){
        int srow = w*32 + t*16 + g*4 + reg;
        X16[srow*64 + ((d>>3)^(srow&7))*8 + (d&7)] = f2b(c0[reg]);
      }
    }
  }
#pragma unroll
  for(int it=0; it<4; ++it){
    int s = w*32 + it*8 + (l>>3);
    int c2 = l & 7;
    int r = base + s;
    if(r < C_N){
      y_o  [(size_t)r*8 + c2] = X_u4[s*8 + (c2 ^ (s&7))];
      xa1_o[(size_t)r*8 + c2] = A_u4[s*8 + (c2 ^ (s&7))];
    }
  }
}

// ---------------- MFMA edge-logit kernel ----------------
__global__ __launch_bounds__(256) void k_edge_mfma(const int* __restrict__ u_s, const int* __restrict__ c_s,
                                                   const uint4* __restrict__ xa1p, const uint4* __restrict__ userp,
                                                   const uint4* __restrict__ a2t_g,
                                                   const float* __restrict__ a2b,
                                                   const float* __restrict__ a3w, const float* __restrict__ a3b,
                                                   float* __restrict__ wlog){
  __shared__ uint4 A_u4[2048];
  __shared__ uint4 W_u4[512];
  __shared__ float b2s[64];
  __shared__ float a3s[64];
  const int tid = threadIdx.x;
  for(int cid = tid; cid < 512; cid += 256){
    int d = cid >> 3, ch = cid & 7;
    W_u4[d*8 + (ch ^ (d&7))] = a2t_g[cid];
  }
  if(tid < 64){ b2s[tid] = a2b[tid]; a3s[tid] = a3w[tid]; }
  const int base = blockIdx.x*256;
  const int ch = tid & 7;
#pragma unroll
  for(int it=0; it<8; ++it){
    int s = it*32 + (tid>>3);
    int e = base + s;
    uint4 xv = {0,0,0,0}, uv = {0,0,0,0};
    if(e < E_N){
      int c = c_s[e], u = u_s[e];
      xv = xa1p[(size_t)c*8 + ch];
      uv = userp[(size_t)u*8 + ch];
    }
    uint4 o;
    o.x = pkbf(fmaxf(blo(xv.x)+blo(uv.x),0.f), fmaxf(bhi(xv.x)+bhi(uv.x),0.f));
    o.y = pkbf(fmaxf(blo(xv.y)+blo(uv.y),0.f), fmaxf(bhi(xv.y)+bhi(uv.y),0.f));
    o.z = pkbf(fmaxf(blo(xv.z)+blo(uv.z),0.f), fmaxf(bhi(xv.z)+bhi(uv.z),0.f));
    o.w = pkbf(fmaxf(blo(xv.w)+blo(uv.w),0.f), fmaxf(bhi(xv.w)+bhi(uv.w),0.f));
    A_u4[s*8 + (ch ^ (s&7))] = o;
  }
  __syncthreads();
  const int l = tid & 63, w = tid >> 6;
  const int lr = l & 15;
  const int g  = l >> 4;
  bf16x8 bf[4][2];
#pragma unroll
  for(int nt=0; nt<4; ++nt)
#pragma unroll
    for(int kk=0; kk<2; ++kk){
      int d = nt*16 + lr;
      bf[nt][kk] = *(const bf16x8*)&W_u4[d*8 + ((kk*4 + g) ^ (d&7))];
    }
  float b2v[4], a3v[4];
#pragma unroll
  for(int nt=0; nt<4; ++nt){ b2v[nt] = b2s[nt*16 + lr]; a3v[nt] = a3s[nt*16 + lr]; }
  const float a3b0 = a3b[0];
#pragma unroll
  for(int t=0; t<4; ++t){
    int s = w*64 + t*16 + lr;
    bf16x8 af0 = *(const bf16x8*)&A_u4[s*8 + ((0*4 + g) ^ (s&7))];
    bf16x8 af1 = *(const bf16x8*)&A_u4[s*8 + ((1*4 + g) ^ (s&7))];
    f32x4 acc[4];
#pragma unroll
    for(int nt=0; nt<4; ++nt){
      f32x4 c0 = { b2v[nt], b2v[nt], b2v[nt], b2v[nt] };
      c0 = __builtin_amdgcn_mfma_f32_16x16x32_bf16(af0, bf[nt][0], c0, 0, 0, 0);
      c0 = __builtin_amdgcn_mfma_f32_16x16x32_bf16(af1, bf[nt][1], c0, 0, 0, 0);
      acc[nt] = c0;
    }
    float s0=0.f, s1=0.f, s2=0.f, s3=0.f;
#pragma unroll
    for(int nt=0; nt<4; ++nt){
      s0 += fmaxf(acc[nt][0], 0.f) * a3v[nt];
      s1 += fmaxf(acc[nt][1], 0.f) * a3v[nt];
      s2 += fmaxf(acc[nt][2], 0.f) * a3v[nt];
      s3 += fmaxf(acc[nt][3], 0.f) * a3v[nt];
    }
#pragma unroll
    for(int mask=1; mask<16; mask<<=1){
      s0 += __shfl_xor(s0, mask);
      s1 += __shfl_xor(s1, mask);
      s2 += __shfl_xor(s2, mask);
      s3 += __shfl_xor(s3, mask);
    }
    if(lr == 0){
      int e0 = base + w*64 + t*16 + g*4;
      if(e0+0 < E_N) wlog[e0+0] = s0 + a3b0;
      if(e0+1 < E_N) wlog[e0+1] = s1 + a3b0;
      if(e0+2 < E_N) wlog[e0+2] = s2 + a3b0;
      if(e0+3 < E_N) wlog[e0+3] = s3 + a3b0;
    }
  }
}

// ---------------- softmax normalize: pval[e] = bf16(exp(wlog-m)/sum) ----------------
__global__ __launch_bounds__(256) void k_smax(const int* __restrict__ start,
                                              const float* __restrict__ wlog,
                                              u16* __restrict__ pval){
  int w = threadIdx.x >> 6, lane = threadIdx.x & 63;
  int u = blockIdx.x*4 + w;
  int s0 = start[u], n = start[u+1] - s0;
  int nq = (n + 63) >> 6;
  float tq[4];
  float m = -1e30f;
  for(int q=0; q<nq; ++q){
    int j = q*64 + lane;
    float t = (j<n) ? wlog[s0+j] : -1e30f;
    if(q<4) tq[q] = t;
    m = fmaxf(m, t);
  }
#pragma unroll
  for(int off=32; off>=1; off>>=1) m = fmaxf(m, __shfl_xor(m, off));
  float ssum = 0.f;
  for(int q=0; q<nq; ++q){
    int j = q*64 + lane;
    float t = (q<4) ? tq[q] : ((j<n) ? wlog[s0+j] : -1e30f);
    float e = (j<n) ? __expf(t - m) : 0.f;
    if(q<4) tq[q] = e;
    ssum += e;
  }
#pragma unroll
  for(int off=32; off>=1; off>>=1) ssum += __shfl_xor(ssum, off);
  float inv = (n>0) ? (1.f/ssum) : 0.f;
  for(int q=0; q<nq; ++q){
    int j = q*64 + lane;
    float e = (q<4) ? tq[q] : ((j<n) ? __expf(wlog[s0+j] - m) : 0.f);
    if(j<n) pval[s0+j] = f2b(e * inv);
  }
}

// ---------------- MFMA aggregate: out[16 users][64] = P-mask @ Y-rows + w_b ----------------
__global__ __launch_bounds__(256) void k_agg(const int* __restrict__ start,
                                             const int* __restrict__ u_s, const int* __restrict__ c_s,
                                             const u16* __restrict__ pval,
                                             const u16* __restrict__ Y,
                                             const float* __restrict__ wb,
                                             float* __restrict__ out){
  int w = threadIdx.x >> 6, l = threadIdx.x & 63;
  int lr = l & 15, g = l >> 4;
  int base = (blockIdx.x*4 + w) * 16;
  if(base >= U_N) return;
  int s0g = start[base];
  int s1g = start[base+16];
  int myu = base + lr;
  float wbv[4];
#pragma unroll
  for(int nt=0; nt<4; ++nt) wbv[nt] = wb[nt*16 + lr];
  f32x4 acc[4];
#pragma unroll
  for(int nt=0; nt<4; ++nt) acc[nt] = f32x4{ wbv[nt], wbv[nt], wbv[nt], wbv[nt] };

  int sA = s0g & ~31;
  int nch = (s1g - sA + 31) >> 5;
  for(int ch=0; ch<nch; ++ch){
    int e0 = sA + ch*32;
    int kb = g*8;
    bf16x8 pv = *(const bf16x8*)(pval + e0 + kb);
    int4 u0 = *(const int4*)(u_s + e0 + kb);
    int4 u1 = *(const int4*)(u_s + e0 + kb + 4);
    int4 cA = *(const int4*)(c_s + e0 + kb);
    int4 cB = *(const int4*)(c_s + e0 + kb + 4);
    bf16x8 af;
    af[0] = (u0.x == myu) ? pv[0] : (short)0;
    af[1] = (u0.y == myu) ? pv[1] : (short)0;
    af[2] = (u0.z == myu) ? pv[2] : (short)0;
    af[3] = (u0.w == myu) ? pv[3] : (short)0;
    af[4] = (u1.x == myu) ? pv[4] : (short)0;
    af[5] = (u1.y == myu) ? pv[5] : (short)0;
    af[6] = (u1.z == myu) ? pv[6] : (short)0;
    af[7] = (u1.w == myu) ? pv[7] : (short)0;
    int cj[8] = {cA.x, cA.y, cA.z, cA.w, cB.x, cB.y, cB.z, cB.w};
    bf16x8 b0, b1, b2, b3;
#pragma unroll
    for(int j=0; j<8; ++j){
      const u16* yr = Y + (size_t)cj[j]*64 + lr;
      b0[j] = (short)yr[0];
      b1[j] = (short)yr[16];
      b2[j] = (short)yr[32];
      b3[j] = (short)yr[48];
    }
    acc[0] = __builtin_amdgcn_mfma_f32_16x16x32_bf16(af, b0, acc[0], 0, 0, 0);
    acc[1] = __builtin_amdgcn_mfma_f32_16x16x32_bf16(af, b1, acc[1], 0, 0, 0);
    acc[2] = __builtin_amdgcn_mfma_f32_16x16x32_bf16(af, b2, acc[2], 0, 0, 0);
    acc[3] = __builtin_amdgcn_mfma_f32_16x16x32_bf16(af, b3, acc[3], 0, 0, 0);
  }
#pragma unroll
  for(int nt=0; nt<4; ++nt){
#pragma unroll
    for(int reg=0; reg<4; ++reg){
      int u = base + g*4 + reg;
      out[(size_t)u*64 + nt*16 + lr] = acc[nt][reg];
    }
  }
}

extern "C" void kernel_launch(void* const* d_in, const int* in_sizes, int n_in,
                              void* d_out, int out_size, void* d_ws, size_t ws_size,
                              hipStream_t stream){
  (void)in_sizes; (void)n_in; (void)out_size; (void)ws_size;
  const float4* user_feat  = (const float4*)d_in[0];
  const float4* item_feat  = (const float4*)d_in[1];
  const float*  rating_feat= (const float*)d_in[2];
  const int*    rows       = (const int*)d_in[3];
  const int*    cols       = (const int*)d_in[4];
  const int*    rats       = (const int*)d_in[5];
  const float* gv_w1 = (const float*)d_in[6];
  const float* gv_b1 = (const float*)d_in[7];
  const float* gv_w2 = (const float*)d_in[8];
  const float* gv_b2 = (const float*)d_in[9];
  const float* att_w1= (const float*)d_in[10];
  const float* att_b1= (const float*)d_in[11];
  const float* att_w2= (const float*)d_in[12];
  const float* att_b2= (const float*)d_in[13];
  const float* att_w3= (const float*)d_in[14];
  const float* att_b3= (const float*)d_in[15];
  const float* w_w   = (const float*)d_in[16];
  const float* w_b   = (const float*)d_in[17];
  float* out = (float*)d_out;

  char* ws = (char*)d_ws; size_t off = 0;
  auto take = [&](size_t b)->char*{ char* p = ws + off; off = (off + b + 255) & ~(size_t)255; return p; };
  bf16_t* item_part  = (bf16_t*)take((size_t)I_N*64*2);       // 6.4 MB
  bf16_t* user_part  = (bf16_t*)take((size_t)U_N*64*2);       // 12.8 MB
  float*  rating_part= (float*) take((size_t)R_N*64*4);
  bf16_t* y_t        = (bf16_t*)take((size_t)C_N*64*2);       // 32 MB  (Y = x_ia @ w_w)
  bf16_t* xa1_t      = (bf16_t*)take((size_t)C_N*64*2);       // 32 MB
  float*  wlog_s     = (float*) take((size_t)E_N*4);          // 8 MB
  int*    c_s        = (int*)   take((size_t)E_N*4);          // 8 MB
  int*    u_s        = (int*)   take((size_t)E_N*4);          // 8 MB
  u16*    pval       = (u16*)   take((size_t)E_N*2);          // 4 MB
  unsigned* uc       = (unsigned*)take((size_t)NBUCK*SUBB*CAPB*4); // 25.6 MB
  int*    tails      = (int*)   take((size_t)NBUCK*SUBB*4);
  int*    cnt        = (int*)   take((size_t)(NBLK_U*256)*4);
  int*    start      = (int*)   take((size_t)(NBLK_U*256)*4);
  int*    bsum       = (int*)   take((size_t)512*4);
  u16*    w1t        = (u16*)   take((size_t)4096*2);
  u16*    u1t        = (u16*)   take((size_t)4096*2);
  u16*    w2t        = (u16*)   take((size_t)4096*2);
  u16*    a1t        = (u16*)   take((size_t)4096*2);
  u16*    a2t        = (u16*)   take((size_t)4096*2);
  u16*    wwt        = (u16*)   take((size_t)4096*2);

  // CSR build (bucketed, XCD-local)
  k_zero_tails<<<(NBUCK*SUBB+255)/256, 256, 0, stream>>>(tails);
  k_binA <<<NBLK_E, 256, 0, stream>>>(rows, cols, rats, tails, uc);
  k_binB1<<<NBUCK, 256, 0, stream>>>(tails, uc, cnt);
  k_scanA<<<NBLK_U, 256, 0, stream>>>(cnt, start, bsum);
  k_scanB<<<1, 512, 0, stream>>>(bsum, NBLK_U);
  k_scanC<<<NBLK_U, 256, 0, stream>>>(start, bsum);
  k_binB2<<<NBUCK, 256, 0, stream>>>(tails, uc, start, u_s, c_s);
  // weights + tiny GEMV
  k_ratpart <<<1, 320, 0, stream>>>(rating_feat, gv_w1, gv_b1, rating_part);
  k_prepw6  <<<96, 256, 0, stream>>>(gv_w1, att_w1, gv_w2, att_w2, w_w, w1t, u1t, w2t, a1t, a2t, wwt);
  // dense precompute (MFMA)
  k_rowgemm<false><<<(I_N+255)/256, 256, 0, stream>>>(item_feat, (const uint4*)w1t, nullptr,
                                                      (uint4*)item_part, I_N);
  k_rowgemm<true> <<<NBLK_U, 256, 0, stream>>>(user_feat, (const uint4*)u1t, att_b1,
                                               (uint4*)user_part, U_N);
  k_combo_mfma<<<NBLK_C, 256, 0, stream>>>((const uint4*)item_part, (const float4*)rating_part,
                                           (const uint4*)w2t, (const uint4*)a1t, (const uint4*)wwt, gv_b2,
                                           (uint4*)y_t, (uint4*)xa1_t);
  // per-edge logits (MFMA)
  k_edge_mfma<<<NBLK_E, 256, 0, stream>>>(u_s, c_s, (const uint4*)xa1_t, (const uint4*)user_part,
                                          (const uint4*)a2t, att_b2, att_w3, att_b3, wlog_s);
  // softmax normalize + MFMA aggregate (out = P @ Y + w_b)
  k_smax <<<U_N/4, 256, 0, stream>>>(start, wlog_s, pval);
  k_agg  <<<(U_N/64)+1, 256, 0, stream>>>(start, u_s, c_s, pval, (const u16*)y_t, w_b, out);
}

// Round 9
// 397.153 us; speedup vs baseline: 1.2390x; 1.2359x over previous
//
#include <hip/hip_runtime.h>
#include <hip/hip_bf16.h>

#define U_N 100000
#define I_N 50000
#define E_N 2000000
#define R_N 5
#define C_N (I_N*R_N)   // 250000 combos
#define NBLK_U 391      // ceil(100000/256); NBLK_U*256 = 100096
#define NBLK_E 7813     // ceil(2000000/256)
#define NBLK_C 1954     // ceil(250000/128)
#define NBUCK 782       // ceil(100000/128) user buckets
#define SUBB 8          // sub-buckets
#define CAPB 1024       // usable capacity per (bucket,sub); mean fill 320
#define STRD 1040       // stream stride in ints: 4160B = 65 cache lines (odd) -> no L2 set aliasing

typedef __hip_bfloat16 bf16_t;
typedef unsigned short u16;
typedef __attribute__((ext_vector_type(8))) short bf16x8;
typedef __attribute__((ext_vector_type(4))) float f32x4;

__device__ __forceinline__ float blo(unsigned u){ return __uint_as_float(u<<16); }
__device__ __forceinline__ float bhi(unsigned u){ return __uint_as_float(u & 0xffff0000u); }
__device__ __forceinline__ unsigned pkbf(float a, float b){
  __hip_bfloat162 t = __float22bfloat162_rn(float2{a,b});
  union { __hip_bfloat162 h; unsigned u; } cv; cv.h = t; return cv.u;
}
__device__ __forceinline__ u16 f2b(float v){
  union { __hip_bfloat16 h; u16 u; } cv; cv.h = __float2bfloat16(v); return cv.u;
}

// ---------------- CSR build: bucketed two-pass ----------------
__global__ __launch_bounds__(256) void k_zero_tails(int* tails){
  int i = blockIdx.x*256 + threadIdx.x;
  if(i < NBUCK*SUBB) tails[i] = 0;
}

// pass A: append packed (u&127)<<18 | c to bucket (u>>7), sub-bucket by blockIdx&7.
// Stream stride 4160B (not 4096) so open append lines spread across L2 sets.
__global__ __launch_bounds__(256) void k_binA(const int* __restrict__ rows, const int* __restrict__ cols,
                                              const int* __restrict__ rats,
                                              int* __restrict__ tails, unsigned* __restrict__ uc){
  int e = blockIdx.x*256 + threadIdx.x; if(e >= E_N) return;
  int u = cols[e];
  int c = rows[e]*5 + rats[e];
  int b = u >> 7;
  int sb = b*SUBB + (blockIdx.x & 7);
  int slot = atomicAdd(tails + sb, 1);
  if(slot < CAPB) uc[(size_t)sb*STRD + slot] = ((unsigned)(u & 127) << 18) | (unsigned)c;
}

// pass B1: per-bucket LDS histogram -> cnt
__global__ __launch_bounds__(256) void k_binB1(const int* __restrict__ tails, const unsigned* __restrict__ uc,
                                               int* __restrict__ cnt){
  __shared__ int hist[128];
  int t = threadIdx.x, b = blockIdx.x;
  if(t < 128) hist[t] = 0;
  __syncthreads();
  for(int sub=0; sub<SUBB; ++sub){
    int sb = b*SUBB + sub;
    int n = tails[sb]; if(n > CAPB) n = CAPB;
    const unsigned* p = uc + (size_t)sb*STRD;
    for(int j=t; j<n; j+=256) atomicAdd(&hist[(p[j]>>18) & 127], 1);
  }
  __syncthreads();
  if(t < 128) cnt[b*128 + t] = hist[t];
}

__global__ __launch_bounds__(256) void k_scanA(const int* __restrict__ cnt, int* __restrict__ start,
                                               int* __restrict__ bsum){
  __shared__ int s[256];
  int t = threadIdx.x, i = blockIdx.x*256 + t;
  int v = (i < U_N) ? cnt[i] : 0;
  s[t] = v; __syncthreads();
  for(int off=1; off<256; off<<=1){
    int x = (t>=off) ? s[t-off] : 0;
    __syncthreads();
    s[t] += x;
    __syncthreads();
  }
  start[i] = s[t] - v;
  if(t == 255) bsum[blockIdx.x] = s[255];
}

__global__ void k_scanB(int* bsum, int n){
  __shared__ int s[512];
  int t = threadIdx.x;
  int v = (t < n) ? bsum[t] : 0;
  s[t] = v; __syncthreads();
  for(int off=1; off<512; off<<=1){
    int x = (t>=off) ? s[t-off] : 0;
    __syncthreads();
    s[t] += x;
    __syncthreads();
  }
  if(t < n) bsum[t] = s[t] - v;
}

__global__ __launch_bounds__(256) void k_scanC(int* start, const int* __restrict__ bsum){
  int i = blockIdx.x*256 + threadIdx.x;
  start[i] += bsum[blockIdx.x];
}

// pass B2: per-bucket placement into L2-resident final windows
__global__ __launch_bounds__(256) void k_binB2(const int* __restrict__ tails, const unsigned* __restrict__ uc,
                                               const int* __restrict__ start,
                                               int* __restrict__ u_s, int* __restrict__ c_s){
  __shared__ int fillb[128];
  __shared__ int startb[128];
  int t = threadIdx.x, b = blockIdx.x;
  if(t < 128){
    fillb[t] = 0;
    startb[t] = start[b*128 + t];
  }
  __syncthreads();
  for(int sub=0; sub<SUBB; ++sub){
    int sb = b*SUBB + sub;
    int n = tails[sb]; if(n > CAPB) n = CAPB;
    const unsigned* p = uc + (size_t)sb*STRD;
    for(int j=t; j<n; j+=256){
      unsigned v = p[j];
      int ul = (int)(v >> 18);
      int c  = (int)(v & 0x3FFFFu);
      int off = atomicAdd(&fillb[ul], 1);
      int pos = startb[ul] + off;
      u_s[pos] = (b << 7) | ul;
      c_s[pos] = c;
    }
  }
}

// ---------------- tiny precompute ----------------
__global__ void k_ratpart(const float* __restrict__ rf, const float* __restrict__ w1,
                          const float* __restrict__ b1, float* __restrict__ out){
  int t = threadIdx.x; if(t >= R_N*64) return;
  int r = t>>6, d = t&63;
  float acc = b1[d];
  for(int k=0;k<64;k++) acc += rf[r*64 + k] * w1[(64+k)*64 + d];
  out[t] = acc;
}

__global__ __launch_bounds__(256) void k_prepw6(const float* __restrict__ w1, const float* __restrict__ a1,
                                                const float* __restrict__ w2, const float* __restrict__ a2,
                                                const float* __restrict__ ww,
                                                u16* w1t, u16* u1t, u16* w2t, u16* a1t, u16* a2t, u16* wwt){
  int idx = (blockIdx.x & 15)*256 + threadIdx.x;
  int sec = blockIdx.x >> 4;
  int d = idx >> 6, k = idx & 63;
  const float* src; u16* dst; int ko = 0;
  switch(sec){
    case 0: src=w1; dst=w1t; break;
    case 1: src=a1; dst=u1t; ko=64; break;
    case 2: src=w2; dst=w2t; break;
    case 3: src=a1; dst=a1t; break;
    case 4: src=a2; dst=a2t; break;
    default: src=ww; dst=wwt; break;
  }
  dst[idx] = f2b(src[(size_t)(ko+k)*64 + d]);
}

// ---------------- MFMA row-GEMM: out[n][64](bf16) = in[n][64](f32) @ W (+bias) ----------------
template<bool BIAS>
__global__ __launch_bounds__(256) void k_rowgemm(const float4* __restrict__ in,
                                                 const uint4* __restrict__ wt,
                                                 const float* __restrict__ bias,
                                                 uint4* __restrict__ outp, int n){
  __shared__ uint4 A_u4[2048];
  __shared__ uint4 W_u4[512];
  __shared__ float bsh[64];
  u16* A16 = (u16*)A_u4;
  const int tid = threadIdx.x;
  for(int cid = tid; cid < 512; cid += 256){
    int dd = cid >> 3, ch = cid & 7;
    W_u4[dd*8 + (ch ^ (dd&7))] = wt[cid];
  }
  if(BIAS && tid < 64) bsh[tid] = bias[tid];
  const int base = blockIdx.x*256;
  const int ch = tid & 7;
#pragma unroll
  for(int it=0; it<8; ++it){
    int s = it*32 + (tid>>3);
    int r = base + s;
    uint4 o = {0,0,0,0};
    if(r < n){
      const float4* p = in + (size_t)r*16 + ch*2;
      float4 v0 = p[0], v1 = p[1];
      o.x = pkbf(v0.x, v0.y); o.y = pkbf(v0.z, v0.w);
      o.z = pkbf(v1.x, v1.y); o.w = pkbf(v1.z, v1.w);
    }
    A_u4[s*8 + (ch ^ (s&7))] = o;
  }
  __syncthreads();
  const int l = tid & 63, w = tid >> 6;
  const int lr = l & 15, g = l >> 4;
  bf16x8 bfr[4][2];
#pragma unroll
  for(int nt=0; nt<4; ++nt)
#pragma unroll
    for(int kk=0; kk<2; ++kk){
      int d = nt*16 + lr;
      bfr[nt][kk] = *(const bf16x8*)&W_u4[d*8 + ((kk*4+g) ^ (d&7))];
    }
  float bv[4];
#pragma unroll
  for(int nt=0; nt<4; ++nt) bv[nt] = BIAS ? bsh[nt*16 + lr] : 0.f;
#pragma unroll
  for(int t=0; t<4; ++t){
    int s = w*64 + t*16 + lr;
    bf16x8 af0 = *(const bf16x8*)&A_u4[s*8 + ((0*4+g) ^ (s&7))];
    bf16x8 af1 = *(const bf16x8*)&A_u4[s*8 + ((1*4+g) ^ (s&7))];
    f32x4 acc[4];
#pragma unroll
    for(int nt=0; nt<4; ++nt){
      f32x4 c0 = { bv[nt], bv[nt], bv[nt], bv[nt] };
      c0 = __builtin_amdgcn_mfma_f32_16x16x32_bf16(af0, bfr[nt][0], c0, 0, 0, 0);
      c0 = __builtin_amdgcn_mfma_f32_16x16x32_bf16(af1, bfr[nt][1], c0, 0, 0, 0);
      acc[nt] = c0;
    }
#pragma unroll
    for(int nt=0; nt<4; ++nt){
      int d = nt*16 + lr;
#pragma unroll
      for(int reg=0; reg<4; ++reg){
        int srow = w*64 + t*16 + g*4 + reg;
        A16[srow*64 + ((d>>3)^(srow&7))*8 + (d&7)] = f2b(acc[nt][reg]);
      }
    }
  }
#pragma unroll
  for(int it=0; it<8; ++it){
    int s = w*64 + it*8 + (l>>3);
    int c2 = l & 7;
    int r = base + s;
    if(r < n) outp[(size_t)r*8 + c2] = A_u4[s*8 + (c2 ^ (s&7))];
  }
}

// ---------------- combo: h1=relu(itemp+ratp); x_ia=relu(h1@W2+b2); xa1=x_ia@A1top; Y=x_ia@WW ----------------
__global__ __launch_bounds__(256) void k_combo_mfma(const uint4* __restrict__ itemp,
                                                    const float4* __restrict__ ratp,
                                                    const uint4* __restrict__ w2t_g, const uint4* __restrict__ a1t_g,
                                                    const uint4* __restrict__ wwt_g,
                                                    const float* __restrict__ b2,
                                                    uint4* __restrict__ y_o, uint4* __restrict__ xa1_o){
  __shared__ uint4 A_u4[1024];
  __shared__ uint4 X_u4[1024];
  __shared__ uint4 W2_u4[512];
  __shared__ uint4 A1_u4[512];
  __shared__ uint4 WW_u4[512];
  __shared__ float4 rsh4[80];
  __shared__ float b2sh[64];
  u16* A16 = (u16*)A_u4;
  u16* X16 = (u16*)X_u4;
  const int tid = threadIdx.x;
  for(int cid = tid; cid < 512; cid += 256){
    int dd = cid >> 3, ch = cid & 7;
    W2_u4[dd*8 + (ch ^ (dd&7))] = w2t_g[cid];
    A1_u4[dd*8 + (ch ^ (dd&7))] = a1t_g[cid];
    WW_u4[dd*8 + (ch ^ (dd&7))] = wwt_g[cid];
  }
  if(tid < 80) rsh4[tid] = ratp[tid];
  if(tid < 64) b2sh[tid] = b2[tid];
  __syncthreads();

  const int base = blockIdx.x*128;
  const int ch = tid & 7;
#pragma unroll
  for(int it=0; it<4; ++it){
    int s = it*32 + (tid>>3);
    int cidx = base + s;
    uint4 o = {0,0,0,0};
    if(cidx < C_N){
      int i = cidx/5, r = cidx - i*5;
      uint4 iv = itemp[(size_t)i*8 + ch];
      float4 r0 = rsh4[r*16 + ch*2], r1 = rsh4[r*16 + ch*2 + 1];
      o.x = pkbf(fmaxf(blo(iv.x)+r0.x,0.f), fmaxf(bhi(iv.x)+r0.y,0.f));
      o.y = pkbf(fmaxf(blo(iv.y)+r0.z,0.f), fmaxf(bhi(iv.y)+r0.w,0.f));
      o.z = pkbf(fmaxf(blo(iv.z)+r1.x,0.f), fmaxf(bhi(iv.z)+r1.y,0.f));
      o.w = pkbf(fmaxf(blo(iv.w)+r1.z,0.f), fmaxf(bhi(iv.w)+r1.w,0.f));
    }
    A_u4[s*8 + (ch ^ (s&7))] = o;
  }
  __syncthreads();

  const int l = tid & 63, w = tid >> 6;
  const int lr = l & 15, g = l >> 4;
  bf16x8 w2f[4][2], a1f[4][2], wwf[4][2];
#pragma unroll
  for(int nt=0; nt<4; ++nt)
#pragma unroll
    for(int kk=0; kk<2; ++kk){
      int d = nt*16 + lr;
      w2f[nt][kk] = *(const bf16x8*)&W2_u4[d*8 + ((kk*4+g) ^ (d&7))];
      a1f[nt][kk] = *(const bf16x8*)&A1_u4[d*8 + ((kk*4+g) ^ (d&7))];
      wwf[nt][kk] = *(const bf16x8*)&WW_u4[d*8 + ((kk*4+g) ^ (d&7))];
    }
  float b2v[4];
#pragma unroll
  for(int nt=0; nt<4; ++nt) b2v[nt] = b2sh[nt*16 + lr];

#pragma unroll
  for(int t=0; t<2; ++t){
    int s = w*32 + t*16 + lr;
    bf16x8 af0 = *(const bf16x8*)&A_u4[s*8 + ((0*4+g) ^ (s&7))];
    bf16x8 af1 = *(const bf16x8*)&A_u4[s*8 + ((1*4+g) ^ (s&7))];
    // GEMM1: x_ia
#pragma unroll
    for(int nt=0; nt<4; ++nt){
      f32x4 c0 = { b2v[nt], b2v[nt], b2v[nt], b2v[nt] };
      c0 = __builtin_amdgcn_mfma_f32_16x16x32_bf16(af0, w2f[nt][0], c0, 0, 0, 0);
      c0 = __builtin_amdgcn_mfma_f32_16x16x32_bf16(af1, w2f[nt][1], c0, 0, 0, 0);
      int d = nt*16 + lr;
#pragma unroll
      for(int reg=0; reg<4; ++reg){
        int srow = w*32 + t*16 + g*4 + reg;
        X16[srow*64 + ((d>>3)^(srow&7))*8 + (d&7)] = f2b(fmaxf(c0[reg], 0.f));
      }
    }
    bf16x8 xf0 = *(const bf16x8*)&X_u4[s*8 + ((0*4+g) ^ (s&7))];
    bf16x8 xf1 = *(const bf16x8*)&X_u4[s*8 + ((1*4+g) ^ (s&7))];
    // GEMM2: xa1 -> A16 rows (h1 dead)
#pragma unroll
    for(int nt=0; nt<4; ++nt){
      f32x4 c0 = { 0.f, 0.f, 0.f, 0.f };
      c0 = __builtin_amdgcn_mfma_f32_16x16x32_bf16(xf0, a1f[nt][0], c0, 0, 0, 0);
      c0 = __builtin_amdgcn_mfma_f32_16x16x32_bf16(xf1, a1f[nt][1], c0, 0, 0, 0);
      int d = nt*16 + lr;
#pragma unroll
      for(int reg=0; reg<4; ++reg){
        int srow = w*32 + t*16 + g*4 + reg;
        A16[srow*64 + ((d>>3)^(srow&7))*8 + (d&7)] = f2b(c0[reg]);
      }
    }
    // GEMM3: Y = x_ia @ WW -> X16 rows (x_ia consumed)
#pragma unroll
    for(int nt=0; nt<4; ++nt){
      f32x4 c0 = { 0.f, 0.f, 0.f, 0.f };
      c0 = __builtin_amdgcn_mfma_f32_16x16x32_bf16(xf0, wwf[nt][0], c0, 0, 0, 0);
      c0 = __builtin_amdgcn_mfma_f32_16x16x32_bf16(xf1, wwf[nt][1], c0, 0, 0, 0);
      int d = nt*16 + lr;
#pragma unroll
      for(int reg=0; reg<4; ++reg){
        int srow = w*32 + t*16 + g*4 + reg;
        X16[srow*64 + ((d>>3)^(srow&7))*8 + (d&7)] = f2b(c0[reg]);
      }
    }
  }
#pragma unroll
  for(int it=0; it<4; ++it){
    int s = w*32 + it*8 + (l>>3);
    int c2 = l & 7;
    int r = base + s;
    if(r < C_N){
      y_o  [(size_t)r*8 + c2] = X_u4[s*8 + (c2 ^ (s&7))];
      xa1_o[(size_t)r*8 + c2] = A_u4[s*8 + (c2 ^ (s&7))];
    }
  }
}

// ---------------- MFMA edge-logit kernel ----------------
__global__ __launch_bounds__(256) void k_edge_mfma(const int* __restrict__ u_s, const int* __restrict__ c_s,
                                                   const uint4* __restrict__ xa1p, const uint4* __restrict__ userp,
                                                   const uint4* __restrict__ a2t_g,
                                                   const float* __restrict__ a2b,
                                                   const float* __restrict__ a3w, const float* __restrict__ a3b,
                                                   float* __restrict__ wlog){
  __shared__ uint4 A_u4[2048];
  __shared__ uint4 W_u4[512];
  __shared__ float b2s[64];
  __shared__ float a3s[64];
  const int tid = threadIdx.x;
  for(int cid = tid; cid < 512; cid += 256){
    int d = cid >> 3, ch = cid & 7;
    W_u4[d*8 + (ch ^ (d&7))] = a2t_g[cid];
  }
  if(tid < 64){ b2s[tid] = a2b[tid]; a3s[tid] = a3w[tid]; }
  const int base = blockIdx.x*256;
  const int ch = tid & 7;
#pragma unroll
  for(int it=0; it<8; ++it){
    int s = it*32 + (tid>>3);
    int e = base + s;
    uint4 xv = {0,0,0,0}, uv = {0,0,0,0};
    if(e < E_N){
      int c = c_s[e], u = u_s[e];
      xv = xa1p[(size_t)c*8 + ch];
      uv = userp[(size_t)u*8 + ch];
    }
    uint4 o;
    o.x = pkbf(fmaxf(blo(xv.x)+blo(uv.x),0.f), fmaxf(bhi(xv.x)+bhi(uv.x),0.f));
    o.y = pkbf(fmaxf(blo(xv.y)+blo(uv.y),0.f), fmaxf(bhi(xv.y)+bhi(uv.y),0.f));
    o.z = pkbf(fmaxf(blo(xv.z)+blo(uv.z),0.f), fmaxf(bhi(xv.z)+bhi(uv.z),0.f));
    o.w = pkbf(fmaxf(blo(xv.w)+blo(uv.w),0.f), fmaxf(bhi(xv.w)+bhi(uv.w),0.f));
    A_u4[s*8 + (ch ^ (s&7))] = o;
  }
  __syncthreads();
  const int l = tid & 63, w = tid >> 6;
  const int lr = l & 15;
  const int g  = l >> 4;
  bf16x8 bf[4][2];
#pragma unroll
  for(int nt=0; nt<4; ++nt)
#pragma unroll
    for(int kk=0; kk<2; ++kk){
      int d = nt*16 + lr;
      bf[nt][kk] = *(const bf16x8*)&W_u4[d*8 + ((kk*4 + g) ^ (d&7))];
    }
  float b2v[4], a3v[4];
#pragma unroll
  for(int nt=0; nt<4; ++nt){ b2v[nt] = b2s[nt*16 + lr]; a3v[nt] = a3s[nt*16 + lr]; }
  const float a3b0 = a3b[0];
#pragma unroll
  for(int t=0; t<4; ++t){
    int s = w*64 + t*16 + lr;
    bf16x8 af0 = *(const bf16x8*)&A_u4[s*8 + ((0*4 + g) ^ (s&7))];
    bf16x8 af1 = *(const bf16x8*)&A_u4[s*8 + ((1*4 + g) ^ (s&7))];
    f32x4 acc[4];
#pragma unroll
    for(int nt=0; nt<4; ++nt){
      f32x4 c0 = { b2v[nt], b2v[nt], b2v[nt], b2v[nt] };
      c0 = __builtin_amdgcn_mfma_f32_16x16x32_bf16(af0, bf[nt][0], c0, 0, 0, 0);
      c0 = __builtin_amdgcn_mfma_f32_16x16x32_bf16(af1, bf[nt][1], c0, 0, 0, 0);
      acc[nt] = c0;
    }
    float s0=0.f, s1=0.f, s2=0.f, s3=0.f;
#pragma unroll
    for(int nt=0; nt<4; ++nt){
      s0 += fmaxf(acc[nt][0], 0.f) * a3v[nt];
      s1 += fmaxf(acc[nt][1], 0.f) * a3v[nt];
      s2 += fmaxf(acc[nt][2], 0.f) * a3v[nt];
      s3 += fmaxf(acc[nt][3], 0.f) * a3v[nt];
    }
#pragma unroll
    for(int mask=1; mask<16; mask<<=1){
      s0 += __shfl_xor(s0, mask);
      s1 += __shfl_xor(s1, mask);
      s2 += __shfl_xor(s2, mask);
      s3 += __shfl_xor(s3, mask);
    }
    if(lr == 0){
      int e0 = base + w*64 + t*16 + g*4;
      if(e0+0 < E_N) wlog[e0+0] = s0 + a3b0;
      if(e0+1 < E_N) wlog[e0+1] = s1 + a3b0;
      if(e0+2 < E_N) wlog[e0+2] = s2 + a3b0;
      if(e0+3 < E_N) wlog[e0+3] = s3 + a3b0;
    }
  }
}

// ---------------- softmax normalize: pval[e] = bf16(exp(wlog-m)/sum) ----------------
__global__ __launch_bounds__(256) void k_smax(const int* __restrict__ start,
                                              const float* __restrict__ wlog,
                                              u16* __restrict__ pval){
  int w = threadIdx.x >> 6, lane = threadIdx.x & 63;
  int u = blockIdx.x*4 + w;
  int s0 = start[u], n = start[u+1] - s0;
  int nq = (n + 63) >> 6;
  float tq[4];
  float m = -1e30f;
  for(int q=0; q<nq; ++q){
    int j = q*64 + lane;
    float t = (j<n) ? wlog[s0+j] : -1e30f;
    if(q<4) tq[q] = t;
    m = fmaxf(m, t);
  }
#pragma unroll
  for(int off=32; off>=1; off>>=1) m = fmaxf(m, __shfl_xor(m, off));
  float ssum = 0.f;
  for(int q=0; q<nq; ++q){
    int j = q*64 + lane;
    float t = (q<4) ? tq[q] : ((j<n) ? wlog[s0+j] : -1e30f);
    float e = (j<n) ? __expf(t - m) : 0.f;
    if(q<4) tq[q] = e;
    ssum += e;
  }
#pragma unroll
  for(int off=32; off>=1; off>>=1) ssum += __shfl_xor(ssum, off);
  float inv = (n>0) ? (1.f/ssum) : 0.f;
  for(int q=0; q<nq; ++q){
    int j = q*64 + lane;
    float e = (q<4) ? tq[q] : ((j<n) ? __expf(wlog[s0+j] - m) : 0.f);
    if(j<n) pval[s0+j] = f2b(e * inv);
  }
}

// ---------------- MFMA aggregate: out[16 users][64] = P-mask @ Y-rows + w_b ----------------
__global__ __launch_bounds__(256) void k_agg(const int* __restrict__ start,
                                             const int* __restrict__ u_s, const int* __restrict__ c_s,
                                             const u16* __restrict__ pval,
                                             const u16* __restrict__ Y,
                                             const float* __restrict__ wb,
                                             float* __restrict__ out){
  int w = threadIdx.x >> 6, l = threadIdx.x & 63;
  int lr = l & 15, g = l >> 4;
  int base = (blockIdx.x*4 + w) * 16;
  if(base >= U_N) return;
  int s0g = start[base];
  int s1g = start[base+16];
  int myu = base + lr;
  float wbv[4];
#pragma unroll
  for(int nt=0; nt<4; ++nt) wbv[nt] = wb[nt*16 + lr];
  f32x4 acc[4];
#pragma unroll
  for(int nt=0; nt<4; ++nt) acc[nt] = f32x4{ wbv[nt], wbv[nt], wbv[nt], wbv[nt] };

  int sA = s0g & ~31;
  int nch = (s1g - sA + 31) >> 5;
  for(int ch=0; ch<nch; ++ch){
    int e0 = sA + ch*32;
    int kb = g*8;
    bf16x8 pv = *(const bf16x8*)(pval + e0 + kb);
    int4 u0 = *(const int4*)(u_s + e0 + kb);
    int4 u1 = *(const int4*)(u_s + e0 + kb + 4);
    int4 cA = *(const int4*)(c_s + e0 + kb);
    int4 cB = *(const int4*)(c_s + e0 + kb + 4);
    bf16x8 af;
    af[0] = (u0.x == myu) ? pv[0] : (short)0;
    af[1] = (u0.y == myu) ? pv[1] : (short)0;
    af[2] = (u0.z == myu) ? pv[2] : (short)0;
    af[3] = (u0.w == myu) ? pv[3] : (short)0;
    af[4] = (u1.x == myu) ? pv[4] : (short)0;
    af[5] = (u1.y == myu) ? pv[5] : (short)0;
    af[6] = (u1.z == myu) ? pv[6] : (short)0;
    af[7] = (u1.w == myu) ? pv[7] : (short)0;
    int cj[8] = {cA.x, cA.y, cA.z, cA.w, cB.x, cB.y, cB.z, cB.w};
    bf16x8 b0, b1, b2, b3;
#pragma unroll
    for(int j=0; j<8; ++j){
      const u16* yr = Y + (size_t)cj[j]*64 + lr;
      b0[j] = (short)yr[0];
      b1[j] = (short)yr[16];
      b2[j] = (short)yr[32];
      b3[j] = (short)yr[48];
    }
    acc[0] = __builtin_amdgcn_mfma_f32_16x16x32_bf16(af, b0, acc[0], 0, 0, 0);
    acc[1] = __builtin_amdgcn_mfma_f32_16x16x32_bf16(af, b1, acc[1], 0, 0, 0);
    acc[2] = __builtin_amdgcn_mfma_f32_16x16x32_bf16(af, b2, acc[2], 0, 0, 0);
    acc[3] = __builtin_amdgcn_mfma_f32_16x16x32_bf16(af, b3, acc[3], 0, 0, 0);
  }
#pragma unroll
  for(int nt=0; nt<4; ++nt){
#pragma unroll
    for(int reg=0; reg<4; ++reg){
      int u = base + g*4 + reg;
      out[(size_t)u*64 + nt*16 + lr] = acc[nt][reg];
    }
  }
}

extern "C" void kernel_launch(void* const* d_in, const int* in_sizes, int n_in,
                              void* d_out, int out_size, void* d_ws, size_t ws_size,
                              hipStream_t stream){
  (void)in_sizes; (void)n_in; (void)out_size; (void)ws_size;
  const float4* user_feat  = (const float4*)d_in[0];
  const float4* item_feat  = (const float4*)d_in[1];
  const float*  rating_feat= (const float*)d_in[2];
  const int*    rows       = (const int*)d_in[3];
  const int*    cols       = (const int*)d_in[4];
  const int*    rats       = (const int*)d_in[5];
  const float* gv_w1 = (const float*)d_in[6];
  const float* gv_b1 = (const float*)d_in[7];
  const float* gv_w2 = (const float*)d_in[8];
  const float* gv_b2 = (const float*)d_in[9];
  const float* att_w1= (const float*)d_in[10];
  const float* att_b1= (const float*)d_in[11];
  const float* att_w2= (const float*)d_in[12];
  const float* att_b2= (const float*)d_in[13];
  const float* att_w3= (const float*)d_in[14];
  const float* att_b3= (const float*)d_in[15];
  const float* w_w   = (const float*)d_in[16];
  const float* w_b   = (const float*)d_in[17];
  float* out = (float*)d_out;

  char* ws = (char*)d_ws; size_t off = 0;
  auto take = [&](size_t b)->char*{ char* p = ws + off; off = (off + b + 255) & ~(size_t)255; return p; };
  bf16_t* item_part  = (bf16_t*)take((size_t)I_N*64*2);       // 6.4 MB
  bf16_t* user_part  = (bf16_t*)take((size_t)U_N*64*2);       // 12.8 MB
  float*  rating_part= (float*) take((size_t)R_N*64*4);
  bf16_t* y_t        = (bf16_t*)take((size_t)C_N*64*2);       // 32 MB  (Y = x_ia @ w_w)
  bf16_t* xa1_t      = (bf16_t*)take((size_t)C_N*64*2);       // 32 MB
  float*  wlog_s     = (float*) take((size_t)E_N*4);          // 8 MB
  int*    c_s        = (int*)   take((size_t)E_N*4);          // 8 MB
  int*    u_s        = (int*)   take((size_t)E_N*4);          // 8 MB
  u16*    pval       = (u16*)   take((size_t)E_N*2);          // 4 MB
  unsigned* uc       = (unsigned*)take((size_t)NBUCK*SUBB*STRD*4); // 26 MB
  int*    tails      = (int*)   take((size_t)NBUCK*SUBB*4);
  int*    cnt        = (int*)   take((size_t)(NBLK_U*256)*4);
  int*    start      = (int*)   take((size_t)(NBLK_U*256)*4);
  int*    bsum       = (int*)   take((size_t)512*4);
  u16*    w1t        = (u16*)   take((size_t)4096*2);
  u16*    u1t        = (u16*)   take((size_t)4096*2);
  u16*    w2t        = (u16*)   take((size_t)4096*2);
  u16*    a1t        = (u16*)   take((size_t)4096*2);
  u16*    a2t        = (u16*)   take((size_t)4096*2);
  u16*    wwt        = (u16*)   take((size_t)4096*2);

  // CSR build (bucketed, set-aliasing-free streams)
  k_zero_tails<<<(NBUCK*SUBB+255)/256, 256, 0, stream>>>(tails);
  k_binA <<<NBLK_E, 256, 0, stream>>>(rows, cols, rats, tails, uc);
  k_binB1<<<NBUCK, 256, 0, stream>>>(tails, uc, cnt);
  k_scanA<<<NBLK_U, 256, 0, stream>>>(cnt, start, bsum);
  k_scanB<<<1, 512, 0, stream>>>(bsum, NBLK_U);
  k_scanC<<<NBLK_U, 256, 0, stream>>>(start, bsum);
  k_binB2<<<NBUCK, 256, 0, stream>>>(tails, uc, start, u_s, c_s);
  // weights + tiny GEMV
  k_ratpart <<<1, 320, 0, stream>>>(rating_feat, gv_w1, gv_b1, rating_part);
  k_prepw6  <<<96, 256, 0, stream>>>(gv_w1, att_w1, gv_w2, att_w2, w_w, w1t, u1t, w2t, a1t, a2t, wwt);
  // dense precompute (MFMA)
  k_rowgemm<false><<<(I_N+255)/256, 256, 0, stream>>>(item_feat, (const uint4*)w1t, nullptr,
                                                      (uint4*)item_part, I_N);
  k_rowgemm<true> <<<NBLK_U, 256, 0, stream>>>(user_feat, (const uint4*)u1t, att_b1,
                                               (uint4*)user_part, U_N);
  k_combo_mfma<<<NBLK_C, 256, 0, stream>>>((const uint4*)item_part, (const float4*)rating_part,
                                           (const uint4*)w2t, (const uint4*)a1t, (const uint4*)wwt, gv_b2,
                                           (uint4*)y_t, (uint4*)xa1_t);
  // per-edge logits (MFMA)
  k_edge_mfma<<<NBLK_E, 256, 0, stream>>>(u_s, c_s, (const uint4*)xa1_t, (const uint4*)user_part,
                                          (const uint4*)a2t, att_b2, att_w3, att_b3, wlog_s);
  // softmax normalize + MFMA aggregate (out = P @ Y + w_b)
  k_smax <<<U_N/4, 256, 0, stream>>>(start, wlog_s, pval);
  k_agg  <<<(U_N/64)+1, 256, 0, stream>>>(start, u_s, c_s, pval, (const u16*)y_t, w_b, out);
}

// Round 10
// 382.658 us; speedup vs baseline: 1.2860x; 1.0379x over previous
//
#include <hip/hip_runtime.h>
#include <hip/hip_bf16.h>

#define U_N 100000
#define I_N 50000
#define E_N 2000000
#define R_N 5
#define C_N (I_N*R_N)   // 250000 combos
#define NBLK_U 391      // ceil(100000/256); NBLK_U*256 = 100096
#define NBLK_E 7813     // ceil(2000000/256)
#define NBLK_C 1954     // ceil(250000/128)
#define NBUCK 782       // ceil(100000/128) user buckets
#define SUBB 8          // sub-buckets
#define CAPB 1024       // usable capacity per (bucket,sub); mean fill 320
#define STRD 1040       // stream stride in ints: 4160B = 65 cache lines (odd) -> no L2 set aliasing

typedef __hip_bfloat16 bf16_t;
typedef unsigned short u16;
typedef __attribute__((ext_vector_type(8))) short bf16x8;
typedef __attribute__((ext_vector_type(4))) float f32x4;

__device__ __forceinline__ float blo(unsigned u){ return __uint_as_float(u<<16); }
__device__ __forceinline__ float bhi(unsigned u){ return __uint_as_float(u & 0xffff0000u); }
__device__ __forceinline__ unsigned pkbf(float a, float b){
  __hip_bfloat162 t = __float22bfloat162_rn(float2{a,b});
  union { __hip_bfloat162 h; unsigned u; } cv; cv.h = t; return cv.u;
}
__device__ __forceinline__ u16 f2b(float v){
  union { __hip_bfloat16 h; u16 u; } cv; cv.h = __float2bfloat16(v); return cv.u;
}

// ---------------- CSR build: bucketed two-pass ----------------
__global__ __launch_bounds__(256) void k_zero_tails(int* tails){
  int i = blockIdx.x*256 + threadIdx.x;
  if(i < NBUCK*SUBB) tails[i] = 0;
}

__global__ __launch_bounds__(256) void k_binA(const int* __restrict__ rows, const int* __restrict__ cols,
                                              const int* __restrict__ rats,
                                              int* __restrict__ tails, unsigned* __restrict__ uc){
  int e = blockIdx.x*256 + threadIdx.x; if(e >= E_N) return;
  int u = cols[e];
  int c = rows[e]*5 + rats[e];
  int b = u >> 7;
  int sb = b*SUBB + (blockIdx.x & 7);
  int slot = atomicAdd(tails + sb, 1);
  if(slot < CAPB) uc[(size_t)sb*STRD + slot] = ((unsigned)(u & 127) << 18) | (unsigned)c;
}

__global__ __launch_bounds__(256) void k_binB1(const int* __restrict__ tails, const unsigned* __restrict__ uc,
                                               int* __restrict__ cnt){
  __shared__ int hist[128];
  int t = threadIdx.x, b = blockIdx.x;
  if(t < 128) hist[t] = 0;
  __syncthreads();
  for(int sub=0; sub<SUBB; ++sub){
    int sb = b*SUBB + sub;
    int n = tails[sb]; if(n > CAPB) n = CAPB;
    const unsigned* p = uc + (size_t)sb*STRD;
    for(int j=t; j<n; j+=256) atomicAdd(&hist[(p[j]>>18) & 127], 1);
  }
  __syncthreads();
  if(t < 128) cnt[b*128 + t] = hist[t];
}

__global__ __launch_bounds__(256) void k_scanA(const int* __restrict__ cnt, int* __restrict__ start,
                                               int* __restrict__ bsum){
  __shared__ int s[256];
  int t = threadIdx.x, i = blockIdx.x*256 + t;
  int v = (i < U_N) ? cnt[i] : 0;
  s[t] = v; __syncthreads();
  for(int off=1; off<256; off<<=1){
    int x = (t>=off) ? s[t-off] : 0;
    __syncthreads();
    s[t] += x;
    __syncthreads();
  }
  start[i] = s[t] - v;
  if(t == 255) bsum[blockIdx.x] = s[255];
}

__global__ void k_scanB(int* bsum, int n){
  __shared__ int s[512];
  int t = threadIdx.x;
  int v = (t < n) ? bsum[t] : 0;
  s[t] = v; __syncthreads();
  for(int off=1; off<512; off<<=1){
    int x = (t>=off) ? s[t-off] : 0;
    __syncthreads();
    s[t] += x;
    __syncthreads();
  }
  if(t < n) bsum[t] = s[t] - v;
}

__global__ __launch_bounds__(256) void k_scanC(int* start, const int* __restrict__ bsum){
  int i = blockIdx.x*256 + threadIdx.x;
  start[i] += bsum[blockIdx.x];
}

__global__ __launch_bounds__(256) void k_binB2(const int* __restrict__ tails, const unsigned* __restrict__ uc,
                                               const int* __restrict__ start,
                                               int* __restrict__ u_s, int* __restrict__ c_s){
  __shared__ int fillb[128];
  __shared__ int startb[128];
  int t = threadIdx.x, b = blockIdx.x;
  if(t < 128){
    fillb[t] = 0;
    startb[t] = start[b*128 + t];
  }
  __syncthreads();
  for(int sub=0; sub<SUBB; ++sub){
    int sb = b*SUBB + sub;
    int n = tails[sb]; if(n > CAPB) n = CAPB;
    const unsigned* p = uc + (size_t)sb*STRD;
    for(int j=t; j<n; j+=256){
      unsigned v = p[j];
      int ul = (int)(v >> 18);
      int c  = (int)(v & 0x3FFFFu);
      int off = atomicAdd(&fillb[ul], 1);
      int pos = startb[ul] + off;
      u_s[pos] = (b << 7) | ul;
      c_s[pos] = c;
    }
  }
}

// ---------------- tiny precompute ----------------
__global__ void k_ratpart(const float* __restrict__ rf, const float* __restrict__ w1,
                          const float* __restrict__ b1, float* __restrict__ out){
  int t = threadIdx.x; if(t >= R_N*64) return;
  int r = t>>6, d = t&63;
  float acc = b1[d];
  for(int k=0;k<64;k++) acc += rf[r*64 + k] * w1[(64+k)*64 + d];
  out[t] = acc;
}

__global__ __launch_bounds__(256) void k_prepw6(const float* __restrict__ w1, const float* __restrict__ a1,
                                                const float* __restrict__ w2, const float* __restrict__ a2,
                                                const float* __restrict__ ww,
                                                u16* w1t, u16* u1t, u16* w2t, u16* a1t, u16* a2t, u16* wwt){
  int idx = (blockIdx.x & 15)*256 + threadIdx.x;
  int sec = blockIdx.x >> 4;
  int d = idx >> 6, k = idx & 63;
  const float* src; u16* dst; int ko = 0;
  switch(sec){
    case 0: src=w1; dst=w1t; break;
    case 1: src=a1; dst=u1t; ko=64; break;
    case 2: src=w2; dst=w2t; break;
    case 3: src=a1; dst=a1t; break;
    case 4: src=a2; dst=a2t; break;
    default: src=ww; dst=wwt; break;
  }
  dst[idx] = f2b(src[(size_t)(ko+k)*64 + d]);
}

// ---------------- MFMA row-GEMM: out[n][64](bf16) = in[n][64](f32) @ W (+bias) ----------------
template<bool BIAS>
__global__ __launch_bounds__(256) void k_rowgemm(const float4* __restrict__ in,
                                                 const uint4* __restrict__ wt,
                                                 const float* __restrict__ bias,
                                                 uint4* __restrict__ outp, int n){
  __shared__ uint4 A_u4[2048];
  __shared__ uint4 W_u4[512];
  __shared__ float bsh[64];
  u16* A16 = (u16*)A_u4;
  const int tid = threadIdx.x;
  for(int cid = tid; cid < 512; cid += 256){
    int dd = cid >> 3, ch = cid & 7;
    W_u4[dd*8 + (ch ^ (dd&7))] = wt[cid];
  }
  if(BIAS && tid < 64) bsh[tid] = bias[tid];
  const int base = blockIdx.x*256;
  const int ch = tid & 7;
#pragma unroll
  for(int it=0; it<8; ++it){
    int s = it*32 + (tid>>3);
    int r = base + s;
    uint4 o = {0,0,0,0};
    if(r < n){
      const float4* p = in + (size_t)r*16 + ch*2;
      float4 v0 = p[0], v1 = p[1];
      o.x = pkbf(v0.x, v0.y); o.y = pkbf(v0.z, v0.w);
      o.z = pkbf(v1.x, v1.y); o.w = pkbf(v1.z, v1.w);
    }
    A_u4[s*8 + (ch ^ (s&7))] = o;
  }
  __syncthreads();
  const int l = tid & 63, w = tid >> 6;
  const int lr = l & 15, g = l >> 4;
  bf16x8 bfr[4][2];
#pragma unroll
  for(int nt=0; nt<4; ++nt)
#pragma unroll
    for(int kk=0; kk<2; ++kk){
      int d = nt*16 + lr;
      bfr[nt][kk] = *(const bf16x8*)&W_u4[d*8 + ((kk*4+g) ^ (d&7))];
    }
  float bv[4];
#pragma unroll
  for(int nt=0; nt<4; ++nt) bv[nt] = BIAS ? bsh[nt*16 + lr] : 0.f;
#pragma unroll
  for(int t=0; t<4; ++t){
    int s = w*64 + t*16 + lr;
    bf16x8 af0 = *(const bf16x8*)&A_u4[s*8 + ((0*4+g) ^ (s&7))];
    bf16x8 af1 = *(const bf16x8*)&A_u4[s*8 + ((1*4+g) ^ (s&7))];
    f32x4 acc[4];
#pragma unroll
    for(int nt=0; nt<4; ++nt){
      f32x4 c0 = { bv[nt], bv[nt], bv[nt], bv[nt] };
      c0 = __builtin_amdgcn_mfma_f32_16x16x32_bf16(af0, bfr[nt][0], c0, 0, 0, 0);
      c0 = __builtin_amdgcn_mfma_f32_16x16x32_bf16(af1, bfr[nt][1], c0, 0, 0, 0);
      acc[nt] = c0;
    }
#pragma unroll
    for(int nt=0; nt<4; ++nt){
      int d = nt*16 + lr;
#pragma unroll
      for(int reg=0; reg<4; ++reg){
        int srow = w*64 + t*16 + g*4 + reg;
        A16[srow*64 + ((d>>3)^(srow&7))*8 + (d&7)] = f2b(acc[nt][reg]);
      }
    }
  }
#pragma unroll
  for(int it=0; it<8; ++it){
    int s = w*64 + it*8 + (l>>3);
    int c2 = l & 7;
    int r = base + s;
    if(r < n) outp[(size_t)r*8 + c2] = A_u4[s*8 + (c2 ^ (s&7))];
  }
}

// ---------------- combo: h1=relu(itemp+ratp); x_ia=relu(h1@W2+b2); xa1=x_ia@A1top; Y=x_ia@WW ----------------
__global__ __launch_bounds__(256) void k_combo_mfma(const uint4* __restrict__ itemp,
                                                    const float4* __restrict__ ratp,
                                                    const uint4* __restrict__ w2t_g, const uint4* __restrict__ a1t_g,
                                                    const uint4* __restrict__ wwt_g,
                                                    const float* __restrict__ b2,
                                                    uint4* __restrict__ y_o, uint4* __restrict__ xa1_o){
  __shared__ uint4 A_u4[1024];
  __shared__ uint4 X_u4[1024];
  __shared__ uint4 W2_u4[512];
  __shared__ uint4 A1_u4[512];
  __shared__ uint4 WW_u4[512];
  __shared__ float4 rsh4[80];
  __shared__ float b2sh[64];
  u16* A16 = (u16*)A_u4;
  u16* X16 = (u16*)X_u4;
  const int tid = threadIdx.x;
  for(int cid = tid; cid < 512; cid += 256){
    int dd = cid >> 3, ch = cid & 7;
    W2_u4[dd*8 + (ch ^ (dd&7))] = w2t_g[cid];
    A1_u4[dd*8 + (ch ^ (dd&7))] = a1t_g[cid];
    WW_u4[dd*8 + (ch ^ (dd&7))] = wwt_g[cid];
  }
  if(tid < 80) rsh4[tid] = ratp[tid];
  if(tid < 64) b2sh[tid] = b2[tid];
  __syncthreads();

  const int base = blockIdx.x*128;
  const int ch = tid & 7;
#pragma unroll
  for(int it=0; it<4; ++it){
    int s = it*32 + (tid>>3);
    int cidx = base + s;
    uint4 o = {0,0,0,0};
    if(cidx < C_N){
      int i = cidx/5, r = cidx - i*5;
      uint4 iv = itemp[(size_t)i*8 + ch];
      float4 r0 = rsh4[r*16 + ch*2], r1 = rsh4[r*16 + ch*2 + 1];
      o.x = pkbf(fmaxf(blo(iv.x)+r0.x,0.f), fmaxf(bhi(iv.x)+r0.y,0.f));
      o.y = pkbf(fmaxf(blo(iv.y)+r0.z,0.f), fmaxf(bhi(iv.y)+r0.w,0.f));
      o.z = pkbf(fmaxf(blo(iv.z)+r1.x,0.f), fmaxf(bhi(iv.z)+r1.y,0.f));
      o.w = pkbf(fmaxf(blo(iv.w)+r1.z,0.f), fmaxf(bhi(iv.w)+r1.w,0.f));
    }
    A_u4[s*8 + (ch ^ (s&7))] = o;
  }
  __syncthreads();

  const int l = tid & 63, w = tid >> 6;
  const int lr = l & 15, g = l >> 4;
  bf16x8 w2f[4][2], a1f[4][2], wwf[4][2];
#pragma unroll
  for(int nt=0; nt<4; ++nt)
#pragma unroll
    for(int kk=0; kk<2; ++kk){
      int d = nt*16 + lr;
      w2f[nt][kk] = *(const bf16x8*)&W2_u4[d*8 + ((kk*4+g) ^ (d&7))];
      a1f[nt][kk] = *(const bf16x8*)&A1_u4[d*8 + ((kk*4+g) ^ (d&7))];
      wwf[nt][kk] = *(const bf16x8*)&WW_u4[d*8 + ((kk*4+g) ^ (d&7))];
    }
  float b2v[4];
#pragma unroll
  for(int nt=0; nt<4; ++nt) b2v[nt] = b2sh[nt*16 + lr];

#pragma unroll
  for(int t=0; t<2; ++t){
    int s = w*32 + t*16 + lr;
    bf16x8 af0 = *(const bf16x8*)&A_u4[s*8 + ((0*4+g) ^ (s&7))];
    bf16x8 af1 = *(const bf16x8*)&A_u4[s*8 + ((1*4+g) ^ (s&7))];
    // GEMM1: x_ia
#pragma unroll
    for(int nt=0; nt<4; ++nt){
      f32x4 c0 = { b2v[nt], b2v[nt], b2v[nt], b2v[nt] };
      c0 = __builtin_amdgcn_mfma_f32_16x16x32_bf16(af0, w2f[nt][0], c0, 0, 0, 0);
      c0 = __builtin_amdgcn_mfma_f32_16x16x32_bf16(af1, w2f[nt][1], c0, 0, 0, 0);
      int d = nt*16 + lr;
#pragma unroll
      for(int reg=0; reg<4; ++reg){
        int srow = w*32 + t*16 + g*4 + reg;
        X16[srow*64 + ((d>>3)^(srow&7))*8 + (d&7)] = f2b(fmaxf(c0[reg], 0.f));
      }
    }
    bf16x8 xf0 = *(const bf16x8*)&X_u4[s*8 + ((0*4+g) ^ (s&7))];
    bf16x8 xf1 = *(const bf16x8*)&X_u4[s*8 + ((1*4+g) ^ (s&7))];
    // GEMM2: xa1 -> A16 rows (h1 dead)
#pragma unroll
    for(int nt=0; nt<4; ++nt){
      f32x4 c0 = { 0.f, 0.f, 0.f, 0.f };
      c0 = __builtin_amdgcn_mfma_f32_16x16x32_bf16(xf0, a1f[nt][0], c0, 0, 0, 0);
      c0 = __builtin_amdgcn_mfma_f32_16x16x32_bf16(xf1, a1f[nt][1], c0, 0, 0, 0);
      int d = nt*16 + lr;
#pragma unroll
      for(int reg=0; reg<4; ++reg){
        int srow = w*32 + t*16 + g*4 + reg;
        A16[srow*64 + ((d>>3)^(srow&7))*8 + (d&7)] = f2b(c0[reg]);
      }
    }
    // GEMM3: Y = x_ia @ WW -> X16 rows (x_ia consumed)
#pragma unroll
    for(int nt=0; nt<4; ++nt){
      f32x4 c0 = { 0.f, 0.f, 0.f, 0.f };
      c0 = __builtin_amdgcn_mfma_f32_16x16x32_bf16(xf0, wwf[nt][0], c0, 0, 0, 0);
      c0 = __builtin_amdgcn_mfma_f32_16x16x32_bf16(xf1, wwf[nt][1], c0, 0, 0, 0);
      int d = nt*16 + lr;
#pragma unroll
      for(int reg=0; reg<4; ++reg){
        int srow = w*32 + t*16 + g*4 + reg;
        X16[srow*64 + ((d>>3)^(srow&7))*8 + (d&7)] = f2b(c0[reg]);
      }
    }
  }
#pragma unroll
  for(int it=0; it<4; ++it){
    int s = w*32 + it*8 + (l>>3);
    int c2 = l & 7;
    int r = base + s;
    if(r < C_N){
      y_o  [(size_t)r*8 + c2] = X_u4[s*8 + (c2 ^ (s&7))];
      xa1_o[(size_t)r*8 + c2] = A_u4[s*8 + (c2 ^ (s&7))];
    }
  }
}

// ---------------- MFMA edge-logit kernel (LDS = A-tile only -> 5 blocks/CU) ----------------
__global__ __launch_bounds__(256) void k_edge_mfma(const int* __restrict__ u_s, const int* __restrict__ c_s,
                                                   const uint4* __restrict__ xa1p, const uint4* __restrict__ userp,
                                                   const u16* __restrict__ w2t_g,
                                                   const float* __restrict__ a2b,
                                                   const float* __restrict__ a3w, const float* __restrict__ a3b,
                                                   float* __restrict__ wlog){
  __shared__ uint4 A_u4[2048];    // 32 KB, the only LDS
  const int tid = threadIdx.x;
  const int base = blockIdx.x*256;
  const int ch = tid & 7;
#pragma unroll
  for(int it=0; it<8; ++it){
    int s = it*32 + (tid>>3);
    int e = base + s;
    uint4 xv = {0,0,0,0}, uv = {0,0,0,0};
    if(e < E_N){
      int c = c_s[e], u = u_s[e];
      xv = xa1p[(size_t)c*8 + ch];
      uv = userp[(size_t)u*8 + ch];
    }
    uint4 o;
    o.x = pkbf(fmaxf(blo(xv.x)+blo(uv.x),0.f), fmaxf(bhi(xv.x)+bhi(uv.x),0.f));
    o.y = pkbf(fmaxf(blo(xv.y)+blo(uv.y),0.f), fmaxf(bhi(xv.y)+bhi(uv.y),0.f));
    o.z = pkbf(fmaxf(blo(xv.z)+blo(uv.z),0.f), fmaxf(bhi(xv.z)+bhi(uv.z),0.f));
    o.w = pkbf(fmaxf(blo(xv.w)+blo(uv.w),0.f), fmaxf(bhi(xv.w)+bhi(uv.w),0.f));
    A_u4[s*8 + (ch ^ (s&7))] = o;
  }
  const int l = tid & 63, w = tid >> 6;
  const int lr = l & 15;
  const int g  = l >> 4;
  // B-frags + biases straight from global (8KB table, L1-resident after first wave)
  bf16x8 bf[4][2];
#pragma unroll
  for(int nt=0; nt<4; ++nt)
#pragma unroll
    for(int kk=0; kk<2; ++kk){
      int d = nt*16 + lr;
      bf[nt][kk] = *(const bf16x8*)(w2t_g + d*64 + kk*32 + g*8);
    }
  float b2v[4], a3v[4];
#pragma unroll
  for(int nt=0; nt<4; ++nt){ b2v[nt] = a2b[nt*16 + lr]; a3v[nt] = a3w[nt*16 + lr]; }
  const float a3b0 = a3b[0];
  __syncthreads();
#pragma unroll
  for(int t=0; t<4; ++t){
    int s = w*64 + t*16 + lr;
    bf16x8 af0 = *(const bf16x8*)&A_u4[s*8 + ((0*4 + g) ^ (s&7))];
    bf16x8 af1 = *(const bf16x8*)&A_u4[s*8 + ((1*4 + g) ^ (s&7))];
    f32x4 acc[4];
#pragma unroll
    for(int nt=0; nt<4; ++nt){
      f32x4 c0 = { b2v[nt], b2v[nt], b2v[nt], b2v[nt] };
      c0 = __builtin_amdgcn_mfma_f32_16x16x32_bf16(af0, bf[nt][0], c0, 0, 0, 0);
      c0 = __builtin_amdgcn_mfma_f32_16x16x32_bf16(af1, bf[nt][1], c0, 0, 0, 0);
      acc[nt] = c0;
    }
    float s0=0.f, s1=0.f, s2=0.f, s3=0.f;
#pragma unroll
    for(int nt=0; nt<4; ++nt){
      s0 += fmaxf(acc[nt][0], 0.f) * a3v[nt];
      s1 += fmaxf(acc[nt][1], 0.f) * a3v[nt];
      s2 += fmaxf(acc[nt][2], 0.f) * a3v[nt];
      s3 += fmaxf(acc[nt][3], 0.f) * a3v[nt];
    }
#pragma unroll
    for(int mask=1; mask<16; mask<<=1){
      s0 += __shfl_xor(s0, mask);
      s1 += __shfl_xor(s1, mask);
      s2 += __shfl_xor(s2, mask);
      s3 += __shfl_xor(s3, mask);
    }
    if(lr == 0){
      int e0 = base + w*64 + t*16 + g*4;
      if(e0+0 < E_N) wlog[e0+0] = s0 + a3b0;
      if(e0+1 < E_N) wlog[e0+1] = s1 + a3b0;
      if(e0+2 < E_N) wlog[e0+2] = s2 + a3b0;
      if(e0+3 < E_N) wlog[e0+3] = s3 + a3b0;
    }
  }
}

// ---------------- softmax normalize: pval[e] = bf16(exp(wlog-m)/sum) ----------------
__global__ __launch_bounds__(256) void k_smax(const int* __restrict__ start,
                                              const float* __restrict__ wlog,
                                              u16* __restrict__ pval){
  int w = threadIdx.x >> 6, lane = threadIdx.x & 63;
  int u = blockIdx.x*4 + w;
  int s0 = start[u], n = start[u+1] - s0;
  int nq = (n + 63) >> 6;
  float tq[4];
  float m = -1e30f;
  for(int q=0; q<nq; ++q){
    int j = q*64 + lane;
    float t = (j<n) ? wlog[s0+j] : -1e30f;
    if(q<4) tq[q] = t;
    m = fmaxf(m, t);
  }
#pragma unroll
  for(int off=32; off>=1; off>>=1) m = fmaxf(m, __shfl_xor(m, off));
  float ssum = 0.f;
  for(int q=0; q<nq; ++q){
    int j = q*64 + lane;
    float t = (q<4) ? tq[q] : ((j<n) ? wlog[s0+j] : -1e30f);
    float e = (j<n) ? __expf(t - m) : 0.f;
    if(q<4) tq[q] = e;
    ssum += e;
  }
#pragma unroll
  for(int off=32; off>=1; off>>=1) ssum += __shfl_xor(ssum, off);
  float inv = (n>0) ? (1.f/ssum) : 0.f;
  for(int q=0; q<nq; ++q){
    int j = q*64 + lane;
    float e = (q<4) ? tq[q] : ((j<n) ? __expf(wlog[s0+j] - m) : 0.f);
    if(j<n) pval[s0+j] = f2b(e * inv);
  }
}

// ---------------- MFMA aggregate: out[16 users][64] = P-mask @ Y-rows + w_b ----------------
__global__ __launch_bounds__(256) void k_agg(const int* __restrict__ start,
                                             const int* __restrict__ u_s, const int* __restrict__ c_s,
                                             const u16* __restrict__ pval,
                                             const u16* __restrict__ Y,
                                             const float* __restrict__ wb,
                                             float* __restrict__ out){
  int w = threadIdx.x >> 6, l = threadIdx.x & 63;
  int lr = l & 15, g = l >> 4;
  int base = (blockIdx.x*4 + w) * 16;
  if(base >= U_N) return;
  int s0g = start[base];
  int s1g = start[base+16];
  int myu = base + lr;
  float wbv[4];
#pragma unroll
  for(int nt=0; nt<4; ++nt) wbv[nt] = wb[nt*16 + lr];
  f32x4 acc[4];
#pragma unroll
  for(int nt=0; nt<4; ++nt) acc[nt] = f32x4{ wbv[nt], wbv[nt], wbv[nt], wbv[nt] };

  int sA = s0g & ~31;
  int nch = (s1g - sA + 31) >> 5;
  for(int ch=0; ch<nch; ++ch){
    int e0 = sA + ch*32;
    int kb = g*8;
    bf16x8 pv = *(const bf16x8*)(pval + e0 + kb);
    int4 u0 = *(const int4*)(u_s + e0 + kb);
    int4 u1 = *(const int4*)(u_s + e0 + kb + 4);
    int4 cA = *(const int4*)(c_s + e0 + kb);
    int4 cB = *(const int4*)(c_s + e0 + kb + 4);
    bf16x8 af;
    af[0] = (u0.x == myu) ? pv[0] : (short)0;
    af[1] = (u0.y == myu) ? pv[1] : (short)0;
    af[2] = (u0.z == myu) ? pv[2] : (short)0;
    af[3] = (u0.w == myu) ? pv[3] : (short)0;
    af[4] = (u1.x == myu) ? pv[4] : (short)0;
    af[5] = (u1.y == myu) ? pv[5] : (short)0;
    af[6] = (u1.z == myu) ? pv[6] : (short)0;
    af[7] = (u1.w == myu) ? pv[7] : (short)0;
    int cj[8] = {cA.x, cA.y, cA.z, cA.w, cB.x, cB.y, cB.z, cB.w};
    bf16x8 b0, b1, b2, b3;
#pragma unroll
    for(int j=0; j<8; ++j){
      const u16* yr = Y + (size_t)cj[j]*64 + lr;
      b0[j] = (short)yr[0];
      b1[j] = (short)yr[16];
      b2[j] = (short)yr[32];
      b3[j] = (short)yr[48];
    }
    acc[0] = __builtin_amdgcn_mfma_f32_16x16x32_bf16(af, b0, acc[0], 0, 0, 0);
    acc[1] = __builtin_amdgcn_mfma_f32_16x16x32_bf16(af, b1, acc[1], 0, 0, 0);
    acc[2] = __builtin_amdgcn_mfma_f32_16x16x32_bf16(af, b2, acc[2], 0, 0, 0);
    acc[3] = __builtin_amdgcn_mfma_f32_16x16x32_bf16(af, b3, acc[3], 0, 0, 0);
  }
#pragma unroll
  for(int nt=0; nt<4; ++nt){
#pragma unroll
    for(int reg=0; reg<4; ++reg){
      int u = base + g*4 + reg;
      out[(size_t)u*64 + nt*16 + lr] = acc[nt][reg];
    }
  }
}

extern "C" void kernel_launch(void* const* d_in, const int* in_sizes, int n_in,
                              void* d_out, int out_size, void* d_ws, size_t ws_size,
                              hipStream_t stream){
  (void)in_sizes; (void)n_in; (void)out_size; (void)ws_size;
  const float4* user_feat  = (const float4*)d_in[0];
  const float4* item_feat  = (const float4*)d_in[1];
  const float*  rating_feat= (const float*)d_in[2];
  const int*    rows       = (const int*)d_in[3];
  const int*    cols       = (const int*)d_in[4];
  const int*    rats       = (const int*)d_in[5];
  const float* gv_w1 = (const float*)d_in[6];
  const float* gv_b1 = (const float*)d_in[7];
  const float* gv_w2 = (const float*)d_in[8];
  const float* gv_b2 = (const float*)d_in[9];
  const float* att_w1= (const float*)d_in[10];
  const float* att_b1= (const float*)d_in[11];
  const float* att_w2= (const float*)d_in[12];
  const float* att_b2= (const float*)d_in[13];
  const float* att_w3= (const float*)d_in[14];
  const float* att_b3= (const float*)d_in[15];
  const float* w_w   = (const float*)d_in[16];
  const float* w_b   = (const float*)d_in[17];
  float* out = (float*)d_out;

  char* ws = (char*)d_ws; size_t off = 0;
  auto take = [&](size_t b)->char*{ char* p = ws + off; off = (off + b + 255) & ~(size_t)255; return p; };
  bf16_t* item_part  = (bf16_t*)take((size_t)I_N*64*2);       // 6.4 MB
  bf16_t* user_part  = (bf16_t*)take((size_t)U_N*64*2);       // 12.8 MB
  float*  rating_part= (float*) take((size_t)R_N*64*4);
  bf16_t* y_t        = (bf16_t*)take((size_t)C_N*64*2);       // 32 MB  (Y = x_ia @ w_w)
  bf16_t* xa1_t      = (bf16_t*)take((size_t)C_N*64*2);       // 32 MB
  float*  wlog_s     = (float*) take((size_t)E_N*4);          // 8 MB
  int*    c_s        = (int*)   take((size_t)E_N*4);          // 8 MB
  int*    u_s        = (int*)   take((size_t)E_N*4);          // 8 MB
  u16*    pval       = (u16*)   take((size_t)E_N*2);          // 4 MB
  unsigned* uc       = (unsigned*)take((size_t)NBUCK*SUBB*STRD*4); // 26 MB
  int*    tails      = (int*)   take((size_t)NBUCK*SUBB*4);
  int*    cnt        = (int*)   take((size_t)(NBLK_U*256)*4);
  int*    start      = (int*)   take((size_t)(NBLK_U*256)*4);
  int*    bsum       = (int*)   take((size_t)512*4);
  u16*    w1t        = (u16*)   take((size_t)4096*2);
  u16*    u1t        = (u16*)   take((size_t)4096*2);
  u16*    w2t        = (u16*)   take((size_t)4096*2);
  u16*    a1t        = (u16*)   take((size_t)4096*2);
  u16*    a2t        = (u16*)   take((size_t)4096*2);
  u16*    wwt        = (u16*)   take((size_t)4096*2);

  // CSR build (bucketed, set-aliasing-free streams)
  k_zero_tails<<<(NBUCK*SUBB+255)/256, 256, 0, stream>>>(tails);
  k_binA <<<NBLK_E, 256, 0, stream>>>(rows, cols, rats, tails, uc);
  k_binB1<<<NBUCK, 256, 0, stream>>>(tails, uc, cnt);
  k_scanA<<<NBLK_U, 256, 0, stream>>>(cnt, start, bsum);
  k_scanB<<<1, 512, 0, stream>>>(bsum, NBLK_U);
  k_scanC<<<NBLK_U, 256, 0, stream>>>(start, bsum);
  k_binB2<<<NBUCK, 256, 0, stream>>>(tails, uc, start, u_s, c_s);
  // weights + tiny GEMV
  k_ratpart <<<1, 320, 0, stream>>>(rating_feat, gv_w1, gv_b1, rating_part);
  k_prepw6  <<<96, 256, 0, stream>>>(gv_w1, att_w1, gv_w2, att_w2, w_w, w1t, u1t, w2t, a1t, a2t, wwt);
  // dense precompute (MFMA)
  k_rowgemm<false><<<(I_N+255)/256, 256, 0, stream>>>(item_feat, (const uint4*)w1t, nullptr,
                                                      (uint4*)item_part, I_N);
  k_rowgemm<true> <<<NBLK_U, 256, 0, stream>>>(user_feat, (const uint4*)u1t, att_b1,
                                               (uint4*)user_part, U_N);
  k_combo_mfma<<<NBLK_C, 256, 0, stream>>>((const uint4*)item_part, (const float4*)rating_part,
                                           (const uint4*)w2t, (const uint4*)a1t, (const uint4*)wwt, gv_b2,
                                           (uint4*)y_t, (uint4*)xa1_t);
  // per-edge logits (MFMA, low-LDS)
  k_edge_mfma<<<NBLK_E, 256, 0, stream>>>(u_s, c_s, (const uint4*)xa1_t, (const uint4*)user_part,
                                          w2t, att_b2, att_w3, att_b3, wlog_s);
  // softmax normalize + MFMA aggregate (out = P @ Y + w_b)
  k_smax <<<U_N/4, 256, 0, stream>>>(start, wlog_s, pval);
  k_agg  <<<(U_N/64)+1, 256, 0, stream>>>(start, u_s, c_s, pval, (const u16*)y_t, w_b, out);
}

// Round 11
// 369.183 us; speedup vs baseline: 1.3329x; 1.0365x over previous
//
#include <hip/hip_runtime.h>
#include <hip/hip_bf16.h>

#define U_N 100000
#define I_N 50000
#define E_N 2000000
#define R_N 5
#define C_N (I_N*R_N)   // 250000 combos
#define NBLK_U 391      // ceil(100000/256); NBLK_U*256 = 100096
#define NBLK_E 7813     // ceil(2000000/256)
#define NBLK_C 1954     // ceil(250000/128)
#define NBUCKC 196      // ceil(100000/512) coarse buckets (512 users each)

typedef __hip_bfloat16 bf16_t;
typedef unsigned short u16;
typedef unsigned char u8;
typedef __attribute__((ext_vector_type(8))) short bf16x8;
typedef __attribute__((ext_vector_type(4))) float f32x4;

__device__ __forceinline__ float blo(unsigned u){ return __uint_as_float(u<<16); }
__device__ __forceinline__ float bhi(unsigned u){ return __uint_as_float(u & 0xffff0000u); }
__device__ __forceinline__ unsigned pkbf(float a, float b){
  __hip_bfloat162 t = __float22bfloat162_rn(float2{a,b});
  union { __hip_bfloat162 h; unsigned u; } cv; cv.h = t; return cv.u;
}
__device__ __forceinline__ u16 f2b(float v){
  union { __hip_bfloat16 h; u16 u; } cv; cv.h = __float2bfloat16(v); return cv.u;
}

// ================= CSR build: atomic-free two-level counting sort =================
// pass A: block-local counting sort by coarse bucket q=u>>9; coalesced run write + histogram
__global__ __launch_bounds__(256) void k_sortA(const int* __restrict__ rows, const int* __restrict__ cols,
                                               const int* __restrict__ rats,
                                               unsigned* __restrict__ ucs, u8* __restrict__ qarr,
                                               int* __restrict__ hist_g){
  __shared__ int histI[NBUCKC];
  __shared__ int s[256];
  __shared__ int rs[NBUCKC];
  int t = threadIdx.x, b = blockIdx.x;
  if(t < NBUCKC) histI[t] = 0;
  __syncthreads();
  int e = b*256 + t;
  int q = 0, rank = 0; unsigned pv = 0;
  bool valid = (e < E_N);
  if(valid){
    int u = cols[e];
    int c = rows[e]*5 + rats[e];
    q = u >> 9;
    pv = ((unsigned)(u & 511) << 18) | (unsigned)c;
    rank = atomicAdd(&histI[q], 1);
  }
  __syncthreads();
  int v = (t < NBUCKC) ? histI[t] : 0;
  s[t] = v; __syncthreads();
  for(int off=1; off<256; off<<=1){
    int x = (t>=off) ? s[t-off] : 0;
    __syncthreads();
    s[t] += x;
    __syncthreads();
  }
  if(t < NBUCKC){
    rs[t] = s[t] - v;                      // exclusive run start
    hist_g[(size_t)b*NBUCKC + t] = v;      // coalesced histogram write
  }
  __syncthreads();
  if(valid){
    int dst = rs[q] + rank;
    ucs [b*256 + dst] = pv;
    qarr[b*256 + dst] = (u8)q;
  }
}

// per-bucket scan over blocks: boff[b][q] = prefix of hist over blocks; qtot[q] = total
__global__ __launch_bounds__(256) void k_scanQ(const int* __restrict__ hist_g, int* __restrict__ boff_g,
                                               int* __restrict__ qtot){
  __shared__ int s[256];
  int t = threadIdx.x, q = blockIdx.x;
  int running = 0;
  for(int c0=0; c0<NBLK_E; c0+=256){
    int b = c0 + t;
    int v = (b < NBLK_E) ? hist_g[(size_t)b*NBUCKC + q] : 0;
    s[t] = v; __syncthreads();
    for(int off=1; off<256; off<<=1){
      int x = (t>=off) ? s[t-off] : 0;
      __syncthreads();
      s[t] += x;
      __syncthreads();
    }
    if(b < NBLK_E) boff_g[(size_t)b*NBUCKC + q] = running + s[t] - v;
    running += s[255];
    __syncthreads();
  }
  if(t == 0) qtot[q] = running;
}

__global__ void k_scanT(const int* __restrict__ qtot, int* __restrict__ qbase){
  __shared__ int s[256];
  int t = threadIdx.x;
  int v = (t < NBUCKC) ? qtot[t] : 0;
  s[t] = v; __syncthreads();
  for(int off=1; off<256; off<<=1){
    int x = (t>=off) ? s[t-off] : 0;
    __syncthreads();
    s[t] += x;
    __syncthreads();
  }
  if(t < NBUCKC) qbase[t] = s[t] - v;
  if(t == 255)   qbase[NBUCKC] = s[255];   // == E_N
}

// deterministic placement into bucket-sorted uc2 (no atomics)
__global__ __launch_bounds__(256) void k_place2(const unsigned* __restrict__ ucs, const u8* __restrict__ qarr,
                                                const int* __restrict__ hist_g, const int* __restrict__ boff_g,
                                                const int* __restrict__ qbase,
                                                unsigned* __restrict__ uc2){
  __shared__ int s[256];
  __shared__ int rs[NBUCKC];
  __shared__ int bsh[NBUCKC];
  __shared__ int qb[NBUCKC];
  int t = threadIdx.x, b = blockIdx.x;
  int v = (t < NBUCKC) ? hist_g[(size_t)b*NBUCKC + t] : 0;
  if(t < NBUCKC){
    bsh[t] = boff_g[(size_t)b*NBUCKC + t];
    qb[t]  = qbase[t];
  }
  s[t] = v; __syncthreads();
  for(int off=1; off<256; off<<=1){
    int x = (t>=off) ? s[t-off] : 0;
    __syncthreads();
    s[t] += x;
    __syncthreads();
  }
  if(t < NBUCKC) rs[t] = s[t] - v;
  __syncthreads();
  int nvalid = E_N - b*256; if(nvalid > 256) nvalid = 256;
  if(t < nvalid){
    unsigned pv = ucs[b*256 + t];
    int q = (int)qarr[b*256 + t];
    int dst = qb[q] + bsh[q] + (t - rs[q]);
    uc2[dst] = pv;
  }
}

// per-bucket fine histogram (512 users) -> cnt
__global__ __launch_bounds__(256) void k_fineB1(const unsigned* __restrict__ uc2, const int* __restrict__ qbase,
                                                int* __restrict__ cnt){
  __shared__ int hist[512];
  int t = threadIdx.x, q = blockIdx.x;
  hist[t] = 0; hist[t+256] = 0;
  __syncthreads();
  int r0 = qbase[q], r1 = qbase[q+1];
  for(int j=r0+t; j<r1; j+=256) atomicAdd(&hist[(uc2[j]>>18) & 511], 1);
  __syncthreads();
  cnt[q*512 + t]       = hist[t];
  cnt[q*512 + t + 256] = hist[t+256];
}

__global__ __launch_bounds__(256) void k_scanA(const int* __restrict__ cnt, int* __restrict__ start,
                                               int* __restrict__ bsum){
  __shared__ int s[256];
  int t = threadIdx.x, i = blockIdx.x*256 + t;
  int v = (i < U_N) ? cnt[i] : 0;
  s[t] = v; __syncthreads();
  for(int off=1; off<256; off<<=1){
    int x = (t>=off) ? s[t-off] : 0;
    __syncthreads();
    s[t] += x;
    __syncthreads();
  }
  start[i] = s[t] - v;
  if(t == 255) bsum[blockIdx.x] = s[255];
}

__global__ void k_scanB(int* bsum, int n){
  __shared__ int s[512];
  int t = threadIdx.x;
  int v = (t < n) ? bsum[t] : 0;
  s[t] = v; __syncthreads();
  for(int off=1; off<512; off<<=1){
    int x = (t>=off) ? s[t-off] : 0;
    __syncthreads();
    s[t] += x;
    __syncthreads();
  }
  if(t < n) bsum[t] = s[t] - v;
}

__global__ __launch_bounds__(256) void k_scanC(int* start, const int* __restrict__ bsum){
  int i = blockIdx.x*256 + threadIdx.x;
  start[i] += bsum[blockIdx.x];
}

// per-bucket placement into per-user CSR (LDS fill counters; windows are L2-resident)
__global__ __launch_bounds__(256) void k_fineB2(const unsigned* __restrict__ uc2, const int* __restrict__ qbase,
                                                const int* __restrict__ start,
                                                int* __restrict__ u_s, int* __restrict__ c_s){
  __shared__ int fillb[512];
  __shared__ int startb[512];
  int t = threadIdx.x, q = blockIdx.x;
  fillb[t] = 0; fillb[t+256] = 0;
  startb[t]     = start[q*512 + t];
  startb[t+256] = start[q*512 + t + 256];
  __syncthreads();
  int r0 = qbase[q], r1 = qbase[q+1];
  for(int j=r0+t; j<r1; j+=256){
    unsigned v = uc2[j];
    int ul = (int)((v>>18) & 511);
    int off = atomicAdd(&fillb[ul], 1);
    int pos = startb[ul] + off;
    u_s[pos] = (q<<9) | ul;
    c_s[pos] = (int)(v & 0x3FFFFu);
  }
}

// ---------------- tiny precompute ----------------
__global__ void k_ratpart(const float* __restrict__ rf, const float* __restrict__ w1,
                          const float* __restrict__ b1, float* __restrict__ out){
  int t = threadIdx.x; if(t >= R_N*64) return;
  int r = t>>6, d = t&63;
  float acc = b1[d];
  for(int k=0;k<64;k++) acc += rf[r*64 + k] * w1[(64+k)*64 + d];
  out[t] = acc;
}

__global__ __launch_bounds__(256) void k_prepw6(const float* __restrict__ w1, const float* __restrict__ a1,
                                                const float* __restrict__ w2, const float* __restrict__ a2,
                                                const float* __restrict__ ww,
                                                u16* w1t, u16* u1t, u16* w2t, u16* a1t, u16* a2t, u16* wwt){
  int idx = (blockIdx.x & 15)*256 + threadIdx.x;
  int sec = blockIdx.x >> 4;
  int d = idx >> 6, k = idx & 63;
  const float* src; u16* dst; int ko = 0;
  switch(sec){
    case 0: src=w1; dst=w1t; break;
    case 1: src=a1; dst=u1t; ko=64; break;
    case 2: src=w2; dst=w2t; break;
    case 3: src=a1; dst=a1t; break;
    case 4: src=a2; dst=a2t; break;
    default: src=ww; dst=wwt; break;
  }
  dst[idx] = f2b(src[(size_t)(ko+k)*64 + d]);
}

// ---------------- MFMA row-GEMM ----------------
template<bool BIAS>
__global__ __launch_bounds__(256) void k_rowgemm(const float4* __restrict__ in,
                                                 const uint4* __restrict__ wt,
                                                 const float* __restrict__ bias,
                                                 uint4* __restrict__ outp, int n){
  __shared__ uint4 A_u4[2048];
  __shared__ uint4 W_u4[512];
  __shared__ float bsh[64];
  u16* A16 = (u16*)A_u4;
  const int tid = threadIdx.x;
  for(int cid = tid; cid < 512; cid += 256){
    int dd = cid >> 3, ch = cid & 7;
    W_u4[dd*8 + (ch ^ (dd&7))] = wt[cid];
  }
  if(BIAS && tid < 64) bsh[tid] = bias[tid];
  const int base = blockIdx.x*256;
  const int ch = tid & 7;
#pragma unroll
  for(int it=0; it<8; ++it){
    int s = it*32 + (tid>>3);
    int r = base + s;
    uint4 o = {0,0,0,0};
    if(r < n){
      const float4* p = in + (size_t)r*16 + ch*2;
      float4 v0 = p[0], v1 = p[1];
      o.x = pkbf(v0.x, v0.y); o.y = pkbf(v0.z, v0.w);
      o.z = pkbf(v1.x, v1.y); o.w = pkbf(v1.z, v1.w);
    }
    A_u4[s*8 + (ch ^ (s&7))] = o;
  }
  __syncthreads();
  const int l = tid & 63, w = tid >> 6;
  const int lr = l & 15, g = l >> 4;
  bf16x8 bfr[4][2];
#pragma unroll
  for(int nt=0; nt<4; ++nt)
#pragma unroll
    for(int kk=0; kk<2; ++kk){
      int d = nt*16 + lr;
      bfr[nt][kk] = *(const bf16x8*)&W_u4[d*8 + ((kk*4+g) ^ (d&7))];
    }
  float bv[4];
#pragma unroll
  for(int nt=0; nt<4; ++nt) bv[nt] = BIAS ? bsh[nt*16 + lr] : 0.f;
#pragma unroll
  for(int t=0; t<4; ++t){
    int s = w*64 + t*16 + lr;
    bf16x8 af0 = *(const bf16x8*)&A_u4[s*8 + ((0*4+g) ^ (s&7))];
    bf16x8 af1 = *(const bf16x8*)&A_u4[s*8 + ((1*4+g) ^ (s&7))];
    f32x4 acc[4];
#pragma unroll
    for(int nt=0; nt<4; ++nt){
      f32x4 c0 = { bv[nt], bv[nt], bv[nt], bv[nt] };
      c0 = __builtin_amdgcn_mfma_f32_16x16x32_bf16(af0, bfr[nt][0], c0, 0, 0, 0);
      c0 = __builtin_amdgcn_mfma_f32_16x16x32_bf16(af1, bfr[nt][1], c0, 0, 0, 0);
      acc[nt] = c0;
    }
#pragma unroll
    for(int nt=0; nt<4; ++nt){
      int d = nt*16 + lr;
#pragma unroll
      for(int reg=0; reg<4; ++reg){
        int srow = w*64 + t*16 + g*4 + reg;
        A16[srow*64 + ((d>>3)^(srow&7))*8 + (d&7)] = f2b(acc[nt][reg]);
      }
    }
  }
#pragma unroll
  for(int it=0; it<8; ++it){
    int s = w*64 + it*8 + (l>>3);
    int c2 = l & 7;
    int r = base + s;
    if(r < n) outp[(size_t)r*8 + c2] = A_u4[s*8 + (c2 ^ (s&7))];
  }
}

// ---------------- combo ----------------
__global__ __launch_bounds__(256) void k_combo_mfma(const uint4* __restrict__ itemp,
                                                    const float4* __restrict__ ratp,
                                                    const uint4* __restrict__ w2t_g, const uint4* __restrict__ a1t_g,
                                                    const uint4* __restrict__ wwt_g,
                                                    const float* __restrict__ b2,
                                                    uint4* __restrict__ y_o, uint4* __restrict__ xa1_o){
  __shared__ uint4 A_u4[1024];
  __shared__ uint4 X_u4[1024];
  __shared__ uint4 W2_u4[512];
  __shared__ uint4 A1_u4[512];
  __shared__ uint4 WW_u4[512];
  __shared__ float4 rsh4[80];
  __shared__ float b2sh[64];
  u16* A16 = (u16*)A_u4;
  u16* X16 = (u16*)X_u4;
  const int tid = threadIdx.x;
  for(int cid = tid; cid < 512; cid += 256){
    int dd = cid >> 3, ch = cid & 7;
    W2_u4[dd*8 + (ch ^ (dd&7))] = w2t_g[cid];
    A1_u4[dd*8 + (ch ^ (dd&7))] = a1t_g[cid];
    WW_u4[dd*8 + (ch ^ (dd&7))] = wwt_g[cid];
  }
  if(tid < 80) rsh4[tid] = ratp[tid];
  if(tid < 64) b2sh[tid] = b2[tid];
  __syncthreads();

  const int base = blockIdx.x*128;
  const int ch = tid & 7;
#pragma unroll
  for(int it=0; it<4; ++it){
    int s = it*32 + (tid>>3);
    int cidx = base + s;
    uint4 o = {0,0,0,0};
    if(cidx < C_N){
      int i = cidx/5, r = cidx - i*5;
      uint4 iv = itemp[(size_t)i*8 + ch];
      float4 r0 = rsh4[r*16 + ch*2], r1 = rsh4[r*16 + ch*2 + 1];
      o.x = pkbf(fmaxf(blo(iv.x)+r0.x,0.f), fmaxf(bhi(iv.x)+r0.y,0.f));
      o.y = pkbf(fmaxf(blo(iv.y)+r0.z,0.f), fmaxf(bhi(iv.y)+r0.w,0.f));
      o.z = pkbf(fmaxf(blo(iv.z)+r1.x,0.f), fmaxf(bhi(iv.z)+r1.y,0.f));
      o.w = pkbf(fmaxf(blo(iv.w)+r1.z,0.f), fmaxf(bhi(iv.w)+r1.w,0.f));
    }
    A_u4[s*8 + (ch ^ (s&7))] = o;
  }
  __syncthreads();

  const int l = tid & 63, w = tid >> 6;
  const int lr = l & 15, g = l >> 4;
  bf16x8 w2f[4][2], a1f[4][2], wwf[4][2];
#pragma unroll
  for(int nt=0; nt<4; ++nt)
#pragma unroll
    for(int kk=0; kk<2; ++kk){
      int d = nt*16 + lr;
      w2f[nt][kk] = *(const bf16x8*)&W2_u4[d*8 + ((kk*4+g) ^ (d&7))];
      a1f[nt][kk] = *(const bf16x8*)&A1_u4[d*8 + ((kk*4+g) ^ (d&7))];
      wwf[nt][kk] = *(const bf16x8*)&WW_u4[d*8 + ((kk*4+g) ^ (d&7))];
    }
  float b2v[4];
#pragma unroll
  for(int nt=0; nt<4; ++nt) b2v[nt] = b2sh[nt*16 + lr];

#pragma unroll
  for(int t=0; t<2; ++t){
    int s = w*32 + t*16 + lr;
    bf16x8 af0 = *(const bf16x8*)&A_u4[s*8 + ((0*4+g) ^ (s&7))];
    bf16x8 af1 = *(const bf16x8*)&A_u4[s*8 + ((1*4+g) ^ (s&7))];
#pragma unroll
    for(int nt=0; nt<4; ++nt){
      f32x4 c0 = { b2v[nt], b2v[nt], b2v[nt], b2v[nt] };
      c0 = __builtin_amdgcn_mfma_f32_16x16x32_bf16(af0, w2f[nt][0], c0, 0, 0, 0);
      c0 = __builtin_amdgcn_mfma_f32_16x16x32_bf16(af1, w2f[nt][1], c0, 0, 0, 0);
      int d = nt*16 + lr;
#pragma unroll
      for(int reg=0; reg<4; ++reg){
        int srow = w*32 + t*16 + g*4 + reg;
        X16[srow*64 + ((d>>3)^(srow&7))*8 + (d&7)] = f2b(fmaxf(c0[reg], 0.f));
      }
    }
    bf16x8 xf0 = *(const bf16x8*)&X_u4[s*8 + ((0*4+g) ^ (s&7))];
    bf16x8 xf1 = *(const bf16x8*)&X_u4[s*8 + ((1*4+g) ^ (s&7))];
#pragma unroll
    for(int nt=0; nt<4; ++nt){
      f32x4 c0 = { 0.f, 0.f, 0.f, 0.f };
      c0 = __builtin_amdgcn_mfma_f32_16x16x32_bf16(xf0, a1f[nt][0], c0, 0, 0, 0);
      c0 = __builtin_amdgcn_mfma_f32_16x16x32_bf16(xf1, a1f[nt][1], c0, 0, 0, 0);
      int d = nt*16 + lr;
#pragma unroll
      for(int reg=0; reg<4; ++reg){
        int srow = w*32 + t*16 + g*4 + reg;
        A16[srow*64 + ((d>>3)^(srow&7))*8 + (d&7)] = f2b(c0[reg]);
      }
    }
#pragma unroll
    for(int nt=0; nt<4; ++nt){
      f32x4 c0 = { 0.f, 0.f, 0.f, 0.f };
      c0 = __builtin_amdgcn_mfma_f32_16x16x32_bf16(xf0, wwf[nt][0], c0, 0, 0, 0);
      c0 = __builtin_amdgcn_mfma_f32_16x16x32_bf16(xf1, wwf[nt][1], c0, 0, 0, 0);
      int d = nt*16 + lr;
#pragma unroll
      for(int reg=0; reg<4; ++reg){
        int srow = w*32 + t*16 + g*4 + reg;
        X16[srow*64 + ((d>>3)^(srow&7))*8 + (d&7)] = f2b(c0[reg]);
      }
    }
  }
#pragma unroll
  for(int it=0; it<4; ++it){
    int s = w*32 + it*8 + (l>>3);
    int c2 = l & 7;
    int r = base + s;
    if(r < C_N){
      y_o  [(size_t)r*8 + c2] = X_u4[s*8 + (c2 ^ (s&7))];
      xa1_o[(size_t)r*8 + c2] = A_u4[s*8 + (c2 ^ (s&7))];
    }
  }
}

// ---------------- MFMA edge-logit kernel (LDS = A-tile only) ----------------
__global__ __launch_bounds__(256) void k_edge_mfma(const int* __restrict__ u_s, const int* __restrict__ c_s,
                                                   const uint4* __restrict__ xa1p, const uint4* __restrict__ userp,
                                                   const u16* __restrict__ w2t_g,
                                                   const float* __restrict__ a2b,
                                                   const float* __restrict__ a3w, const float* __restrict__ a3b,
                                                   float* __restrict__ wlog){
  __shared__ uint4 A_u4[2048];
  const int tid = threadIdx.x;
  const int base = blockIdx.x*256;
  const int ch = tid & 7;
#pragma unroll
  for(int it=0; it<8; ++it){
    int s = it*32 + (tid>>3);
    int e = base + s;
    uint4 xv = {0,0,0,0}, uv = {0,0,0,0};
    if(e < E_N){
      int c = c_s[e], u = u_s[e];
      xv = xa1p[(size_t)c*8 + ch];
      uv = userp[(size_t)u*8 + ch];
    }
    uint4 o;
    o.x = pkbf(fmaxf(blo(xv.x)+blo(uv.x),0.f), fmaxf(bhi(xv.x)+bhi(uv.x),0.f));
    o.y = pkbf(fmaxf(blo(xv.y)+blo(uv.y),0.f), fmaxf(bhi(xv.y)+bhi(uv.y),0.f));
    o.z = pkbf(fmaxf(blo(xv.z)+blo(uv.z),0.f), fmaxf(bhi(xv.z)+bhi(uv.z),0.f));
    o.w = pkbf(fmaxf(blo(xv.w)+blo(uv.w),0.f), fmaxf(bhi(xv.w)+bhi(uv.w),0.f));
    A_u4[s*8 + (ch ^ (s&7))] = o;
  }
  const int l = tid & 63, w = tid >> 6;
  const int lr = l & 15;
  const int g  = l >> 4;
  bf16x8 bf[4][2];
#pragma unroll
  for(int nt=0; nt<4; ++nt)
#pragma unroll
    for(int kk=0; kk<2; ++kk){
      int d = nt*16 + lr;
      bf[nt][kk] = *(const bf16x8*)(w2t_g + d*64 + kk*32 + g*8);
    }
  float b2v[4], a3v[4];
#pragma unroll
  for(int nt=0; nt<4; ++nt){ b2v[nt] = a2b[nt*16 + lr]; a3v[nt] = a3w[nt*16 + lr]; }
  const float a3b0 = a3b[0];
  __syncthreads();
#pragma unroll
  for(int t=0; t<4; ++t){
    int s = w*64 + t*16 + lr;
    bf16x8 af0 = *(const bf16x8*)&A_u4[s*8 + ((0*4 + g) ^ (s&7))];
    bf16x8 af1 = *(const bf16x8*)&A_u4[s*8 + ((1*4 + g) ^ (s&7))];
    f32x4 acc[4];
#pragma unroll
    for(int nt=0; nt<4; ++nt){
      f32x4 c0 = { b2v[nt], b2v[nt], b2v[nt], b2v[nt] };
      c0 = __builtin_amdgcn_mfma_f32_16x16x32_bf16(af0, bf[nt][0], c0, 0, 0, 0);
      c0 = __builtin_amdgcn_mfma_f32_16x16x32_bf16(af1, bf[nt][1], c0, 0, 0, 0);
      acc[nt] = c0;
    }
    float s0=0.f, s1=0.f, s2=0.f, s3=0.f;
#pragma unroll
    for(int nt=0; nt<4; ++nt){
      s0 += fmaxf(acc[nt][0], 0.f) * a3v[nt];
      s1 += fmaxf(acc[nt][1], 0.f) * a3v[nt];
      s2 += fmaxf(acc[nt][2], 0.f) * a3v[nt];
      s3 += fmaxf(acc[nt][3], 0.f) * a3v[nt];
    }
#pragma unroll
    for(int mask=1; mask<16; mask<<=1){
      s0 += __shfl_xor(s0, mask);
      s1 += __shfl_xor(s1, mask);
      s2 += __shfl_xor(s2, mask);
      s3 += __shfl_xor(s3, mask);
    }
    if(lr == 0){
      int e0 = base + w*64 + t*16 + g*4;
      if(e0+0 < E_N) wlog[e0+0] = s0 + a3b0;
      if(e0+1 < E_N) wlog[e0+1] = s1 + a3b0;
      if(e0+2 < E_N) wlog[e0+2] = s2 + a3b0;
      if(e0+3 < E_N) wlog[e0+3] = s3 + a3b0;
    }
  }
}

// ---------------- softmax normalize ----------------
__global__ __launch_bounds__(256) void k_smax(const int* __restrict__ start,
                                              const float* __restrict__ wlog,
                                              u16* __restrict__ pval){
  int w = threadIdx.x >> 6, lane = threadIdx.x & 63;
  int u = blockIdx.x*4 + w;
  int s0 = start[u], n = start[u+1] - s0;
  int nq = (n + 63) >> 6;
  float tq[4];
  float m = -1e30f;
  for(int q=0; q<nq; ++q){
    int j = q*64 + lane;
    float t = (j<n) ? wlog[s0+j] : -1e30f;
    if(q<4) tq[q] = t;
    m = fmaxf(m, t);
  }
#pragma unroll
  for(int off=32; off>=1; off>>=1) m = fmaxf(m, __shfl_xor(m, off));
  float ssum = 0.f;
  for(int q=0; q<nq; ++q){
    int j = q*64 + lane;
    float t = (q<4) ? tq[q] : ((j<n) ? wlog[s0+j] : -1e30f);
    float e = (j<n) ? __expf(t - m) : 0.f;
    if(q<4) tq[q] = e;
    ssum += e;
  }
#pragma unroll
  for(int off=32; off>=1; off>>=1) ssum += __shfl_xor(ssum, off);
  float inv = (n>0) ? (1.f/ssum) : 0.f;
  for(int q=0; q<nq; ++q){
    int j = q*64 + lane;
    float e = (q<4) ? tq[q] : ((j<n) ? __expf(wlog[s0+j] - m) : 0.f);
    if(j<n) pval[s0+j] = f2b(e * inv);
  }
}

// ---------------- MFMA aggregate ----------------
__global__ __launch_bounds__(256) void k_agg(const int* __restrict__ start,
                                             const int* __restrict__ u_s, const int* __restrict__ c_s,
                                             const u16* __restrict__ pval,
                                             const u16* __restrict__ Y,
                                             const float* __restrict__ wb,
                                             float* __restrict__ out){
  int w = threadIdx.x >> 6, l = threadIdx.x & 63;
  int lr = l & 15, g = l >> 4;
  int base = (blockIdx.x*4 + w) * 16;
  if(base >= U_N) return;
  int s0g = start[base];
  int s1g = start[base+16];
  int myu = base + lr;
  float wbv[4];
#pragma unroll
  for(int nt=0; nt<4; ++nt) wbv[nt] = wb[nt*16 + lr];
  f32x4 acc[4];
#pragma unroll
  for(int nt=0; nt<4; ++nt) acc[nt] = f32x4{ wbv[nt], wbv[nt], wbv[nt], wbv[nt] };

  int sA = s0g & ~31;
  int nch = (s1g - sA + 31) >> 5;
  for(int ch=0; ch<nch; ++ch){
    int e0 = sA + ch*32;
    int kb = g*8;
    bf16x8 pv = *(const bf16x8*)(pval + e0 + kb);
    int4 u0 = *(const int4*)(u_s + e0 + kb);
    int4 u1 = *(const int4*)(u_s + e0 + kb + 4);
    int4 cA = *(const int4*)(c_s + e0 + kb);
    int4 cB = *(const int4*)(c_s + e0 + kb + 4);
    bf16x8 af;
    af[0] = (u0.x == myu) ? pv[0] : (short)0;
    af[1] = (u0.y == myu) ? pv[1] : (short)0;
    af[2] = (u0.z == myu) ? pv[2] : (short)0;
    af[3] = (u0.w == myu) ? pv[3] : (short)0;
    af[4] = (u1.x == myu) ? pv[4] : (short)0;
    af[5] = (u1.y == myu) ? pv[5] : (short)0;
    af[6] = (u1.z == myu) ? pv[6] : (short)0;
    af[7] = (u1.w == myu) ? pv[7] : (short)0;
    int cj[8] = {cA.x, cA.y, cA.z, cA.w, cB.x, cB.y, cB.z, cB.w};
    bf16x8 b0, b1, b2, b3;
#pragma unroll
    for(int j=0; j<8; ++j){
      const u16* yr = Y + (size_t)cj[j]*64 + lr;
      b0[j] = (short)yr[0];
      b1[j] = (short)yr[16];
      b2[j] = (short)yr[32];
      b3[j] = (short)yr[48];
    }
    acc[0] = __builtin_amdgcn_mfma_f32_16x16x32_bf16(af, b0, acc[0], 0, 0, 0);
    acc[1] = __builtin_amdgcn_mfma_f32_16x16x32_bf16(af, b1, acc[1], 0, 0, 0);
    acc[2] = __builtin_amdgcn_mfma_f32_16x16x32_bf16(af, b2, acc[2], 0, 0, 0);
    acc[3] = __builtin_amdgcn_mfma_f32_16x16x32_bf16(af, b3, acc[3], 0, 0, 0);
  }
#pragma unroll
  for(int nt=0; nt<4; ++nt){
#pragma unroll
    for(int reg=0; reg<4; ++reg){
      int u = base + g*4 + reg;
      out[(size_t)u*64 + nt*16 + lr] = acc[nt][reg];
    }
  }
}

extern "C" void kernel_launch(void* const* d_in, const int* in_sizes, int n_in,
                              void* d_out, int out_size, void* d_ws, size_t ws_size,
                              hipStream_t stream){
  (void)in_sizes; (void)n_in; (void)out_size; (void)ws_size;
  const float4* user_feat  = (const float4*)d_in[0];
  const float4* item_feat  = (const float4*)d_in[1];
  const float*  rating_feat= (const float*)d_in[2];
  const int*    rows       = (const int*)d_in[3];
  const int*    cols       = (const int*)d_in[4];
  const int*    rats       = (const int*)d_in[5];
  const float* gv_w1 = (const float*)d_in[6];
  const float* gv_b1 = (const float*)d_in[7];
  const float* gv_w2 = (const float*)d_in[8];
  const float* gv_b2 = (const float*)d_in[9];
  const float* att_w1= (const float*)d_in[10];
  const float* att_b1= (const float*)d_in[11];
  const float* att_w2= (const float*)d_in[12];
  const float* att_b2= (const float*)d_in[13];
  const float* att_w3= (const float*)d_in[14];
  const float* att_b3= (const float*)d_in[15];
  const float* w_w   = (const float*)d_in[16];
  const float* w_b   = (const float*)d_in[17];
  float* out = (float*)d_out;

  char* ws = (char*)d_ws; size_t off = 0;
  auto take = [&](size_t b)->char*{ char* p = ws + off; off = (off + b + 255) & ~(size_t)255; return p; };
  bf16_t*   item_part  = (bf16_t*)take((size_t)I_N*64*2);       // 6.4 MB
  bf16_t*   user_part  = (bf16_t*)take((size_t)U_N*64*2);       // 12.8 MB
  float*    rating_part= (float*) take((size_t)R_N*64*4);
  bf16_t*   y_t        = (bf16_t*)take((size_t)C_N*64*2);       // 32 MB
  bf16_t*   xa1_t      = (bf16_t*)take((size_t)C_N*64*2);       // 32 MB
  float*    wlog_s     = (float*) take((size_t)E_N*4);          // 8 MB
  int*      c_s        = (int*)   take((size_t)E_N*4);          // 8 MB
  int*      u_s        = (int*)   take((size_t)E_N*4);          // 8 MB
  u16*      pval       = (u16*)   take((size_t)E_N*2);          // 4 MB
  unsigned* ucs        = (unsigned*)take((size_t)E_N*4);        // 8 MB (block-sorted runs)
  u8*       qarr       = (u8*)    take((size_t)E_N);            // 2 MB
  unsigned* uc2        = (unsigned*)take((size_t)E_N*4);        // 8 MB (bucket-sorted)
  int*      hist_g     = (int*)   take((size_t)NBLK_E*NBUCKC*4);// 6.1 MB
  int*      boff_g     = (int*)   take((size_t)NBLK_E*NBUCKC*4);// 6.1 MB
  int*      qtot       = (int*)   take((size_t)256*4);
  int*      qbase      = (int*)   take((size_t)256*4);
  int*      cnt        = (int*)   take((size_t)(NBUCKC*512+256)*4);
  int*      start      = (int*)   take((size_t)(NBUCKC*512+256)*4);
  int*      bsum       = (int*)   take((size_t)512*4);
  u16*      w1t        = (u16*)   take((size_t)4096*2);
  u16*      u1t        = (u16*)   take((size_t)4096*2);
  u16*      w2t        = (u16*)   take((size_t)4096*2);
  u16*      a1t        = (u16*)   take((size_t)4096*2);
  u16*      a2t        = (u16*)   take((size_t)4096*2);
  u16*      wwt        = (u16*)   take((size_t)4096*2);

  // CSR build: atomic-free counting sort
  k_sortA <<<NBLK_E, 256, 0, stream>>>(rows, cols, rats, ucs, qarr, hist_g);
  k_scanQ <<<NBUCKC, 256, 0, stream>>>(hist_g, boff_g, qtot);
  k_scanT <<<1, 256, 0, stream>>>(qtot, qbase);
  k_place2<<<NBLK_E, 256, 0, stream>>>(ucs, qarr, hist_g, boff_g, qbase, uc2);
  k_fineB1<<<NBUCKC, 256, 0, stream>>>(uc2, qbase, cnt);
  k_scanA <<<NBLK_U, 256, 0, stream>>>(cnt, start, bsum);
  k_scanB <<<1, 512, 0, stream>>>(bsum, NBLK_U);
  k_scanC <<<NBLK_U, 256, 0, stream>>>(start, bsum);
  k_fineB2<<<NBUCKC, 256, 0, stream>>>(uc2, qbase, start, u_s, c_s);
  // weights + tiny GEMV
  k_ratpart <<<1, 320, 0, stream>>>(rating_feat, gv_w1, gv_b1, rating_part);
  k_prepw6  <<<96, 256, 0, stream>>>(gv_w1, att_w1, gv_w2, att_w2, w_w, w1t, u1t, w2t, a1t, a2t, wwt);
  // dense precompute (MFMA)
  k_rowgemm<false><<<(I_N+255)/256, 256, 0, stream>>>(item_feat, (const uint4*)w1t, nullptr,
                                                      (uint4*)item_part, I_N);
  k_rowgemm<true> <<<NBLK_U, 256, 0, stream>>>(user_feat, (const uint4*)u1t, att_b1,
                                               (uint4*)user_part, U_N);
  k_combo_mfma<<<NBLK_C, 256, 0, stream>>>((const uint4*)item_part, (const float4*)rating_part,
                                           (const uint4*)w2t, (const uint4*)a1t, (const uint4*)wwt, gv_b2,
                                           (uint4*)y_t, (uint4*)xa1_t);
  // per-edge logits (MFMA, low-LDS)
  k_edge_mfma<<<NBLK_E, 256, 0, stream>>>(u_s, c_s, (const uint4*)xa1_t, (const uint4*)user_part,
                                          w2t, att_b2, att_w3, att_b3, wlog_s);
  // softmax normalize + MFMA aggregate (out = P @ Y + w_b)
  k_smax <<<U_N/4, 256, 0, stream>>>(start, wlog_s, pval);
  k_agg  <<<(U_N/64)+1, 256, 0, stream>>>(start, u_s, c_s, pval, (const u16*)y_t, w_b, out);
}

// Round 12
// 361.839 us; speedup vs baseline: 1.3600x; 1.0203x over previous
//
#include <hip/hip_runtime.h>
#include <hip/hip_bf16.h>

#define U_N 100000
#define I_N 50000
#define E_N 2000000
#define R_N 5
#define C_N (I_N*R_N)   // 250000 combos
#define NBLK_U 391      // ceil(100000/256); NBLK_U*256 = 100096
#define NBLK_E 7813     // ceil(2000000/256)
#define NBLK_C 1954     // ceil(250000/128)
#define NBUCKC 196      // ceil(100000/512) coarse buckets (512 users each)

typedef __hip_bfloat16 bf16_t;
typedef unsigned short u16;
typedef unsigned char u8;
typedef __attribute__((ext_vector_type(8))) short bf16x8;
typedef __attribute__((ext_vector_type(4))) float f32x4;

__device__ __forceinline__ float blo(unsigned u){ return __uint_as_float(u<<16); }
__device__ __forceinline__ float bhi(unsigned u){ return __uint_as_float(u & 0xffff0000u); }
__device__ __forceinline__ unsigned pkbf(float a, float b){
  __hip_bfloat162 t = __float22bfloat162_rn(float2{a,b});
  union { __hip_bfloat162 h; unsigned u; } cv; cv.h = t; return cv.u;
}
__device__ __forceinline__ u16 f2b(float v){
  union { __hip_bfloat16 h; u16 u; } cv; cv.h = __float2bfloat16(v); return cv.u;
}
// relu(a+b) over a uint (2 packed bf16) pair -> packed bf16
__device__ __forceinline__ unsigned relu_add_pk(unsigned a, unsigned b){
  return pkbf(fmaxf(blo(a)+blo(b),0.f), fmaxf(bhi(a)+bhi(b),0.f));
}

// ================= CSR build: atomic-free two-level counting sort =================
__global__ __launch_bounds__(256) void k_sortA(const int* __restrict__ rows, const int* __restrict__ cols,
                                               const int* __restrict__ rats,
                                               unsigned* __restrict__ ucs, u8* __restrict__ qarr,
                                               int* __restrict__ hist_g){
  __shared__ int histI[NBUCKC];
  __shared__ int s[256];
  __shared__ int rs[NBUCKC];
  int t = threadIdx.x, b = blockIdx.x;
  if(t < NBUCKC) histI[t] = 0;
  __syncthreads();
  int e = b*256 + t;
  int q = 0, rank = 0; unsigned pv = 0;
  bool valid = (e < E_N);
  if(valid){
    int u = cols[e];
    int c = rows[e]*5 + rats[e];
    q = u >> 9;
    pv = ((unsigned)(u & 511) << 18) | (unsigned)c;
    rank = atomicAdd(&histI[q], 1);
  }
  __syncthreads();
  int v = (t < NBUCKC) ? histI[t] : 0;
  s[t] = v; __syncthreads();
  for(int off=1; off<256; off<<=1){
    int x = (t>=off) ? s[t-off] : 0;
    __syncthreads();
    s[t] += x;
    __syncthreads();
  }
  if(t < NBUCKC){
    rs[t] = s[t] - v;
    hist_g[(size_t)b*NBUCKC + t] = v;
  }
  __syncthreads();
  if(valid){
    int dst = rs[q] + rank;
    ucs [b*256 + dst] = pv;
    qarr[b*256 + dst] = (u8)q;
  }
}

__global__ __launch_bounds__(256) void k_scanQ(const int* __restrict__ hist_g, int* __restrict__ boff_g,
                                               int* __restrict__ qtot){
  __shared__ int s[256];
  int t = threadIdx.x, q = blockIdx.x;
  int running = 0;
  for(int c0=0; c0<NBLK_E; c0+=256){
    int b = c0 + t;
    int v = (b < NBLK_E) ? hist_g[(size_t)b*NBUCKC + q] : 0;
    s[t] = v; __syncthreads();
    for(int off=1; off<256; off<<=1){
      int x = (t>=off) ? s[t-off] : 0;
      __syncthreads();
      s[t] += x;
      __syncthreads();
    }
    if(b < NBLK_E) boff_g[(size_t)b*NBUCKC + q] = running + s[t] - v;
    running += s[255];
    __syncthreads();
  }
  if(t == 0) qtot[q] = running;
}

__global__ void k_scanT(const int* __restrict__ qtot, int* __restrict__ qbase){
  __shared__ int s[256];
  int t = threadIdx.x;
  int v = (t < NBUCKC) ? qtot[t] : 0;
  s[t] = v; __syncthreads();
  for(int off=1; off<256; off<<=1){
    int x = (t>=off) ? s[t-off] : 0;
    __syncthreads();
    s[t] += x;
    __syncthreads();
  }
  if(t < NBUCKC) qbase[t] = s[t] - v;
  if(t == 255)   qbase[NBUCKC] = s[255];
}

__global__ __launch_bounds__(256) void k_place2(const unsigned* __restrict__ ucs, const u8* __restrict__ qarr,
                                                const int* __restrict__ hist_g, const int* __restrict__ boff_g,
                                                const int* __restrict__ qbase,
                                                unsigned* __restrict__ uc2){
  __shared__ int s[256];
  __shared__ int rs[NBUCKC];
  __shared__ int bsh[NBUCKC];
  __shared__ int qb[NBUCKC];
  int t = threadIdx.x, b = blockIdx.x;
  int v = (t < NBUCKC) ? hist_g[(size_t)b*NBUCKC + t] : 0;
  if(t < NBUCKC){
    bsh[t] = boff_g[(size_t)b*NBUCKC + t];
    qb[t]  = qbase[t];
  }
  s[t] = v; __syncthreads();
  for(int off=1; off<256; off<<=1){
    int x = (t>=off) ? s[t-off] : 0;
    __syncthreads();
    s[t] += x;
    __syncthreads();
  }
  if(t < NBUCKC) rs[t] = s[t] - v;
  __syncthreads();
  int nvalid = E_N - b*256; if(nvalid > 256) nvalid = 256;
  if(t < nvalid){
    unsigned pv = ucs[b*256 + t];
    int q = (int)qarr[b*256 + t];
    int dst = qb[q] + bsh[q] + (t - rs[q]);
    uc2[dst] = pv;
  }
}

__global__ __launch_bounds__(256) void k_fineB1(const unsigned* __restrict__ uc2, const int* __restrict__ qbase,
                                                int* __restrict__ cnt){
  __shared__ int hist[512];
  int t = threadIdx.x, q = blockIdx.x;
  hist[t] = 0; hist[t+256] = 0;
  __syncthreads();
  int r0 = qbase[q], r1 = qbase[q+1];
  for(int j=r0+t; j<r1; j+=256) atomicAdd(&hist[(uc2[j]>>18) & 511], 1);
  __syncthreads();
  cnt[q*512 + t]       = hist[t];
  cnt[q*512 + t + 256] = hist[t+256];
}

__global__ __launch_bounds__(256) void k_scanA(const int* __restrict__ cnt, int* __restrict__ start,
                                               int* __restrict__ bsum){
  __shared__ int s[256];
  int t = threadIdx.x, i = blockIdx.x*256 + t;
  int v = (i < U_N) ? cnt[i] : 0;
  s[t] = v; __syncthreads();
  for(int off=1; off<256; off<<=1){
    int x = (t>=off) ? s[t-off] : 0;
    __syncthreads();
    s[t] += x;
    __syncthreads();
  }
  start[i] = s[t] - v;
  if(t == 255) bsum[blockIdx.x] = s[255];
}

__global__ void k_scanB(int* bsum, int n){
  __shared__ int s[512];
  int t = threadIdx.x;
  int v = (t < n) ? bsum[t] : 0;
  s[t] = v; __syncthreads();
  for(int off=1; off<512; off<<=1){
    int x = (t>=off) ? s[t-off] : 0;
    __syncthreads();
    s[t] += x;
    __syncthreads();
  }
  if(t < n) bsum[t] = s[t] - v;
}

__global__ __launch_bounds__(256) void k_scanC(int* start, const int* __restrict__ bsum){
  int i = blockIdx.x*256 + threadIdx.x;
  start[i] += bsum[blockIdx.x];
}

__global__ __launch_bounds__(256) void k_fineB2(const unsigned* __restrict__ uc2, const int* __restrict__ qbase,
                                                const int* __restrict__ start,
                                                int* __restrict__ u_s, int* __restrict__ c_s){
  __shared__ int fillb[512];
  __shared__ int startb[512];
  int t = threadIdx.x, q = blockIdx.x;
  fillb[t] = 0; fillb[t+256] = 0;
  startb[t]     = start[q*512 + t];
  startb[t+256] = start[q*512 + t + 256];
  __syncthreads();
  int r0 = qbase[q], r1 = qbase[q+1];
  for(int j=r0+t; j<r1; j+=256){
    unsigned v = uc2[j];
    int ul = (int)((v>>18) & 511);
    int off = atomicAdd(&fillb[ul], 1);
    int pos = startb[ul] + off;
    u_s[pos] = (q<<9) | ul;
    c_s[pos] = (int)(v & 0x3FFFFu);
  }
}

// ---------------- tiny precompute ----------------
__global__ void k_ratpart(const float* __restrict__ rf, const float* __restrict__ w1,
                          const float* __restrict__ b1, float* __restrict__ out){
  int t = threadIdx.x; if(t >= R_N*64) return;
  int r = t>>6, d = t&63;
  float acc = b1[d];
  for(int k=0;k<64;k++) acc += rf[r*64 + k] * w1[(64+k)*64 + d];
  out[t] = acc;
}

__global__ __launch_bounds__(256) void k_prepw6(const float* __restrict__ w1, const float* __restrict__ a1,
                                                const float* __restrict__ w2, const float* __restrict__ a2,
                                                const float* __restrict__ ww,
                                                u16* w1t, u16* u1t, u16* w2t, u16* a1t, u16* a2t, u16* wwt){
  int idx = (blockIdx.x & 15)*256 + threadIdx.x;
  int sec = blockIdx.x >> 4;
  int d = idx >> 6, k = idx & 63;
  const float* src; u16* dst; int ko = 0;
  switch(sec){
    case 0: src=w1; dst=w1t; break;
    case 1: src=a1; dst=u1t; ko=64; break;
    case 2: src=w2; dst=w2t; break;
    case 3: src=a1; dst=a1t; break;
    case 4: src=a2; dst=a2t; break;
    default: src=ww; dst=wwt; break;
  }
  dst[idx] = f2b(src[(size_t)(ko+k)*64 + d]);
}

// ---------------- MFMA row-GEMM ----------------
template<bool BIAS>
__global__ __launch_bounds__(256) void k_rowgemm(const float4* __restrict__ in,
                                                 const uint4* __restrict__ wt,
                                                 const float* __restrict__ bias,
                                                 uint4* __restrict__ outp, int n){
  __shared__ uint4 A_u4[2048];
  __shared__ uint4 W_u4[512];
  __shared__ float bsh[64];
  u16* A16 = (u16*)A_u4;
  const int tid = threadIdx.x;
  for(int cid = tid; cid < 512; cid += 256){
    int dd = cid >> 3, ch = cid & 7;
    W_u4[dd*8 + (ch ^ (dd&7))] = wt[cid];
  }
  if(BIAS && tid < 64) bsh[tid] = bias[tid];
  const int base = blockIdx.x*256;
  const int ch = tid & 7;
#pragma unroll
  for(int it=0; it<8; ++it){
    int s = it*32 + (tid>>3);
    int r = base + s;
    uint4 o = {0,0,0,0};
    if(r < n){
      const float4* p = in + (size_t)r*16 + ch*2;
      float4 v0 = p[0], v1 = p[1];
      o.x = pkbf(v0.x, v0.y); o.y = pkbf(v0.z, v0.w);
      o.z = pkbf(v1.x, v1.y); o.w = pkbf(v1.z, v1.w);
    }
    A_u4[s*8 + (ch ^ (s&7))] = o;
  }
  __syncthreads();
  const int l = tid & 63, w = tid >> 6;
  const int lr = l & 15, g = l >> 4;
  bf16x8 bfr[4][2];
#pragma unroll
  for(int nt=0; nt<4; ++nt)
#pragma unroll
    for(int kk=0; kk<2; ++kk){
      int d = nt*16 + lr;
      bfr[nt][kk] = *(const bf16x8*)&W_u4[d*8 + ((kk*4+g) ^ (d&7))];
    }
  float bv[4];
#pragma unroll
  for(int nt=0; nt<4; ++nt) bv[nt] = BIAS ? bsh[nt*16 + lr] : 0.f;
#pragma unroll
  for(int t=0; t<4; ++t){
    int s = w*64 + t*16 + lr;
    bf16x8 af0 = *(const bf16x8*)&A_u4[s*8 + ((0*4+g) ^ (s&7))];
    bf16x8 af1 = *(const bf16x8*)&A_u4[s*8 + ((1*4+g) ^ (s&7))];
    f32x4 acc[4];
#pragma unroll
    for(int nt=0; nt<4; ++nt){
      f32x4 c0 = { bv[nt], bv[nt], bv[nt], bv[nt] };
      c0 = __builtin_amdgcn_mfma_f32_16x16x32_bf16(af0, bfr[nt][0], c0, 0, 0, 0);
      c0 = __builtin_amdgcn_mfma_f32_16x16x32_bf16(af1, bfr[nt][1], c0, 0, 0, 0);
      acc[nt] = c0;
    }
#pragma unroll
    for(int nt=0; nt<4; ++nt){
      int d = nt*16 + lr;
#pragma unroll
      for(int reg=0; reg<4; ++reg){
        int srow = w*64 + t*16 + g*4 + reg;
        A16[srow*64 + ((d>>3)^(srow&7))*8 + (d&7)] = f2b(acc[nt][reg]);
      }
    }
  }
#pragma unroll
  for(int it=0; it<8; ++it){
    int s = w*64 + it*8 + (l>>3);
    int c2 = l & 7;
    int r = base + s;
    if(r < n) outp[(size_t)r*8 + c2] = A_u4[s*8 + (c2 ^ (s&7))];
  }
}

// ---------------- combo ----------------
__global__ __launch_bounds__(256) void k_combo_mfma(const uint4* __restrict__ itemp,
                                                    const float4* __restrict__ ratp,
                                                    const uint4* __restrict__ w2t_g, const uint4* __restrict__ a1t_g,
                                                    const uint4* __restrict__ wwt_g,
                                                    const float* __restrict__ b2,
                                                    uint4* __restrict__ y_o, uint4* __restrict__ xa1_o){
  __shared__ uint4 A_u4[1024];
  __shared__ uint4 X_u4[1024];
  __shared__ uint4 W2_u4[512];
  __shared__ uint4 A1_u4[512];
  __shared__ uint4 WW_u4[512];
  __shared__ float4 rsh4[80];
  __shared__ float b2sh[64];
  u16* A16 = (u16*)A_u4;
  u16* X16 = (u16*)X_u4;
  const int tid = threadIdx.x;
  for(int cid = tid; cid < 512; cid += 256){
    int dd = cid >> 3, ch = cid & 7;
    W2_u4[dd*8 + (ch ^ (dd&7))] = w2t_g[cid];
    A1_u4[dd*8 + (ch ^ (dd&7))] = a1t_g[cid];
    WW_u4[dd*8 + (ch ^ (dd&7))] = wwt_g[cid];
  }
  if(tid < 80) rsh4[tid] = ratp[tid];
  if(tid < 64) b2sh[tid] = b2[tid];
  __syncthreads();

  const int base = blockIdx.x*128;
  const int ch = tid & 7;
#pragma unroll
  for(int it=0; it<4; ++it){
    int s = it*32 + (tid>>3);
    int cidx = base + s;
    uint4 o = {0,0,0,0};
    if(cidx < C_N){
      int i = cidx/5, r = cidx - i*5;
      uint4 iv = itemp[(size_t)i*8 + ch];
      float4 r0 = rsh4[r*16 + ch*2], r1 = rsh4[r*16 + ch*2 + 1];
      o.x = pkbf(fmaxf(blo(iv.x)+r0.x,0.f), fmaxf(bhi(iv.x)+r0.y,0.f));
      o.y = pkbf(fmaxf(blo(iv.y)+r0.z,0.f), fmaxf(bhi(iv.y)+r0.w,0.f));
      o.z = pkbf(fmaxf(blo(iv.z)+r1.x,0.f), fmaxf(bhi(iv.z)+r1.y,0.f));
      o.w = pkbf(fmaxf(blo(iv.w)+r1.z,0.f), fmaxf(bhi(iv.w)+r1.w,0.f));
    }
    A_u4[s*8 + (ch ^ (s&7))] = o;
  }
  __syncthreads();

  const int l = tid & 63, w = tid >> 6;
  const int lr = l & 15, g = l >> 4;
  bf16x8 w2f[4][2], a1f[4][2], wwf[4][2];
#pragma unroll
  for(int nt=0; nt<4; ++nt)
#pragma unroll
    for(int kk=0; kk<2; ++kk){
      int d = nt*16 + lr;
      w2f[nt][kk] = *(const bf16x8*)&W2_u4[d*8 + ((kk*4+g) ^ (d&7))];
      a1f[nt][kk] = *(const bf16x8*)&A1_u4[d*8 + ((kk*4+g) ^ (d&7))];
      wwf[nt][kk] = *(const bf16x8*)&WW_u4[d*8 + ((kk*4+g) ^ (d&7))];
    }
  float b2v[4];
#pragma unroll
  for(int nt=0; nt<4; ++nt) b2v[nt] = b2sh[nt*16 + lr];

#pragma unroll
  for(int t=0; t<2; ++t){
    int s = w*32 + t*16 + lr;
    bf16x8 af0 = *(const bf16x8*)&A_u4[s*8 + ((0*4+g) ^ (s&7))];
    bf16x8 af1 = *(const bf16x8*)&A_u4[s*8 + ((1*4+g) ^ (s&7))];
#pragma unroll
    for(int nt=0; nt<4; ++nt){
      f32x4 c0 = { b2v[nt], b2v[nt], b2v[nt], b2v[nt] };
      c0 = __builtin_amdgcn_mfma_f32_16x16x32_bf16(af0, w2f[nt][0], c0, 0, 0, 0);
      c0 = __builtin_amdgcn_mfma_f32_16x16x32_bf16(af1, w2f[nt][1], c0, 0, 0, 0);
      int d = nt*16 + lr;
#pragma unroll
      for(int reg=0; reg<4; ++reg){
        int srow = w*32 + t*16 + g*4 + reg;
        X16[srow*64 + ((d>>3)^(srow&7))*8 + (d&7)] = f2b(fmaxf(c0[reg], 0.f));
      }
    }
    bf16x8 xf0 = *(const bf16x8*)&X_u4[s*8 + ((0*4+g) ^ (s&7))];
    bf16x8 xf1 = *(const bf16x8*)&X_u4[s*8 + ((1*4+g) ^ (s&7))];
#pragma unroll
    for(int nt=0; nt<4; ++nt){
      f32x4 c0 = { 0.f, 0.f, 0.f, 0.f };
      c0 = __builtin_amdgcn_mfma_f32_16x16x32_bf16(xf0, a1f[nt][0], c0, 0, 0, 0);
      c0 = __builtin_amdgcn_mfma_f32_16x16x32_bf16(xf1, a1f[nt][1], c0, 0, 0, 0);
      int d = nt*16 + lr;
#pragma unroll
      for(int reg=0; reg<4; ++reg){
        int srow = w*32 + t*16 + g*4 + reg;
        A16[srow*64 + ((d>>3)^(srow&7))*8 + (d&7)] = f2b(c0[reg]);
      }
    }
#pragma unroll
    for(int nt=0; nt<4; ++nt){
      f32x4 c0 = { 0.f, 0.f, 0.f, 0.f };
      c0 = __builtin_amdgcn_mfma_f32_16x16x32_bf16(xf0, wwf[nt][0], c0, 0, 0, 0);
      c0 = __builtin_amdgcn_mfma_f32_16x16x32_bf16(xf1, wwf[nt][1], c0, 0, 0, 0);
      int d = nt*16 + lr;
#pragma unroll
      for(int reg=0; reg<4; ++reg){
        int srow = w*32 + t*16 + g*4 + reg;
        X16[srow*64 + ((d>>3)^(srow&7))*8 + (d&7)] = f2b(c0[reg]);
      }
    }
  }
#pragma unroll
  for(int it=0; it<4; ++it){
    int s = w*32 + it*8 + (l>>3);
    int c2 = l & 7;
    int r = base + s;
    if(r < C_N){
      y_o  [(size_t)r*8 + c2] = X_u4[s*8 + (c2 ^ (s&7))];
      xa1_o[(size_t)r*8 + c2] = A_u4[s*8 + (c2 ^ (s&7))];
    }
  }
}

// ---------------- MFMA edge-logit kernel: LDS-FREE (per-lane direct fragment gather) ----------------
__global__ __launch_bounds__(256) void k_edge_mfma(const int* __restrict__ u_s, const int* __restrict__ c_s,
                                                   const uint4* __restrict__ xa1p, const uint4* __restrict__ userp,
                                                   const u16* __restrict__ w2t_g,
                                                   const float* __restrict__ a2b,
                                                   const float* __restrict__ a3w, const float* __restrict__ a3b,
                                                   float* __restrict__ wlog){
  const int tid = threadIdx.x;
  const int base = blockIdx.x*256;
  const int l = tid & 63, w = tid >> 6;
  const int lr = l & 15;
  const int g  = l >> 4;
  // B-frags + biases from global (8KB table, cache-resident)
  bf16x8 bf[4][2];
#pragma unroll
  for(int nt=0; nt<4; ++nt)
#pragma unroll
    for(int kk=0; kk<2; ++kk){
      int d = nt*16 + lr;
      bf[nt][kk] = *(const bf16x8*)(w2t_g + d*64 + kk*32 + g*8);
    }
  float b2v[4], a3v[4];
#pragma unroll
  for(int nt=0; nt<4; ++nt){ b2v[nt] = a2b[nt*16 + lr]; a3v[nt] = a3w[nt*16 + lr]; }
  const float a3b0 = a3b[0];

#pragma unroll
  for(int t=0; t<4; ++t){
    int s = base + w*64 + t*16 + lr;      // this lane's edge (global index)
    int c = 0, u = 0;
    if(s < E_N){ c = c_s[s]; u = u_s[s]; }
    // fragment chunks kk*4+g of row: a1 = relu(xa1[c] + up[u])
    uint4 xv0 = xa1p[(size_t)c*8 + g];
    uint4 uv0 = userp[(size_t)u*8 + g];
    uint4 xv1 = xa1p[(size_t)c*8 + 4 + g];
    uint4 uv1 = userp[(size_t)u*8 + 4 + g];
    bf16x8 af0, af1;
    {
      unsigned r0 = relu_add_pk(xv0.x, uv0.x);
      unsigned r1 = relu_add_pk(xv0.y, uv0.y);
      unsigned r2 = relu_add_pk(xv0.z, uv0.z);
      unsigned r3 = relu_add_pk(xv0.w, uv0.w);
      af0[0]=(short)(r0&0xffff); af0[1]=(short)(r0>>16);
      af0[2]=(short)(r1&0xffff); af0[3]=(short)(r1>>16);
      af0[4]=(short)(r2&0xffff); af0[5]=(short)(r2>>16);
      af0[6]=(short)(r3&0xffff); af0[7]=(short)(r3>>16);
      r0 = relu_add_pk(xv1.x, uv1.x);
      r1 = relu_add_pk(xv1.y, uv1.y);
      r2 = relu_add_pk(xv1.z, uv1.z);
      r3 = relu_add_pk(xv1.w, uv1.w);
      af1[0]=(short)(r0&0xffff); af1[1]=(short)(r0>>16);
      af1[2]=(short)(r1&0xffff); af1[3]=(short)(r1>>16);
      af1[4]=(short)(r2&0xffff); af1[5]=(short)(r2>>16);
      af1[6]=(short)(r3&0xffff); af1[7]=(short)(r3>>16);
    }
    f32x4 acc[4];
#pragma unroll
    for(int nt=0; nt<4; ++nt){
      f32x4 c0 = { b2v[nt], b2v[nt], b2v[nt], b2v[nt] };
      c0 = __builtin_amdgcn_mfma_f32_16x16x32_bf16(af0, bf[nt][0], c0, 0, 0, 0);
      c0 = __builtin_amdgcn_mfma_f32_16x16x32_bf16(af1, bf[nt][1], c0, 0, 0, 0);
      acc[nt] = c0;
    }
    float s0=0.f, s1=0.f, s2=0.f, s3=0.f;
#pragma unroll
    for(int nt=0; nt<4; ++nt){
      s0 += fmaxf(acc[nt][0], 0.f) * a3v[nt];
      s1 += fmaxf(acc[nt][1], 0.f) * a3v[nt];
      s2 += fmaxf(acc[nt][2], 0.f) * a3v[nt];
      s3 += fmaxf(acc[nt][3], 0.f) * a3v[nt];
    }
#pragma unroll
    for(int mask=1; mask<16; mask<<=1){
      s0 += __shfl_xor(s0, mask);
      s1 += __shfl_xor(s1, mask);
      s2 += __shfl_xor(s2, mask);
      s3 += __shfl_xor(s3, mask);
    }
    if(lr == 0){
      int e0 = base + w*64 + t*16 + g*4;
      if(e0+0 < E_N) wlog[e0+0] = s0 + a3b0;
      if(e0+1 < E_N) wlog[e0+1] = s1 + a3b0;
      if(e0+2 < E_N) wlog[e0+2] = s2 + a3b0;
      if(e0+3 < E_N) wlog[e0+3] = s3 + a3b0;
    }
  }
}

// ---------------- softmax normalize ----------------
__global__ __launch_bounds__(256) void k_smax(const int* __restrict__ start,
                                              const float* __restrict__ wlog,
                                              u16* __restrict__ pval){
  int w = threadIdx.x >> 6, lane = threadIdx.x & 63;
  int u = blockIdx.x*4 + w;
  int s0 = start[u], n = start[u+1] - s0;
  int nq = (n + 63) >> 6;
  float tq[4];
  float m = -1e30f;
  for(int q=0; q<nq; ++q){
    int j = q*64 + lane;
    float t = (j<n) ? wlog[s0+j] : -1e30f;
    if(q<4) tq[q] = t;
    m = fmaxf(m, t);
  }
#pragma unroll
  for(int off=32; off>=1; off>>=1) m = fmaxf(m, __shfl_xor(m, off));
  float ssum = 0.f;
  for(int q=0; q<nq; ++q){
    int j = q*64 + lane;
    float t = (q<4) ? tq[q] : ((j<n) ? wlog[s0+j] : -1e30f);
    float e = (j<n) ? __expf(t - m) : 0.f;
    if(q<4) tq[q] = e;
    ssum += e;
  }
#pragma unroll
  for(int off=32; off>=1; off>>=1) ssum += __shfl_xor(ssum, off);
  float inv = (n>0) ? (1.f/ssum) : 0.f;
  for(int q=0; q<nq; ++q){
    int j = q*64 + lane;
    float e = (q<4) ? tq[q] : ((j<n) ? __expf(wlog[s0+j] - m) : 0.f);
    if(j<n) pval[s0+j] = f2b(e * inv);
  }
}

// ---------------- MFMA aggregate ----------------
__global__ __launch_bounds__(256) void k_agg(const int* __restrict__ start,
                                             const int* __restrict__ u_s, const int* __restrict__ c_s,
                                             const u16* __restrict__ pval,
                                             const u16* __restrict__ Y,
                                             const float* __restrict__ wb,
                                             float* __restrict__ out){
  int w = threadIdx.x >> 6, l = threadIdx.x & 63;
  int lr = l & 15, g = l >> 4;
  int base = (blockIdx.x*4 + w) * 16;
  if(base >= U_N) return;
  int s0g = start[base];
  int s1g = start[base+16];
  int myu = base + lr;
  float wbv[4];
#pragma unroll
  for(int nt=0; nt<4; ++nt) wbv[nt] = wb[nt*16 + lr];
  f32x4 acc[4];
#pragma unroll
  for(int nt=0; nt<4; ++nt) acc[nt] = f32x4{ wbv[nt], wbv[nt], wbv[nt], wbv[nt] };

  int sA = s0g & ~31;
  int nch = (s1g - sA + 31) >> 5;
  for(int ch=0; ch<nch; ++ch){
    int e0 = sA + ch*32;
    int kb = g*8;
    bf16x8 pv = *(const bf16x8*)(pval + e0 + kb);
    int4 u0 = *(const int4*)(u_s + e0 + kb);
    int4 u1 = *(const int4*)(u_s + e0 + kb + 4);
    int4 cA = *(const int4*)(c_s + e0 + kb);
    int4 cB = *(const int4*)(c_s + e0 + kb + 4);
    bf16x8 af;
    af[0] = (u0.x == myu) ? pv[0] : (short)0;
    af[1] = (u0.y == myu) ? pv[1] : (short)0;
    af[2] = (u0.z == myu) ? pv[2] : (short)0;
    af[3] = (u0.w == myu) ? pv[3] : (short)0;
    af[4] = (u1.x == myu) ? pv[4] : (short)0;
    af[5] = (u1.y == myu) ? pv[5] : (short)0;
    af[6] = (u1.z == myu) ? pv[6] : (short)0;
    af[7] = (u1.w == myu) ? pv[7] : (short)0;
    int cj[8] = {cA.x, cA.y, cA.z, cA.w, cB.x, cB.y, cB.z, cB.w};
    bf16x8 b0, b1, b2, b3;
#pragma unroll
    for(int j=0; j<8; ++j){
      const u16* yr = Y + (size_t)cj[j]*64 + lr;
      b0[j] = (short)yr[0];
      b1[j] = (short)yr[16];
      b2[j] = (short)yr[32];
      b3[j] = (short)yr[48];
    }
    acc[0] = __builtin_amdgcn_mfma_f32_16x16x32_bf16(af, b0, acc[0], 0, 0, 0);
    acc[1] = __builtin_amdgcn_mfma_f32_16x16x32_bf16(af, b1, acc[1], 0, 0, 0);
    acc[2] = __builtin_amdgcn_mfma_f32_16x16x32_bf16(af, b2, acc[2], 0, 0, 0);
    acc[3] = __builtin_amdgcn_mfma_f32_16x16x32_bf16(af, b3, acc[3], 0, 0, 0);
  }
#pragma unroll
  for(int nt=0; nt<4; ++nt){
#pragma unroll
    for(int reg=0; reg<4; ++reg){
      int u = base + g*4 + reg;
      out[(size_t)u*64 + nt*16 + lr] = acc[nt][reg];
    }
  }
}

extern "C" void kernel_launch(void* const* d_in, const int* in_sizes, int n_in,
                              void* d_out, int out_size, void* d_ws, size_t ws_size,
                              hipStream_t stream){
  (void)in_sizes; (void)n_in; (void)out_size; (void)ws_size;
  const float4* user_feat  = (const float4*)d_in[0];
  const float4* item_feat  = (const float4*)d_in[1];
  const float*  rating_feat= (const float*)d_in[2];
  const int*    rows       = (const int*)d_in[3];
  const int*    cols       = (const int*)d_in[4];
  const int*    rats       = (const int*)d_in[5];
  const float* gv_w1 = (const float*)d_in[6];
  const float* gv_b1 = (const float*)d_in[7];
  const float* gv_w2 = (const float*)d_in[8];
  const float* gv_b2 = (const float*)d_in[9];
  const float* att_w1= (const float*)d_in[10];
  const float* att_b1= (const float*)d_in[11];
  const float* att_w2= (const float*)d_in[12];
  const float* att_b2= (const float*)d_in[13];
  const float* att_w3= (const float*)d_in[14];
  const float* att_b3= (const float*)d_in[15];
  const float* w_w   = (const float*)d_in[16];
  const float* w_b   = (const float*)d_in[17];
  float* out = (float*)d_out;

  char* ws = (char*)d_ws; size_t off = 0;
  auto take = [&](size_t b)->char*{ char* p = ws + off; off = (off + b + 255) & ~(size_t)255; return p; };
  bf16_t*   item_part  = (bf16_t*)take((size_t)I_N*64*2);
  bf16_t*   user_part  = (bf16_t*)take((size_t)U_N*64*2);
  float*    rating_part= (float*) take((size_t)R_N*64*4);
  bf16_t*   y_t        = (bf16_t*)take((size_t)C_N*64*2);
  bf16_t*   xa1_t      = (bf16_t*)take((size_t)C_N*64*2);
  float*    wlog_s     = (float*) take((size_t)E_N*4);
  int*      c_s        = (int*)   take((size_t)E_N*4);
  int*      u_s        = (int*)   take((size_t)E_N*4);
  u16*      pval       = (u16*)   take((size_t)E_N*2);
  unsigned* ucs        = (unsigned*)take((size_t)E_N*4);
  u8*       qarr       = (u8*)    take((size_t)E_N);
  unsigned* uc2        = (unsigned*)take((size_t)E_N*4);
  int*      hist_g     = (int*)   take((size_t)NBLK_E*NBUCKC*4);
  int*      boff_g     = (int*)   take((size_t)NBLK_E*NBUCKC*4);
  int*      qtot       = (int*)   take((size_t)256*4);
  int*      qbase      = (int*)   take((size_t)256*4);
  int*      cnt        = (int*)   take((size_t)(NBUCKC*512+256)*4);
  int*      start      = (int*)   take((size_t)(NBUCKC*512+256)*4);
  int*      bsum       = (int*)   take((size_t)512*4);
  u16*      w1t        = (u16*)   take((size_t)4096*2);
  u16*      u1t        = (u16*)   take((size_t)4096*2);
  u16*      w2t        = (u16*)   take((size_t)4096*2);
  u16*      a1t        = (u16*)   take((size_t)4096*2);
  u16*      a2t        = (u16*)   take((size_t)4096*2);
  u16*      wwt        = (u16*)   take((size_t)4096*2);

  // CSR build: atomic-free counting sort
  k_sortA <<<NBLK_E, 256, 0, stream>>>(rows, cols, rats, ucs, qarr, hist_g);
  k_scanQ <<<NBUCKC, 256, 0, stream>>>(hist_g, boff_g, qtot);
  k_scanT <<<1, 256, 0, stream>>>(qtot, qbase);
  k_place2<<<NBLK_E, 256, 0, stream>>>(ucs, qarr, hist_g, boff_g, qbase, uc2);
  k_fineB1<<<NBUCKC, 256, 0, stream>>>(uc2, qbase, cnt);
  k_scanA <<<NBLK_U, 256, 0, stream>>>(cnt, start, bsum);
  k_scanB <<<1, 512, 0, stream>>>(bsum, NBLK_U);
  k_scanC <<<NBLK_U, 256, 0, stream>>>(start, bsum);
  k_fineB2<<<NBUCKC, 256, 0, stream>>>(uc2, qbase, start, u_s, c_s);
  // weights + tiny GEMV
  k_ratpart <<<1, 320, 0, stream>>>(rating_feat, gv_w1, gv_b1, rating_part);
  k_prepw6  <<<96, 256, 0, stream>>>(gv_w1, att_w1, gv_w2, att_w2, w_w, w1t, u1t, w2t, a1t, a2t, wwt);
  // dense precompute (MFMA)
  k_rowgemm<false><<<(I_N+255)/256, 256, 0, stream>>>(item_feat, (const uint4*)w1t, nullptr,
                                                      (uint4*)item_part, I_N);
  k_rowgemm<true> <<<NBLK_U, 256, 0, stream>>>(user_feat, (const uint4*)u1t, att_b1,
                                               (uint4*)user_part, U_N);
  k_combo_mfma<<<NBLK_C, 256, 0, stream>>>((const uint4*)item_part, (const float4*)rating_part,
                                           (const uint4*)w2t, (const uint4*)a1t, (const uint4*)wwt, gv_b2,
                                           (uint4*)y_t, (uint4*)xa1_t);
  // per-edge logits (MFMA, LDS-free)
  k_edge_mfma<<<NBLK_E, 256, 0, stream>>>(u_s, c_s, (const uint4*)xa1_t, (const uint4*)user_part,
                                          w2t, att_b2, att_w3, att_b3, wlog_s);
  // softmax normalize + MFMA aggregate (out = P @ Y + w_b)
  k_smax <<<U_N/4, 256, 0, stream>>>(start, wlog_s, pval);
  k_agg  <<<(U_N/64)+1, 256, 0, stream>>>(start, u_s, c_s, pval, (const u16*)y_t, w_b, out);
}

// Round 13
// 329.465 us; speedup vs baseline: 1.4936x; 1.0983x over previous
//
#include <hip/hip_runtime.h>
#include <hip/hip_bf16.h>

#define U_N 100000
#define I_N 50000
#define E_N 2000000
#define R_N 5
#define C_N (I_N*R_N)   // 250000 combos
#define NBLK_U 391      // ceil(100000/256)
#define NBLK_E 7813     // ceil(2000000/256)
#define NBLK_C 1954     // ceil(250000/128)
#define NBUCKC 196      // ceil(100000/512) coarse buckets (512 users each)

typedef __hip_bfloat16 bf16_t;
typedef unsigned short u16;
typedef unsigned char u8;
typedef __attribute__((ext_vector_type(8))) short bf16x8;
typedef __attribute__((ext_vector_type(4))) float f32x4;

__device__ __forceinline__ float blo(unsigned u){ return __uint_as_float(u<<16); }
__device__ __forceinline__ float bhi(unsigned u){ return __uint_as_float(u & 0xffff0000u); }
__device__ __forceinline__ unsigned pkbf(float a, float b){
  __hip_bfloat162 t = __float22bfloat162_rn(float2{a,b});
  union { __hip_bfloat162 h; unsigned u; } cv; cv.h = t; return cv.u;
}
__device__ __forceinline__ u16 f2b(float v){
  union { __hip_bfloat16 h; u16 u; } cv; cv.h = __float2bfloat16(v); return cv.u;
}
__device__ __forceinline__ unsigned relu_add_pk(unsigned a, unsigned b){
  return pkbf(fmaxf(blo(a)+blo(b),0.f), fmaxf(bhi(a)+bhi(b),0.f));
}

// ================= CSR build: histogram + deterministic placement =================
// per-block LDS histogram of q = u>>9 (no sort)
__global__ __launch_bounds__(256) void k_histQ(const int* __restrict__ cols, int* __restrict__ hist_g){
  __shared__ int histI[NBUCKC];
  int t = threadIdx.x, b = blockIdx.x;
  if(t < NBUCKC) histI[t] = 0;
  __syncthreads();
  int e = b*256 + t;
  if(e < E_N) atomicAdd(&histI[cols[e] >> 9], 1);
  __syncthreads();
  if(t < NBUCKC) hist_g[(size_t)b*NBUCKC + t] = histI[t];
}

// per-bucket scan over blocks (shfl wave-scan, 2 barriers/iter)
__global__ __launch_bounds__(256) void k_scanQ(const int* __restrict__ hist_g, int* __restrict__ boff_g,
                                               int* __restrict__ qtot){
  __shared__ int wsum[4];
  int t = threadIdx.x, q = blockIdx.x;
  int lane = t & 63, wv = t >> 6;
  int running = 0;
  for(int c0=0; c0<NBLK_E; c0+=256){
    int b = c0 + t;
    int v = (b < NBLK_E) ? hist_g[(size_t)b*NBUCKC + q] : 0;
    int inc = v;
#pragma unroll
    for(int off=1; off<64; off<<=1){
      int x = __shfl(inc, lane-off);
      if(lane >= off) inc += x;
    }
    if(lane == 63) wsum[wv] = inc;
    __syncthreads();
    int w0=wsum[0], w1=wsum[1], w2=wsum[2], w3=wsum[3];
    int wpre = (wv>0?w0:0) + (wv>1?w1:0) + (wv>2?w2:0);
    if(b < NBLK_E) boff_g[(size_t)b*NBUCKC + q] = running + wpre + inc - v;
    running += w0 + w1 + w2 + w3;
    __syncthreads();
  }
  if(t == 0) qtot[q] = running;
}

__global__ void k_scanT(const int* __restrict__ qtot, int* __restrict__ qbase){
  __shared__ int s[256];
  int t = threadIdx.x;
  int v = (t < NBUCKC) ? qtot[t] : 0;
  s[t] = v; __syncthreads();
  for(int off=1; off<256; off<<=1){
    int x = (t>=off) ? s[t-off] : 0;
    __syncthreads();
    s[t] += x;
    __syncthreads();
  }
  if(t < NBUCKC) qbase[t] = s[t] - v;
  if(t == 255)   qbase[NBUCKC] = s[255];   // == E_N
}

// placement into bucket-grouped uc2 (rank via LDS atomics; order within q arbitrary)
__global__ __launch_bounds__(256) void k_place2(const int* __restrict__ rows, const int* __restrict__ cols,
                                                const int* __restrict__ rats,
                                                const int* __restrict__ boff_g, const int* __restrict__ qbase,
                                                unsigned* __restrict__ uc2){
  __shared__ int rankI[NBUCKC];
  __shared__ int baseI[NBUCKC];
  int t = threadIdx.x, b = blockIdx.x;
  if(t < NBUCKC){
    rankI[t] = 0;
    baseI[t] = qbase[t] + boff_g[(size_t)b*NBUCKC + t];
  }
  __syncthreads();
  int e = b*256 + t;
  if(e < E_N){
    int u = cols[e];
    int c = rows[e]*5 + rats[e];
    int q = u >> 9;
    int r = atomicAdd(&rankI[q], 1);
    uc2[baseI[q] + r] = ((unsigned)(u & 511) << 18) | (unsigned)c;
  }
}

__global__ __launch_bounds__(256) void k_fineB1(const unsigned* __restrict__ uc2, const int* __restrict__ qbase,
                                                int* __restrict__ cnt){
  __shared__ int hist[512];
  int t = threadIdx.x, q = blockIdx.x;
  hist[t] = 0; hist[t+256] = 0;
  __syncthreads();
  int r0 = qbase[q], r1 = qbase[q+1];
  for(int j=r0+t; j<r1; j+=256) atomicAdd(&hist[(uc2[j]>>18) & 511], 1);
  __syncthreads();
  cnt[q*512 + t]       = hist[t];
  cnt[q*512 + t + 256] = hist[t+256];
}

__global__ __launch_bounds__(256) void k_scanA(const int* __restrict__ cnt, int* __restrict__ start,
                                               int* __restrict__ bsum){
  __shared__ int s[256];
  int t = threadIdx.x, i = blockIdx.x*256 + t;
  int v = (i < U_N) ? cnt[i] : 0;
  s[t] = v; __syncthreads();
  for(int off=1; off<256; off<<=1){
    int x = (t>=off) ? s[t-off] : 0;
    __syncthreads();
    s[t] += x;
    __syncthreads();
  }
  start[i] = s[t] - v;
  if(t == 255) bsum[blockIdx.x] = s[255];
}

__global__ void k_scanB(int* bsum, int n){
  __shared__ int s[512];
  int t = threadIdx.x;
  int v = (t < n) ? bsum[t] : 0;
  s[t] = v; __syncthreads();
  for(int off=1; off<512; off<<=1){
    int x = (t>=off) ? s[t-off] : 0;
    __syncthreads();
    s[t] += x;
    __syncthreads();
  }
  if(t < n) bsum[t] = s[t] - v;
}

__global__ __launch_bounds__(256) void k_scanC(int* start, const int* __restrict__ bsum){
  int i = blockIdx.x*256 + threadIdx.x;
  start[i] += bsum[blockIdx.x];
}

__global__ __launch_bounds__(256) void k_fineB2(const unsigned* __restrict__ uc2, const int* __restrict__ qbase,
                                                const int* __restrict__ start,
                                                int* __restrict__ u_s, int* __restrict__ c_s){
  __shared__ int fillb[512];
  __shared__ int startb[512];
  int t = threadIdx.x, q = blockIdx.x;
  fillb[t] = 0; fillb[t+256] = 0;
  startb[t]     = start[q*512 + t];
  startb[t+256] = start[q*512 + t + 256];
  __syncthreads();
  int r0 = qbase[q], r1 = qbase[q+1];
  for(int j=r0+t; j<r1; j+=256){
    unsigned v = uc2[j];
    int ul = (int)((v>>18) & 511);
    int off = atomicAdd(&fillb[ul], 1);
    int pos = startb[ul] + off;
    u_s[pos] = (q<<9) | ul;
    c_s[pos] = (int)(v & 0x3FFFFu);
  }
}

// ---------------- tiny precompute ----------------
__global__ void k_ratpart(const float* __restrict__ rf, const float* __restrict__ w1,
                          const float* __restrict__ b1, float* __restrict__ out){
  int t = threadIdx.x; if(t >= R_N*64) return;
  int r = t>>6, d = t&63;
  float acc = b1[d];
  for(int k=0;k<64;k++) acc += rf[r*64 + k] * w1[(64+k)*64 + d];
  out[t] = acc;
}

__global__ __launch_bounds__(256) void k_prepw6(const float* __restrict__ w1, const float* __restrict__ a1,
                                                const float* __restrict__ w2, const float* __restrict__ a2,
                                                const float* __restrict__ ww,
                                                u16* w1t, u16* u1t, u16* w2t, u16* a1t, u16* a2t, u16* wwt){
  int idx = (blockIdx.x & 15)*256 + threadIdx.x;
  int sec = blockIdx.x >> 4;
  int d = idx >> 6, k = idx & 63;
  const float* src; u16* dst; int ko = 0;
  switch(sec){
    case 0: src=w1; dst=w1t; break;
    case 1: src=a1; dst=u1t; ko=64; break;
    case 2: src=w2; dst=w2t; break;
    case 3: src=a1; dst=a1t; break;
    case 4: src=a2; dst=a2t; break;
    default: src=ww; dst=wwt; break;
  }
  dst[idx] = f2b(src[(size_t)(ko+k)*64 + d]);
}

// ---------------- MFMA row-GEMM ----------------
template<bool BIAS>
__global__ __launch_bounds__(256) void k_rowgemm(const float4* __restrict__ in,
                                                 const uint4* __restrict__ wt,
                                                 const float* __restrict__ bias,
                                                 uint4* __restrict__ outp, int n){
  __shared__ uint4 A_u4[2048];
  __shared__ uint4 W_u4[512];
  __shared__ float bsh[64];
  u16* A16 = (u16*)A_u4;
  const int tid = threadIdx.x;
  for(int cid = tid; cid < 512; cid += 256){
    int dd = cid >> 3, ch = cid & 7;
    W_u4[dd*8 + (ch ^ (dd&7))] = wt[cid];
  }
  if(BIAS && tid < 64) bsh[tid] = bias[tid];
  const int base = blockIdx.x*256;
  const int ch = tid & 7;
#pragma unroll
  for(int it=0; it<8; ++it){
    int s = it*32 + (tid>>3);
    int r = base + s;
    uint4 o = {0,0,0,0};
    if(r < n){
      const float4* p = in + (size_t)r*16 + ch*2;
      float4 v0 = p[0], v1 = p[1];
      o.x = pkbf(v0.x, v0.y); o.y = pkbf(v0.z, v0.w);
      o.z = pkbf(v1.x, v1.y); o.w = pkbf(v1.z, v1.w);
    }
    A_u4[s*8 + (ch ^ (s&7))] = o;
  }
  __syncthreads();
  const int l = tid & 63, w = tid >> 6;
  const int lr = l & 15, g = l >> 4;
  bf16x8 bfr[4][2];
#pragma unroll
  for(int nt=0; nt<4; ++nt)
#pragma unroll
    for(int kk=0; kk<2; ++kk){
      int d = nt*16 + lr;
      bfr[nt][kk] = *(const bf16x8*)&W_u4[d*8 + ((kk*4+g) ^ (d&7))];
    }
  float bv[4];
#pragma unroll
  for(int nt=0; nt<4; ++nt) bv[nt] = BIAS ? bsh[nt*16 + lr] : 0.f;
#pragma unroll
  for(int t=0; t<4; ++t){
    int s = w*64 + t*16 + lr;
    bf16x8 af0 = *(const bf16x8*)&A_u4[s*8 + ((0*4+g) ^ (s&7))];
    bf16x8 af1 = *(const bf16x8*)&A_u4[s*8 + ((1*4+g) ^ (s&7))];
    f32x4 acc[4];
#pragma unroll
    for(int nt=0; nt<4; ++nt){
      f32x4 c0 = { bv[nt], bv[nt], bv[nt], bv[nt] };
      c0 = __builtin_amdgcn_mfma_f32_16x16x32_bf16(af0, bfr[nt][0], c0, 0, 0, 0);
      c0 = __builtin_amdgcn_mfma_f32_16x16x32_bf16(af1, bfr[nt][1], c0, 0, 0, 0);
      acc[nt] = c0;
    }
#pragma unroll
    for(int nt=0; nt<4; ++nt){
      int d = nt*16 + lr;
#pragma unroll
      for(int reg=0; reg<4; ++reg){
        int srow = w*64 + t*16 + g*4 + reg;
        A16[srow*64 + ((d>>3)^(srow&7))*8 + (d&7)] = f2b(acc[nt][reg]);
      }
    }
  }
#pragma unroll
  for(int it=0; it<8; ++it){
    int s = w*64 + it*8 + (l>>3);
    int c2 = l & 7;
    int r = base + s;
    if(r < n) outp[(size_t)r*8 + c2] = A_u4[s*8 + (c2 ^ (s&7))];
  }
}

// ---------------- combo ----------------
__global__ __launch_bounds__(256) void k_combo_mfma(const uint4* __restrict__ itemp,
                                                    const float4* __restrict__ ratp,
                                                    const uint4* __restrict__ w2t_g, const uint4* __restrict__ a1t_g,
                                                    const uint4* __restrict__ wwt_g,
                                                    const float* __restrict__ b2,
                                                    uint4* __restrict__ y_o, uint4* __restrict__ xa1_o){
  __shared__ uint4 A_u4[1024];
  __shared__ uint4 X_u4[1024];
  __shared__ uint4 W2_u4[512];
  __shared__ uint4 A1_u4[512];
  __shared__ uint4 WW_u4[512];
  __shared__ float4 rsh4[80];
  __shared__ float b2sh[64];
  u16* A16 = (u16*)A_u4;
  u16* X16 = (u16*)X_u4;
  const int tid = threadIdx.x;
  for(int cid = tid; cid < 512; cid += 256){
    int dd = cid >> 3, ch = cid & 7;
    W2_u4[dd*8 + (ch ^ (dd&7))] = w2t_g[cid];
    A1_u4[dd*8 + (ch ^ (dd&7))] = a1t_g[cid];
    WW_u4[dd*8 + (ch ^ (dd&7))] = wwt_g[cid];
  }
  if(tid < 80) rsh4[tid] = ratp[tid];
  if(tid < 64) b2sh[tid] = b2[tid];
  __syncthreads();

  const int base = blockIdx.x*128;
  const int ch = tid & 7;
#pragma unroll
  for(int it=0; it<4; ++it){
    int s = it*32 + (tid>>3);
    int cidx = base + s;
    uint4 o = {0,0,0,0};
    if(cidx < C_N){
      int i = cidx/5, r = cidx - i*5;
      uint4 iv = itemp[(size_t)i*8 + ch];
      float4 r0 = rsh4[r*16 + ch*2], r1 = rsh4[r*16 + ch*2 + 1];
      o.x = pkbf(fmaxf(blo(iv.x)+r0.x,0.f), fmaxf(bhi(iv.x)+r0.y,0.f));
      o.y = pkbf(fmaxf(blo(iv.y)+r0.z,0.f), fmaxf(bhi(iv.y)+r0.w,0.f));
      o.z = pkbf(fmaxf(blo(iv.z)+r1.x,0.f), fmaxf(bhi(iv.z)+r1.y,0.f));
      o.w = pkbf(fmaxf(blo(iv.w)+r1.z,0.f), fmaxf(bhi(iv.w)+r1.w,0.f));
    }
    A_u4[s*8 + (ch ^ (s&7))] = o;
  }
  __syncthreads();

  const int l = tid & 63, w = tid >> 6;
  const int lr = l & 15, g = l >> 4;
  bf16x8 w2f[4][2], a1f[4][2], wwf[4][2];
#pragma unroll
  for(int nt=0; nt<4; ++nt)
#pragma unroll
    for(int kk=0; kk<2; ++kk){
      int d = nt*16 + lr;
      w2f[nt][kk] = *(const bf16x8*)&W2_u4[d*8 + ((kk*4+g) ^ (d&7))];
      a1f[nt][kk] = *(const bf16x8*)&A1_u4[d*8 + ((kk*4+g) ^ (d&7))];
      wwf[nt][kk] = *(const bf16x8*)&WW_u4[d*8 + ((kk*4+g) ^ (d&7))];
    }
  float b2v[4];
#pragma unroll
  for(int nt=0; nt<4; ++nt) b2v[nt] = b2sh[nt*16 + lr];

#pragma unroll
  for(int t=0; t<2; ++t){
    int s = w*32 + t*16 + lr;
    bf16x8 af0 = *(const bf16x8*)&A_u4[s*8 + ((0*4+g) ^ (s&7))];
    bf16x8 af1 = *(const bf16x8*)&A_u4[s*8 + ((1*4+g) ^ (s&7))];
#pragma unroll
    for(int nt=0; nt<4; ++nt){
      f32x4 c0 = { b2v[nt], b2v[nt], b2v[nt], b2v[nt] };
      c0 = __builtin_amdgcn_mfma_f32_16x16x32_bf16(af0, w2f[nt][0], c0, 0, 0, 0);
      c0 = __builtin_amdgcn_mfma_f32_16x16x32_bf16(af1, w2f[nt][1], c0, 0, 0, 0);
      int d = nt*16 + lr;
#pragma unroll
      for(int reg=0; reg<4; ++reg){
        int srow = w*32 + t*16 + g*4 + reg;
        X16[srow*64 + ((d>>3)^(srow&7))*8 + (d&7)] = f2b(fmaxf(c0[reg], 0.f));
      }
    }
    bf16x8 xf0 = *(const bf16x8*)&X_u4[s*8 + ((0*4+g) ^ (s&7))];
    bf16x8 xf1 = *(const bf16x8*)&X_u4[s*8 + ((1*4+g) ^ (s&7))];
#pragma unroll
    for(int nt=0; nt<4; ++nt){
      f32x4 c0 = { 0.f, 0.f, 0.f, 0.f };
      c0 = __builtin_amdgcn_mfma_f32_16x16x32_bf16(xf0, a1f[nt][0], c0, 0, 0, 0);
      c0 = __builtin_amdgcn_mfma_f32_16x16x32_bf16(xf1, a1f[nt][1], c0, 0, 0, 0);
      int d = nt*16 + lr;
#pragma unroll
      for(int reg=0; reg<4; ++reg){
        int srow = w*32 + t*16 + g*4 + reg;
        A16[srow*64 + ((d>>3)^(srow&7))*8 + (d&7)] = f2b(c0[reg]);
      }
    }
#pragma unroll
    for(int nt=0; nt<4; ++nt){
      f32x4 c0 = { 0.f, 0.f, 0.f, 0.f };
      c0 = __builtin_amdgcn_mfma_f32_16x16x32_bf16(xf0, wwf[nt][0], c0, 0, 0, 0);
      c0 = __builtin_amdgcn_mfma_f32_16x16x32_bf16(xf1, wwf[nt][1], c0, 0, 0, 0);
      int d = nt*16 + lr;
#pragma unroll
      for(int reg=0; reg<4; ++reg){
        int srow = w*32 + t*16 + g*4 + reg;
        X16[srow*64 + ((d>>3)^(srow&7))*8 + (d&7)] = f2b(c0[reg]);
      }
    }
  }
#pragma unroll
  for(int it=0; it<4; ++it){
    int s = w*32 + it*8 + (l>>3);
    int c2 = l & 7;
    int r = base + s;
    if(r < C_N){
      y_o  [(size_t)r*8 + c2] = X_u4[s*8 + (c2 ^ (s&7))];
      xa1_o[(size_t)r*8 + c2] = A_u4[s*8 + (c2 ^ (s&7))];
    }
  }
}

// ---------------- MFMA edge-logit kernel: LDS-free, software-pipelined ----------------
__global__ __launch_bounds__(256) void k_edge_mfma(const int* __restrict__ u_s, const int* __restrict__ c_s,
                                                   const uint4* __restrict__ xa1p, const uint4* __restrict__ userp,
                                                   const u16* __restrict__ w2t_g,
                                                   const float* __restrict__ a2b,
                                                   const float* __restrict__ a3w, const float* __restrict__ a3b,
                                                   float* __restrict__ wlog){
  const int tid = threadIdx.x;
  const int base = blockIdx.x*256;
  const int l = tid & 63, w = tid >> 6;
  const int lr = l & 15;
  const int g  = l >> 4;
  bf16x8 bf[4][2];
#pragma unroll
  for(int nt=0; nt<4; ++nt)
#pragma unroll
    for(int kk=0; kk<2; ++kk){
      int d = nt*16 + lr;
      bf[nt][kk] = *(const bf16x8*)(w2t_g + d*64 + kk*32 + g*8);
    }
  float b2v[4], a3v[4];
#pragma unroll
  for(int nt=0; nt<4; ++nt){ b2v[nt] = a2b[nt*16 + lr]; a3v[nt] = a3w[nt*16 + lr]; }
  const float a3b0 = a3b[0];

  // hoist all index loads
  int cin[4], uin[4];
#pragma unroll
  for(int t=0; t<4; ++t){
    int s = base + w*64 + t*16 + lr;
    cin[t] = (s < E_N) ? c_s[s] : 0;
    uin[t] = (s < E_N) ? u_s[s] : 0;
  }
  // prefetch t=0 rows
  uint4 xv0 = xa1p[(size_t)cin[0]*8 + g];
  uint4 uv0 = userp[(size_t)uin[0]*8 + g];
  uint4 xv1 = xa1p[(size_t)cin[0]*8 + 4 + g];
  uint4 uv1 = userp[(size_t)uin[0]*8 + 4 + g];

#pragma unroll
  for(int t=0; t<4; ++t){
    uint4 nx0, nu0, nx1, nu1;
    if(t < 3){
      nx0 = xa1p[(size_t)cin[t+1]*8 + g];
      nu0 = userp[(size_t)uin[t+1]*8 + g];
      nx1 = xa1p[(size_t)cin[t+1]*8 + 4 + g];
      nu1 = userp[(size_t)uin[t+1]*8 + 4 + g];
    }
    union { uint4 u4; bf16x8 v; } a0, a1;
    a0.u4.x = relu_add_pk(xv0.x, uv0.x);
    a0.u4.y = relu_add_pk(xv0.y, uv0.y);
    a0.u4.z = relu_add_pk(xv0.z, uv0.z);
    a0.u4.w = relu_add_pk(xv0.w, uv0.w);
    a1.u4.x = relu_add_pk(xv1.x, uv1.x);
    a1.u4.y = relu_add_pk(xv1.y, uv1.y);
    a1.u4.z = relu_add_pk(xv1.z, uv1.z);
    a1.u4.w = relu_add_pk(xv1.w, uv1.w);
    f32x4 acc[4];
#pragma unroll
    for(int nt=0; nt<4; ++nt){
      f32x4 c0 = { b2v[nt], b2v[nt], b2v[nt], b2v[nt] };
      c0 = __builtin_amdgcn_mfma_f32_16x16x32_bf16(a0.v, bf[nt][0], c0, 0, 0, 0);
      c0 = __builtin_amdgcn_mfma_f32_16x16x32_bf16(a1.v, bf[nt][1], c0, 0, 0, 0);
      acc[nt] = c0;
    }
    float s0=0.f, s1=0.f, s2=0.f, s3=0.f;
#pragma unroll
    for(int nt=0; nt<4; ++nt){
      s0 += fmaxf(acc[nt][0], 0.f) * a3v[nt];
      s1 += fmaxf(acc[nt][1], 0.f) * a3v[nt];
      s2 += fmaxf(acc[nt][2], 0.f) * a3v[nt];
      s3 += fmaxf(acc[nt][3], 0.f) * a3v[nt];
    }
#pragma unroll
    for(int mask=1; mask<16; mask<<=1){
      s0 += __shfl_xor(s0, mask);
      s1 += __shfl_xor(s1, mask);
      s2 += __shfl_xor(s2, mask);
      s3 += __shfl_xor(s3, mask);
    }
    if(lr == 0){
      int e0 = base + w*64 + t*16 + g*4;
      if(e0+0 < E_N) wlog[e0+0] = s0 + a3b0;
      if(e0+1 < E_N) wlog[e0+1] = s1 + a3b0;
      if(e0+2 < E_N) wlog[e0+2] = s2 + a3b0;
      if(e0+3 < E_N) wlog[e0+3] = s3 + a3b0;
    }
    xv0 = nx0; uv0 = nu0; xv1 = nx1; uv1 = nu1;
  }
}

// ---------------- softmax normalize ----------------
__global__ __launch_bounds__(256) void k_smax(const int* __restrict__ start,
                                              const float* __restrict__ wlog,
                                              u16* __restrict__ pval){
  int w = threadIdx.x >> 6, lane = threadIdx.x & 63;
  int u = blockIdx.x*4 + w;
  int s0 = start[u], n = start[u+1] - s0;
  int nq = (n + 63) >> 6;
  float tq[4];
  float m = -1e30f;
  for(int q=0; q<nq; ++q){
    int j = q*64 + lane;
    float t = (j<n) ? wlog[s0+j] : -1e30f;
    if(q<4) tq[q] = t;
    m = fmaxf(m, t);
  }
#pragma unroll
  for(int off=32; off>=1; off>>=1) m = fmaxf(m, __shfl_xor(m, off));
  float ssum = 0.f;
  for(int q=0; q<nq; ++q){
    int j = q*64 + lane;
    float t = (q<4) ? tq[q] : ((j<n) ? wlog[s0+j] : -1e30f);
    float e = (j<n) ? __expf(t - m) : 0.f;
    if(q<4) tq[q] = e;
    ssum += e;
  }
#pragma unroll
  for(int off=32; off>=1; off>>=1) ssum += __shfl_xor(ssum, off);
  float inv = (n>0) ? (1.f/ssum) : 0.f;
  for(int q=0; q<nq; ++q){
    int j = q*64 + lane;
    float e = (q<4) ? tq[q] : ((j<n) ? __expf(wlog[s0+j] - m) : 0.f);
    if(j<n) pval[s0+j] = f2b(e * inv);
  }
}

// ---------------- MFMA aggregate: Y rows staged in wave-private LDS ----------------
__global__ __launch_bounds__(256) void k_agg(const int* __restrict__ start,
                                             const int* __restrict__ u_s, const int* __restrict__ c_s,
                                             const u16* __restrict__ pval,
                                             const u16* __restrict__ Y,
                                             const float* __restrict__ wb,
                                             float* __restrict__ out){
  __shared__ uint4 Ysh[4][256];     // per wave: 32 rows x 8 uint4 (4 KB)
  int w = threadIdx.x >> 6, l = threadIdx.x & 63;
  int lr = l & 15, g = l >> 4;
  int base = (blockIdx.x*4 + w) * 16;
  if(base >= U_N) return;
  int s0g = start[base];
  int s1g = start[base+16];
  int myu = base + lr;
  float wbv[4];
#pragma unroll
  for(int nt=0; nt<4; ++nt) wbv[nt] = wb[nt*16 + lr];
  f32x4 acc[4];
#pragma unroll
  for(int nt=0; nt<4; ++nt) acc[nt] = f32x4{ wbv[nt], wbv[nt], wbv[nt], wbv[nt] };

  u16* Ysh16 = (u16*)&Ysh[w][0];
  const int kb = g*8;
  int sA = s0g & ~31;
  int nch = (s1g - sA + 31) >> 5;
  for(int ch=0; ch<nch; ++ch){
    int e0 = sA + ch*32;
    // cooperative stage: 32 Y rows (2 lanes per row, 64B each) into wave-private LDS
    int rowe = e0 + (l>>1);
    int crow = c_s[rowe];
    const uint4* yp = (const uint4*)Y + (size_t)crow*8 + (l&1)*4;
    uint4* dst = &Ysh[w][(l>>1)*8 + (l&1)*4];
    dst[0] = yp[0]; dst[1] = yp[1]; dst[2] = yp[2]; dst[3] = yp[3];

    bf16x8 pv = *(const bf16x8*)(pval + e0 + kb);
    int4 u0 = *(const int4*)(u_s + e0 + kb);
    int4 u1 = *(const int4*)(u_s + e0 + kb + 4);
    bf16x8 af;
    af[0] = (u0.x == myu) ? pv[0] : (short)0;
    af[1] = (u0.y == myu) ? pv[1] : (short)0;
    af[2] = (u0.z == myu) ? pv[2] : (short)0;
    af[3] = (u0.w == myu) ? pv[3] : (short)0;
    af[4] = (u1.x == myu) ? pv[4] : (short)0;
    af[5] = (u1.y == myu) ? pv[5] : (short)0;
    af[6] = (u1.z == myu) ? pv[6] : (short)0;
    af[7] = (u1.w == myu) ? pv[7] : (short)0;
    bf16x8 b0, b1, b2, b3;
#pragma unroll
    for(int j=0; j<8; ++j){
      int r = (kb + j)*64 + lr;
      b0[j] = (short)Ysh16[r];
      b1[j] = (short)Ysh16[r+16];
      b2[j] = (short)Ysh16[r+32];
      b3[j] = (short)Ysh16[r+48];
    }
    acc[0] = __builtin_amdgcn_mfma_f32_16x16x32_bf16(af, b0, acc[0], 0, 0, 0);
    acc[1] = __builtin_amdgcn_mfma_f32_16x16x32_bf16(af, b1, acc[1], 0, 0, 0);
    acc[2] = __builtin_amdgcn_mfma_f32_16x16x32_bf16(af, b2, acc[2], 0, 0, 0);
    acc[3] = __builtin_amdgcn_mfma_f32_16x16x32_bf16(af, b3, acc[3], 0, 0, 0);
  }
#pragma unroll
  for(int nt=0; nt<4; ++nt){
#pragma unroll
    for(int reg=0; reg<4; ++reg){
      int u = base + g*4 + reg;
      out[(size_t)u*64 + nt*16 + lr] = acc[nt][reg];
    }
  }
}

extern "C" void kernel_launch(void* const* d_in, const int* in_sizes, int n_in,
                              void* d_out, int out_size, void* d_ws, size_t ws_size,
                              hipStream_t stream){
  (void)in_sizes; (void)n_in; (void)out_size; (void)ws_size;
  const float4* user_feat  = (const float4*)d_in[0];
  const float4* item_feat  = (const float4*)d_in[1];
  const float*  rating_feat= (const float*)d_in[2];
  const int*    rows       = (const int*)d_in[3];
  const int*    cols       = (const int*)d_in[4];
  const int*    rats       = (const int*)d_in[5];
  const float* gv_w1 = (const float*)d_in[6];
  const float* gv_b1 = (const float*)d_in[7];
  const float* gv_w2 = (const float*)d_in[8];
  const float* gv_b2 = (const float*)d_in[9];
  const float* att_w1= (const float*)d_in[10];
  const float* att_b1= (const float*)d_in[11];
  const float* att_w2= (const float*)d_in[12];
  const float* att_b2= (const float*)d_in[13];
  const float* att_w3= (const float*)d_in[14];
  const float* att_b3= (const float*)d_in[15];
  const float* w_w   = (const float*)d_in[16];
  const float* w_b   = (const float*)d_in[17];
  float* out = (float*)d_out;

  char* ws = (char*)d_ws; size_t off = 0;
  auto take = [&](size_t b)->char*{ char* p = ws + off; off = (off + b + 255) & ~(size_t)255; return p; };
  bf16_t*   item_part  = (bf16_t*)take((size_t)I_N*64*2);
  bf16_t*   user_part  = (bf16_t*)take((size_t)U_N*64*2);
  float*    rating_part= (float*) take((size_t)R_N*64*4);
  bf16_t*   y_t        = (bf16_t*)take((size_t)C_N*64*2);
  bf16_t*   xa1_t      = (bf16_t*)take((size_t)C_N*64*2);
  float*    wlog_s     = (float*) take((size_t)E_N*4);
  int*      c_s        = (int*)   take((size_t)E_N*4);
  int*      u_s        = (int*)   take((size_t)E_N*4);
  u16*      pval       = (u16*)   take((size_t)E_N*2);
  unsigned* uc2        = (unsigned*)take((size_t)E_N*4);
  int*      hist_g     = (int*)   take((size_t)NBLK_E*NBUCKC*4);
  int*      boff_g     = (int*)   take((size_t)NBLK_E*NBUCKC*4);
  int*      qtot       = (int*)   take((size_t)256*4);
  int*      qbase      = (int*)   take((size_t)256*4);
  int*      cnt        = (int*)   take((size_t)(NBUCKC*512+256)*4);
  int*      start      = (int*)   take((size_t)(NBUCKC*512+256)*4);
  int*      bsum       = (int*)   take((size_t)512*4);
  u16*      w1t        = (u16*)   take((size_t)4096*2);
  u16*      u1t        = (u16*)   take((size_t)4096*2);
  u16*      w2t        = (u16*)   take((size_t)4096*2);
  u16*      a1t        = (u16*)   take((size_t)4096*2);
  u16*      a2t        = (u16*)   take((size_t)4096*2);
  u16*      wwt        = (u16*)   take((size_t)4096*2);

  // CSR build: histogram + deterministic placement
  k_histQ <<<NBLK_E, 256, 0, stream>>>(cols, hist_g);
  k_scanQ <<<NBUCKC, 256, 0, stream>>>(hist_g, boff_g, qtot);
  k_scanT <<<1, 256, 0, stream>>>(qtot, qbase);
  k_place2<<<NBLK_E, 256, 0, stream>>>(rows, cols, rats, boff_g, qbase, uc2);
  k_fineB1<<<NBUCKC, 256, 0, stream>>>(uc2, qbase, cnt);
  k_scanA <<<NBLK_U, 256, 0, stream>>>(cnt, start, bsum);
  k_scanB <<<1, 512, 0, stream>>>(bsum, NBLK_U);
  k_scanC <<<NBLK_U, 256, 0, stream>>>(start, bsum);
  k_fineB2<<<NBUCKC, 256, 0, stream>>>(uc2, qbase, start, u_s, c_s);
  // weights + tiny GEMV
  k_ratpart <<<1, 320, 0, stream>>>(rating_feat, gv_w1, gv_b1, rating_part);
  k_prepw6  <<<96, 256, 0, stream>>>(gv_w1, att_w1, gv_w2, att_w2, w_w, w1t, u1t, w2t, a1t, a2t, wwt);
  // dense precompute (MFMA)
  k_rowgemm<false><<<(I_N+255)/256, 256, 0, stream>>>(item_feat, (const uint4*)w1t, nullptr,
                                                      (uint4*)item_part, I_N);
  k_rowgemm<true> <<<NBLK_U, 256, 0, stream>>>(user_feat, (const uint4*)u1t, att_b1,
                                               (uint4*)user_part, U_N);
  k_combo_mfma<<<NBLK_C, 256, 0, stream>>>((const uint4*)item_part, (const float4*)rating_part,
                                           (const uint4*)w2t, (const uint4*)a1t, (const uint4*)wwt, gv_b2,
                                           (uint4*)y_t, (uint4*)xa1_t);
  // per-edge logits (MFMA, LDS-free, pipelined)
  k_edge_mfma<<<NBLK_E, 256, 0, stream>>>(u_s, c_s, (const uint4*)xa1_t, (const uint4*)user_part,
                                          w2t, att_b2, att_w3, att_b3, wlog_s);
  // softmax normalize + MFMA aggregate (out = P @ Y + w_b)
  k_smax <<<U_N/4, 256, 0, stream>>>(start, wlog_s, pval);
  k_agg  <<<(U_N/64)+1, 256, 0, stream>>>(start, u_s, c_s, pval, (const u16*)y_t, w_b, out);
}

// Round 14
// 310.491 us; speedup vs baseline: 1.5849x; 1.0611x over previous
//
#include <hip/hip_runtime.h>
#include <hip/hip_bf16.h>
#include <hip/hip_fp8.h>

#define U_N 100000
#define I_N 50000
#define E_N 2000000
#define R_N 5
#define C_N (I_N*R_N)   // 250000 combos
#define NBLK_U 391      // ceil(100000/256)
#define NBLK_E 7813     // ceil(2000000/256)
#define NBLK_C 1954     // ceil(250000/128)
#define NBUCKC 196      // ceil(100000/512) coarse buckets

typedef __hip_bfloat16 bf16_t;
typedef unsigned short u16;
typedef unsigned char u8;
typedef __attribute__((ext_vector_type(8))) short bf16x8;
typedef __attribute__((ext_vector_type(4))) float f32x4;

__device__ __forceinline__ float blo(unsigned u){ return __uint_as_float(u<<16); }
__device__ __forceinline__ float bhi(unsigned u){ return __uint_as_float(u & 0xffff0000u); }
__device__ __forceinline__ unsigned pkbf(float a, float b){
  __hip_bfloat162 t = __float22bfloat162_rn(float2{a,b});
  union { __hip_bfloat162 h; unsigned u; } cv; cv.h = t; return cv.u;
}
__device__ __forceinline__ u16 f2b(float v){
  union { __hip_bfloat16 h; u16 u; } cv; cv.h = __float2bfloat16(v); return cv.u;
}
__device__ __forceinline__ float f8f(unsigned b){
  __hip_fp8_e4m3 h; h.__x = (u8)b; return (float)h;
}
__device__ __forceinline__ unsigned ff8(float f){
  __hip_fp8_e4m3 h(f); return (unsigned)h.__x;
}

// ================= CSR build: histogram + deterministic placement =================
__global__ __launch_bounds__(256) void k_histQ(const int* __restrict__ cols, int* __restrict__ hist_g){
  __shared__ int histI[NBUCKC];
  int t = threadIdx.x, b = blockIdx.x;
  if(t < NBUCKC) histI[t] = 0;
  __syncthreads();
  int e = b*256 + t;
  if(e < E_N) atomicAdd(&histI[cols[e] >> 9], 1);
  __syncthreads();
  if(t < NBUCKC) hist_g[(size_t)b*NBUCKC + t] = histI[t];
}

__global__ __launch_bounds__(256) void k_scanQ(const int* __restrict__ hist_g, int* __restrict__ boff_g,
                                               int* __restrict__ qtot){
  __shared__ int wsum[4];
  int t = threadIdx.x, q = blockIdx.x;
  int lane = t & 63, wv = t >> 6;
  int running = 0;
  for(int c0=0; c0<NBLK_E; c0+=256){
    int b = c0 + t;
    int v = (b < NBLK_E) ? hist_g[(size_t)b*NBUCKC + q] : 0;
    int inc = v;
#pragma unroll
    for(int off=1; off<64; off<<=1){
      int x = __shfl(inc, lane-off);
      if(lane >= off) inc += x;
    }
    if(lane == 63) wsum[wv] = inc;
    __syncthreads();
    int w0=wsum[0], w1=wsum[1], w2=wsum[2], w3=wsum[3];
    int wpre = (wv>0?w0:0) + (wv>1?w1:0) + (wv>2?w2:0);
    if(b < NBLK_E) boff_g[(size_t)b*NBUCKC + q] = running + wpre + inc - v;
    running += w0 + w1 + w2 + w3;
    __syncthreads();
  }
  if(t == 0) qtot[q] = running;
}

__global__ void k_scanT(const int* __restrict__ qtot, int* __restrict__ qbase){
  __shared__ int s[256];
  int t = threadIdx.x;
  int v = (t < NBUCKC) ? qtot[t] : 0;
  s[t] = v; __syncthreads();
  for(int off=1; off<256; off<<=1){
    int x = (t>=off) ? s[t-off] : 0;
    __syncthreads();
    s[t] += x;
    __syncthreads();
  }
  if(t < NBUCKC) qbase[t] = s[t] - v;
  if(t == 255)   qbase[NBUCKC] = s[255];
}

__global__ __launch_bounds__(256) void k_place2(const int* __restrict__ rows, const int* __restrict__ cols,
                                                const int* __restrict__ rats,
                                                const int* __restrict__ boff_g, const int* __restrict__ qbase,
                                                unsigned* __restrict__ uc2){
  __shared__ int rankI[NBUCKC];
  __shared__ int baseI[NBUCKC];
  int t = threadIdx.x, b = blockIdx.x;
  if(t < NBUCKC){
    rankI[t] = 0;
    baseI[t] = qbase[t] + boff_g[(size_t)b*NBUCKC + t];
  }
  __syncthreads();
  int e = b*256 + t;
  if(e < E_N){
    int u = cols[e];
    int c = rows[e]*5 + rats[e];
    int q = u >> 9;
    int r = atomicAdd(&rankI[q], 1);
    uc2[baseI[q] + r] = ((unsigned)(u & 511) << 18) | (unsigned)c;
  }
}

__global__ __launch_bounds__(256) void k_fineB1(const unsigned* __restrict__ uc2, const int* __restrict__ qbase,
                                                int* __restrict__ cnt){
  __shared__ int hist[512];
  int t = threadIdx.x, q = blockIdx.x;
  hist[t] = 0; hist[t+256] = 0;
  __syncthreads();
  int r0 = qbase[q], r1 = qbase[q+1];
  for(int j=r0+t; j<r1; j+=256) atomicAdd(&hist[(uc2[j]>>18) & 511], 1);
  __syncthreads();
  cnt[q*512 + t]       = hist[t];
  cnt[q*512 + t + 256] = hist[t+256];
}

__global__ __launch_bounds__(256) void k_scanA(const int* __restrict__ cnt, int* __restrict__ start,
                                               int* __restrict__ bsum){
  __shared__ int s[256];
  int t = threadIdx.x, i = blockIdx.x*256 + t;
  int v = (i < U_N) ? cnt[i] : 0;
  s[t] = v; __syncthreads();
  for(int off=1; off<256; off<<=1){
    int x = (t>=off) ? s[t-off] : 0;
    __syncthreads();
    s[t] += x;
    __syncthreads();
  }
  start[i] = s[t] - v;
  if(t == 255) bsum[blockIdx.x] = s[255];
}

__global__ void k_scanB(int* bsum, int n){
  __shared__ int s[512];
  int t = threadIdx.x;
  int v = (t < n) ? bsum[t] : 0;
  s[t] = v; __syncthreads();
  for(int off=1; off<512; off<<=1){
    int x = (t>=off) ? s[t-off] : 0;
    __syncthreads();
    s[t] += x;
    __syncthreads();
  }
  if(t < n) bsum[t] = s[t] - v;
}

__global__ __launch_bounds__(256) void k_scanC(int* start, const int* __restrict__ bsum){
  int i = blockIdx.x*256 + threadIdx.x;
  start[i] += bsum[blockIdx.x];
}

__global__ __launch_bounds__(256) void k_fineB2(const unsigned* __restrict__ uc2, const int* __restrict__ qbase,
                                                const int* __restrict__ start,
                                                int* __restrict__ u_s, int* __restrict__ c_s){
  __shared__ int fillb[512];
  __shared__ int startb[512];
  int t = threadIdx.x, q = blockIdx.x;
  fillb[t] = 0; fillb[t+256] = 0;
  startb[t]     = start[q*512 + t];
  startb[t+256] = start[q*512 + t + 256];
  __syncthreads();
  int r0 = qbase[q], r1 = qbase[q+1];
  for(int j=r0+t; j<r1; j+=256){
    unsigned v = uc2[j];
    int ul = (int)((v>>18) & 511);
    int off = atomicAdd(&fillb[ul], 1);
    int pos = startb[ul] + off;
    u_s[pos] = (q<<9) | ul;
    c_s[pos] = (int)(v & 0x3FFFFu);
  }
}

// ---------------- tiny precompute ----------------
__global__ void k_ratpart(const float* __restrict__ rf, const float* __restrict__ w1,
                          const float* __restrict__ b1, float* __restrict__ out){
  int t = threadIdx.x; if(t >= R_N*64) return;
  int r = t>>6, d = t&63;
  float acc = b1[d];
  for(int k=0;k<64;k++) acc += rf[r*64 + k] * w1[(64+k)*64 + d];
  out[t] = acc;
}

__global__ __launch_bounds__(256) void k_prepw6(const float* __restrict__ w1, const float* __restrict__ a1,
                                                const float* __restrict__ w2, const float* __restrict__ a2,
                                                const float* __restrict__ ww,
                                                u16* w1t, u16* u1t, u16* w2t, u16* a1t, u16* a2t, u16* wwt){
  int idx = (blockIdx.x & 15)*256 + threadIdx.x;
  int sec = blockIdx.x >> 4;
  int d = idx >> 6, k = idx & 63;
  const float* src; u16* dst; int ko = 0;
  switch(sec){
    case 0: src=w1; dst=w1t; break;
    case 1: src=a1; dst=u1t; ko=64; break;
    case 2: src=w2; dst=w2t; break;
    case 3: src=a1; dst=a1t; break;
    case 4: src=a2; dst=a2t; break;
    default: src=ww; dst=wwt; break;
  }
  dst[idx] = f2b(src[(size_t)(ko+k)*64 + d]);
}

// ---------------- MFMA row-GEMM ----------------
template<bool BIAS>
__global__ __launch_bounds__(256) void k_rowgemm(const float4* __restrict__ in,
                                                 const uint4* __restrict__ wt,
                                                 const float* __restrict__ bias,
                                                 uint4* __restrict__ outp, int n){
  __shared__ uint4 A_u4[2048];
  __shared__ uint4 W_u4[512];
  __shared__ float bsh[64];
  u16* A16 = (u16*)A_u4;
  const int tid = threadIdx.x;
  for(int cid = tid; cid < 512; cid += 256){
    int dd = cid >> 3, ch = cid & 7;
    W_u4[dd*8 + (ch ^ (dd&7))] = wt[cid];
  }
  if(BIAS && tid < 64) bsh[tid] = bias[tid];
  const int base = blockIdx.x*256;
  const int ch = tid & 7;
#pragma unroll
  for(int it=0; it<8; ++it){
    int s = it*32 + (tid>>3);
    int r = base + s;
    uint4 o = {0,0,0,0};
    if(r < n){
      const float4* p = in + (size_t)r*16 + ch*2;
      float4 v0 = p[0], v1 = p[1];
      o.x = pkbf(v0.x, v0.y); o.y = pkbf(v0.z, v0.w);
      o.z = pkbf(v1.x, v1.y); o.w = pkbf(v1.z, v1.w);
    }
    A_u4[s*8 + (ch ^ (s&7))] = o;
  }
  __syncthreads();
  const int l = tid & 63, w = tid >> 6;
  const int lr = l & 15, g = l >> 4;
  bf16x8 bfr[4][2];
#pragma unroll
  for(int nt=0; nt<4; ++nt)
#pragma unroll
    for(int kk=0; kk<2; ++kk){
      int d = nt*16 + lr;
      bfr[nt][kk] = *(const bf16x8*)&W_u4[d*8 + ((kk*4+g) ^ (d&7))];
    }
  float bv[4];
#pragma unroll
  for(int nt=0; nt<4; ++nt) bv[nt] = BIAS ? bsh[nt*16 + lr] : 0.f;
#pragma unroll
  for(int t=0; t<4; ++t){
    int s = w*64 + t*16 + lr;
    bf16x8 af0 = *(const bf16x8*)&A_u4[s*8 + ((0*4+g) ^ (s&7))];
    bf16x8 af1 = *(const bf16x8*)&A_u4[s*8 + ((1*4+g) ^ (s&7))];
    f32x4 acc[4];
#pragma unroll
    for(int nt=0; nt<4; ++nt){
      f32x4 c0 = { bv[nt], bv[nt], bv[nt], bv[nt] };
      c0 = __builtin_amdgcn_mfma_f32_16x16x32_bf16(af0, bfr[nt][0], c0, 0, 0, 0);
      c0 = __builtin_amdgcn_mfma_f32_16x16x32_bf16(af1, bfr[nt][1], c0, 0, 0, 0);
      acc[nt] = c0;
    }
#pragma unroll
    for(int nt=0; nt<4; ++nt){
      int d = nt*16 + lr;
#pragma unroll
      for(int reg=0; reg<4; ++reg){
        int srow = w*64 + t*16 + g*4 + reg;
        A16[srow*64 + ((d>>3)^(srow&7))*8 + (d&7)] = f2b(acc[nt][reg]);
      }
    }
  }
#pragma unroll
  for(int it=0; it<8; ++it){
    int s = w*64 + it*8 + (l>>3);
    int c2 = l & 7;
    int r = base + s;
    if(r < n) outp[(size_t)r*8 + c2] = A_u4[s*8 + (c2 ^ (s&7))];
  }
}

// ---------------- combo: y_o (bf16) + xa1_o (fp8 e4m3) ----------------
__global__ __launch_bounds__(256) void k_combo_mfma(const uint4* __restrict__ itemp,
                                                    const float4* __restrict__ ratp,
                                                    const uint4* __restrict__ w2t_g, const uint4* __restrict__ a1t_g,
                                                    const uint4* __restrict__ wwt_g,
                                                    const float* __restrict__ b2,
                                                    uint4* __restrict__ y_o, u8* __restrict__ xa1_o8){
  __shared__ uint4 A_u4[1024];
  __shared__ uint4 X_u4[1024];
  __shared__ uint4 W2_u4[512];
  __shared__ uint4 A1_u4[512];
  __shared__ uint4 WW_u4[512];
  __shared__ float4 rsh4[80];
  __shared__ float b2sh[64];
  u16* A16 = (u16*)A_u4;
  u16* X16 = (u16*)X_u4;
  const int tid = threadIdx.x;
  for(int cid = tid; cid < 512; cid += 256){
    int dd = cid >> 3, ch = cid & 7;
    W2_u4[dd*8 + (ch ^ (dd&7))] = w2t_g[cid];
    A1_u4[dd*8 + (ch ^ (dd&7))] = a1t_g[cid];
    WW_u4[dd*8 + (ch ^ (dd&7))] = wwt_g[cid];
  }
  if(tid < 80) rsh4[tid] = ratp[tid];
  if(tid < 64) b2sh[tid] = b2[tid];
  __syncthreads();

  const int base = blockIdx.x*128;
  const int ch = tid & 7;
#pragma unroll
  for(int it=0; it<4; ++it){
    int s = it*32 + (tid>>3);
    int cidx = base + s;
    uint4 o = {0,0,0,0};
    if(cidx < C_N){
      int i = cidx/5, r = cidx - i*5;
      uint4 iv = itemp[(size_t)i*8 + ch];
      float4 r0 = rsh4[r*16 + ch*2], r1 = rsh4[r*16 + ch*2 + 1];
      o.x = pkbf(fmaxf(blo(iv.x)+r0.x,0.f), fmaxf(bhi(iv.x)+r0.y,0.f));
      o.y = pkbf(fmaxf(blo(iv.y)+r0.z,0.f), fmaxf(bhi(iv.y)+r0.w,0.f));
      o.z = pkbf(fmaxf(blo(iv.z)+r1.x,0.f), fmaxf(bhi(iv.z)+r1.y,0.f));
      o.w = pkbf(fmaxf(blo(iv.w)+r1.z,0.f), fmaxf(bhi(iv.w)+r1.w,0.f));
    }
    A_u4[s*8 + (ch ^ (s&7))] = o;
  }
  __syncthreads();

  const int l = tid & 63, w = tid >> 6;
  const int lr = l & 15, g = l >> 4;
  bf16x8 w2f[4][2], a1f[4][2], wwf[4][2];
#pragma unroll
  for(int nt=0; nt<4; ++nt)
#pragma unroll
    for(int kk=0; kk<2; ++kk){
      int d = nt*16 + lr;
      w2f[nt][kk] = *(const bf16x8*)&W2_u4[d*8 + ((kk*4+g) ^ (d&7))];
      a1f[nt][kk] = *(const bf16x8*)&A1_u4[d*8 + ((kk*4+g) ^ (d&7))];
      wwf[nt][kk] = *(const bf16x8*)&WW_u4[d*8 + ((kk*4+g) ^ (d&7))];
    }
  float b2v[4];
#pragma unroll
  for(int nt=0; nt<4; ++nt) b2v[nt] = b2sh[nt*16 + lr];

#pragma unroll
  for(int t=0; t<2; ++t){
    int s = w*32 + t*16 + lr;
    bf16x8 af0 = *(const bf16x8*)&A_u4[s*8 + ((0*4+g) ^ (s&7))];
    bf16x8 af1 = *(const bf16x8*)&A_u4[s*8 + ((1*4+g) ^ (s&7))];
#pragma unroll
    for(int nt=0; nt<4; ++nt){
      f32x4 c0 = { b2v[nt], b2v[nt], b2v[nt], b2v[nt] };
      c0 = __builtin_amdgcn_mfma_f32_16x16x32_bf16(af0, w2f[nt][0], c0, 0, 0, 0);
      c0 = __builtin_amdgcn_mfma_f32_16x16x32_bf16(af1, w2f[nt][1], c0, 0, 0, 0);
      int d = nt*16 + lr;
#pragma unroll
      for(int reg=0; reg<4; ++reg){
        int srow = w*32 + t*16 + g*4 + reg;
        X16[srow*64 + ((d>>3)^(srow&7))*8 + (d&7)] = f2b(fmaxf(c0[reg], 0.f));
      }
    }
    bf16x8 xf0 = *(const bf16x8*)&X_u4[s*8 + ((0*4+g) ^ (s&7))];
    bf16x8 xf1 = *(const bf16x8*)&X_u4[s*8 + ((1*4+g) ^ (s&7))];
#pragma unroll
    for(int nt=0; nt<4; ++nt){
      f32x4 c0 = { 0.f, 0.f, 0.f, 0.f };
      c0 = __builtin_amdgcn_mfma_f32_16x16x32_bf16(xf0, a1f[nt][0], c0, 0, 0, 0);
      c0 = __builtin_amdgcn_mfma_f32_16x16x32_bf16(xf1, a1f[nt][1], c0, 0, 0, 0);
      int d = nt*16 + lr;
#pragma unroll
      for(int reg=0; reg<4; ++reg){
        int srow = w*32 + t*16 + g*4 + reg;
        A16[srow*64 + ((d>>3)^(srow&7))*8 + (d&7)] = f2b(c0[reg]);
      }
    }
#pragma unroll
    for(int nt=0; nt<4; ++nt){
      f32x4 c0 = { 0.f, 0.f, 0.f, 0.f };
      c0 = __builtin_amdgcn_mfma_f32_16x16x32_bf16(xf0, wwf[nt][0], c0, 0, 0, 0);
      c0 = __builtin_amdgcn_mfma_f32_16x16x32_bf16(xf1, wwf[nt][1], c0, 0, 0, 0);
      int d = nt*16 + lr;
#pragma unroll
      for(int reg=0; reg<4; ++reg){
        int srow = w*32 + t*16 + g*4 + reg;
        X16[srow*64 + ((d>>3)^(srow&7))*8 + (d&7)] = f2b(c0[reg]);
      }
    }
  }
  // y_o store (bf16, uint4 chunks)
#pragma unroll
  for(int it=0; it<4; ++it){
    int s = w*32 + it*8 + (l>>3);
    int c2 = l & 7;
    int r = base + s;
    if(r < C_N) y_o[(size_t)r*8 + c2] = X_u4[s*8 + (c2 ^ (s&7))];
  }
  // xa1 store (fp8: 128 rows x 4 chunks of 16 bytes; wave-private rows)
#pragma unroll
  for(int it=0; it<2; ++it){
    int slot = it*64 + l;          // 0..127
    int rl = slot >> 2;            // local row 0..31
    int c4 = slot & 3;
    int s = w*32 + rl;
    int r = base + s;
    if(r < C_N){
      uint4 h0 = A_u4[s*8 + ((c4*2+0) ^ (s&7))];
      uint4 h1 = A_u4[s*8 + ((c4*2+1) ^ (s&7))];
      uint4 o;
      o.x = ff8(blo(h0.x)) | (ff8(bhi(h0.x))<<8) | (ff8(blo(h0.y))<<16) | (ff8(bhi(h0.y))<<24);
      o.y = ff8(blo(h0.z)) | (ff8(bhi(h0.z))<<8) | (ff8(blo(h0.w))<<16) | (ff8(bhi(h0.w))<<24);
      o.z = ff8(blo(h1.x)) | (ff8(bhi(h1.x))<<8) | (ff8(blo(h1.y))<<16) | (ff8(bhi(h1.y))<<24);
      o.w = ff8(blo(h1.z)) | (ff8(bhi(h1.z))<<8) | (ff8(blo(h1.w))<<16) | (ff8(bhi(h1.w))<<24);
      *(uint4*)(xa1_o8 + (size_t)r*64 + c4*16) = o;
    }
  }
}

// ---------------- MFMA edge-logit kernel: LDS-free, fp8 xa1 gather ----------------
__global__ __launch_bounds__(256) void k_edge_mfma(const int* __restrict__ u_s, const int* __restrict__ c_s,
                                                   const u8* __restrict__ xa1p8, const uint4* __restrict__ userp,
                                                   const u16* __restrict__ w2t_g,
                                                   const float* __restrict__ a2b,
                                                   const float* __restrict__ a3w, const float* __restrict__ a3b,
                                                   float* __restrict__ wlog){
  const int tid = threadIdx.x;
  const int base = blockIdx.x*256;
  const int l = tid & 63, w = tid >> 6;
  const int lr = l & 15;
  const int g  = l >> 4;
  bf16x8 bf[4][2];
#pragma unroll
  for(int nt=0; nt<4; ++nt)
#pragma unroll
    for(int kk=0; kk<2; ++kk){
      int d = nt*16 + lr;
      bf[nt][kk] = *(const bf16x8*)(w2t_g + d*64 + kk*32 + g*8);
    }
  float b2v[4], a3v[4];
#pragma unroll
  for(int nt=0; nt<4; ++nt){ b2v[nt] = a2b[nt*16 + lr]; a3v[nt] = a3w[nt*16 + lr]; }
  const float a3b0 = a3b[0];

  int cin[4], uin[4];
#pragma unroll
  for(int t=0; t<4; ++t){
    int s = base + w*64 + t*16 + lr;
    cin[t] = (s < E_N) ? c_s[s] : 0;
    uin[t] = (s < E_N) ? u_s[s] : 0;
  }
  uint2 xq0 = *(const uint2*)(xa1p8 + (size_t)cin[0]*64 + g*8);
  uint2 xq1 = *(const uint2*)(xa1p8 + (size_t)cin[0]*64 + 32 + g*8);
  uint4 uv0 = userp[(size_t)uin[0]*8 + g];
  uint4 uv1 = userp[(size_t)uin[0]*8 + 4 + g];

#pragma unroll
  for(int t=0; t<4; ++t){
    uint2 nx0, nx1; uint4 nu0, nu1;
    if(t < 3){
      nx0 = *(const uint2*)(xa1p8 + (size_t)cin[t+1]*64 + g*8);
      nx1 = *(const uint2*)(xa1p8 + (size_t)cin[t+1]*64 + 32 + g*8);
      nu0 = userp[(size_t)uin[t+1]*8 + g];
      nu1 = userp[(size_t)uin[t+1]*8 + 4 + g];
    }
    union { uint4 u4; bf16x8 v; } a0, a1;
    a0.u4.x = pkbf(fmaxf(f8f(xq0.x&255u)+blo(uv0.x),0.f),       fmaxf(f8f((xq0.x>>8)&255u)+bhi(uv0.x),0.f));
    a0.u4.y = pkbf(fmaxf(f8f((xq0.x>>16)&255u)+blo(uv0.y),0.f), fmaxf(f8f(xq0.x>>24)+bhi(uv0.y),0.f));
    a0.u4.z = pkbf(fmaxf(f8f(xq0.y&255u)+blo(uv0.z),0.f),       fmaxf(f8f((xq0.y>>8)&255u)+bhi(uv0.z),0.f));
    a0.u4.w = pkbf(fmaxf(f8f((xq0.y>>16)&255u)+blo(uv0.w),0.f), fmaxf(f8f(xq0.y>>24)+bhi(uv0.w),0.f));
    a1.u4.x = pkbf(fmaxf(f8f(xq1.x&255u)+blo(uv1.x),0.f),       fmaxf(f8f((xq1.x>>8)&255u)+bhi(uv1.x),0.f));
    a1.u4.y = pkbf(fmaxf(f8f((xq1.x>>16)&255u)+blo(uv1.y),0.f), fmaxf(f8f(xq1.x>>24)+bhi(uv1.y),0.f));
    a1.u4.z = pkbf(fmaxf(f8f(xq1.y&255u)+blo(uv1.z),0.f),       fmaxf(f8f((xq1.y>>8)&255u)+bhi(uv1.z),0.f));
    a1.u4.w = pkbf(fmaxf(f8f((xq1.y>>16)&255u)+blo(uv1.w),0.f), fmaxf(f8f(xq1.y>>24)+bhi(uv1.w),0.f));
    f32x4 acc[4];
#pragma unroll
    for(int nt=0; nt<4; ++nt){
      f32x4 c0 = { b2v[nt], b2v[nt], b2v[nt], b2v[nt] };
      c0 = __builtin_amdgcn_mfma_f32_16x16x32_bf16(a0.v, bf[nt][0], c0, 0, 0, 0);
      c0 = __builtin_amdgcn_mfma_f32_16x16x32_bf16(a1.v, bf[nt][1], c0, 0, 0, 0);
      acc[nt] = c0;
    }
    float s0=0.f, s1=0.f, s2=0.f, s3=0.f;
#pragma unroll
    for(int nt=0; nt<4; ++nt){
      s0 += fmaxf(acc[nt][0], 0.f) * a3v[nt];
      s1 += fmaxf(acc[nt][1], 0.f) * a3v[nt];
      s2 += fmaxf(acc[nt][2], 0.f) * a3v[nt];
      s3 += fmaxf(acc[nt][3], 0.f) * a3v[nt];
    }
#pragma unroll
    for(int mask=1; mask<16; mask<<=1){
      s0 += __shfl_xor(s0, mask);
      s1 += __shfl_xor(s1, mask);
      s2 += __shfl_xor(s2, mask);
      s3 += __shfl_xor(s3, mask);
    }
    if(lr == 0){
      int e0 = base + w*64 + t*16 + g*4;
      if(e0+0 < E_N) wlog[e0+0] = s0 + a3b0;
      if(e0+1 < E_N) wlog[e0+1] = s1 + a3b0;
      if(e0+2 < E_N) wlog[e0+2] = s2 + a3b0;
      if(e0+3 < E_N) wlog[e0+3] = s3 + a3b0;
    }
    xq0 = nx0; xq1 = nx1; uv0 = nu0; uv1 = nu1;
  }
}

// ---------------- fused softmax + MFMA aggregate + projection bias ----------------
__global__ __launch_bounds__(256) void k_aggf(const int* __restrict__ start,
                                              const int* __restrict__ u_s, const int* __restrict__ c_s,
                                              const float* __restrict__ wlog,
                                              const u16* __restrict__ Y,
                                              const float* __restrict__ wb,
                                              float* __restrict__ out){
  __shared__ uint4 Ysh[4][256];
  int w = threadIdx.x >> 6, l = threadIdx.x & 63;
  int lr = l & 15, g = l >> 4;
  int base = (blockIdx.x*4 + w) * 16;
  if(base >= U_N) return;
  int s0g = start[base];
  int s1g = start[base+16];
  int myu = base + lr;
  int sA = s0g & ~31;
  int nch = (s1g - sA + 31) >> 5;
  const int kb = g*8;

  // phase 1: masked max over this lane's user, k-offset slice
  float m = -1e30f;
  for(int ch=0; ch<nch; ++ch){
    int e0 = sA + ch*32;
    float4 wv0 = *(const float4*)(wlog + e0 + kb);
    float4 wv1 = *(const float4*)(wlog + e0 + kb + 4);
    int4 u0 = *(const int4*)(u_s + e0 + kb);
    int4 u1 = *(const int4*)(u_s + e0 + kb + 4);
    if(u0.x==myu) m = fmaxf(m, wv0.x);
    if(u0.y==myu) m = fmaxf(m, wv0.y);
    if(u0.z==myu) m = fmaxf(m, wv0.z);
    if(u0.w==myu) m = fmaxf(m, wv0.w);
    if(u1.x==myu) m = fmaxf(m, wv1.x);
    if(u1.y==myu) m = fmaxf(m, wv1.y);
    if(u1.z==myu) m = fmaxf(m, wv1.z);
    if(u1.w==myu) m = fmaxf(m, wv1.w);
  }
  m = fmaxf(m, __shfl_xor(m, 16));
  m = fmaxf(m, __shfl_xor(m, 32));

  // phase 2: MFMA with p = exp(x-m); accumulate denominator
  f32x4 acc[4];
#pragma unroll
  for(int nt=0; nt<4; ++nt) acc[nt] = f32x4{0.f,0.f,0.f,0.f};
  float ssum = 0.f;
  u16* Ysh16 = (u16*)&Ysh[w][0];
  for(int ch=0; ch<nch; ++ch){
    int e0 = sA + ch*32;
    int rowe = e0 + (l>>1);
    int crow = c_s[rowe];
    const uint4* yp = (const uint4*)Y + (size_t)crow*8 + (l&1)*4;
    uint4* dst = &Ysh[w][(l>>1)*8 + (l&1)*4];
    dst[0] = yp[0]; dst[1] = yp[1]; dst[2] = yp[2]; dst[3] = yp[3];

    float4 wv0 = *(const float4*)(wlog + e0 + kb);
    float4 wv1 = *(const float4*)(wlog + e0 + kb + 4);
    int4 u0 = *(const int4*)(u_s + e0 + kb);
    int4 u1 = *(const int4*)(u_s + e0 + kb + 4);
    bf16x8 af;
    {
      bool mt; float e;
      mt = (u0.x==myu); e = __expf((mt?wv0.x:-1e30f) - m); ssum += mt?e:0.f; af[0] = mt?(short)f2b(e):(short)0;
      mt = (u0.y==myu); e = __expf((mt?wv0.y:-1e30f) - m); ssum += mt?e:0.f; af[1] = mt?(short)f2b(e):(short)0;
      mt = (u0.z==myu); e = __expf((mt?wv0.z:-1e30f) - m); ssum += mt?e:0.f; af[2] = mt?(short)f2b(e):(short)0;
      mt = (u0.w==myu); e = __expf((mt?wv0.w:-1e30f) - m); ssum += mt?e:0.f; af[3] = mt?(short)f2b(e):(short)0;
      mt = (u1.x==myu); e = __expf((mt?wv1.x:-1e30f) - m); ssum += mt?e:0.f; af[4] = mt?(short)f2b(e):(short)0;
      mt = (u1.y==myu); e = __expf((mt?wv1.y:-1e30f) - m); ssum += mt?e:0.f; af[5] = mt?(short)f2b(e):(short)0;
      mt = (u1.z==myu); e = __expf((mt?wv1.z:-1e30f) - m); ssum += mt?e:0.f; af[6] = mt?(short)f2b(e):(short)0;
      mt = (u1.w==myu); e = __expf((mt?wv1.w:-1e30f) - m); ssum += mt?e:0.f; af[7] = mt?(short)f2b(e):(short)0;
    }
    bf16x8 b0, b1, b2, b3;
#pragma unroll
    for(int j=0; j<8; ++j){
      int r = (kb + j)*64 + lr;
      b0[j] = (short)Ysh16[r];
      b1[j] = (short)Ysh16[r+16];
      b2[j] = (short)Ysh16[r+32];
      b3[j] = (short)Ysh16[r+48];
    }
    acc[0] = __builtin_amdgcn_mfma_f32_16x16x32_bf16(af, b0, acc[0], 0, 0, 0);
    acc[1] = __builtin_amdgcn_mfma_f32_16x16x32_bf16(af, b1, acc[1], 0, 0, 0);
    acc[2] = __builtin_amdgcn_mfma_f32_16x16x32_bf16(af, b2, acc[2], 0, 0, 0);
    acc[3] = __builtin_amdgcn_mfma_f32_16x16x32_bf16(af, b3, acc[3], 0, 0, 0);
  }
  ssum += __shfl_xor(ssum, 16);
  ssum += __shfl_xor(ssum, 32);
  float inv = (ssum > 0.f) ? (1.f/ssum) : 0.f;
  float wbv[4];
#pragma unroll
  for(int nt=0; nt<4; ++nt) wbv[nt] = wb[nt*16 + lr];
#pragma unroll
  for(int reg=0; reg<4; ++reg){
    float sc = __shfl(inv, g*4 + reg);
    int u = base + g*4 + reg;
#pragma unroll
    for(int nt=0; nt<4; ++nt)
      out[(size_t)u*64 + nt*16 + lr] = acc[nt][reg]*sc + wbv[nt];
  }
}

extern "C" void kernel_launch(void* const* d_in, const int* in_sizes, int n_in,
                              void* d_out, int out_size, void* d_ws, size_t ws_size,
                              hipStream_t stream){
  (void)in_sizes; (void)n_in; (void)out_size; (void)ws_size;
  const float4* user_feat  = (const float4*)d_in[0];
  const float4* item_feat  = (const float4*)d_in[1];
  const float*  rating_feat= (const float*)d_in[2];
  const int*    rows       = (const int*)d_in[3];
  const int*    cols       = (const int*)d_in[4];
  const int*    rats       = (const int*)d_in[5];
  const float* gv_w1 = (const float*)d_in[6];
  const float* gv_b1 = (const float*)d_in[7];
  const float* gv_w2 = (const float*)d_in[8];
  const float* gv_b2 = (const float*)d_in[9];
  const float* att_w1= (const float*)d_in[10];
  const float* att_b1= (const float*)d_in[11];
  const float* att_w2= (const float*)d_in[12];
  const float* att_b2= (const float*)d_in[13];
  const float* att_w3= (const float*)d_in[14];
  const float* att_b3= (const float*)d_in[15];
  const float* w_w   = (const float*)d_in[16];
  const float* w_b   = (const float*)d_in[17];
  float* out = (float*)d_out;

  char* ws = (char*)d_ws; size_t off = 0;
  auto take = [&](size_t b)->char*{ char* p = ws + off; off = (off + b + 255) & ~(size_t)255; return p; };
  bf16_t*   item_part  = (bf16_t*)take((size_t)I_N*64*2);
  bf16_t*   user_part  = (bf16_t*)take((size_t)U_N*64*2);
  float*    rating_part= (float*) take((size_t)R_N*64*4);
  bf16_t*   y_t        = (bf16_t*)take((size_t)C_N*64*2);
  u8*       xa1_8      = (u8*)    take((size_t)C_N*64);       // 16 MB fp8
  float*    wlog_s     = (float*) take((size_t)E_N*4);
  int*      c_s        = (int*)   take((size_t)E_N*4);
  int*      u_s        = (int*)   take((size_t)E_N*4);
  unsigned* uc2        = (unsigned*)take((size_t)E_N*4);
  int*      hist_g     = (int*)   take((size_t)NBLK_E*NBUCKC*4);
  int*      boff_g     = (int*)   take((size_t)NBLK_E*NBUCKC*4);
  int*      qtot       = (int*)   take((size_t)256*4);
  int*      qbase      = (int*)   take((size_t)256*4);
  int*      cnt        = (int*)   take((size_t)(NBUCKC*512+256)*4);
  int*      start      = (int*)   take((size_t)(NBUCKC*512+256)*4);
  int*      bsum       = (int*)   take((size_t)512*4);
  u16*      w1t        = (u16*)   take((size_t)4096*2);
  u16*      u1t        = (u16*)   take((size_t)4096*2);
  u16*      w2t        = (u16*)   take((size_t)4096*2);
  u16*      a1t        = (u16*)   take((size_t)4096*2);
  u16*      a2t        = (u16*)   take((size_t)4096*2);
  u16*      wwt        = (u16*)   take((size_t)4096*2);

  // CSR build
  k_histQ <<<NBLK_E, 256, 0, stream>>>(cols, hist_g);
  k_scanQ <<<NBUCKC, 256, 0, stream>>>(hist_g, boff_g, qtot);
  k_scanT <<<1, 256, 0, stream>>>(qtot, qbase);
  k_place2<<<NBLK_E, 256, 0, stream>>>(rows, cols, rats, boff_g, qbase, uc2);
  k_fineB1<<<NBUCKC, 256, 0, stream>>>(uc2, qbase, cnt);
  k_scanA <<<NBLK_U, 256, 0, stream>>>(cnt, start, bsum);
  k_scanB <<<1, 512, 0, stream>>>(bsum, NBLK_U);
  k_scanC <<<NBLK_U, 256, 0, stream>>>(start, bsum);
  k_fineB2<<<NBUCKC, 256, 0, stream>>>(uc2, qbase, start, u_s, c_s);
  // weights + tiny GEMV
  k_ratpart <<<1, 320, 0, stream>>>(rating_feat, gv_w1, gv_b1, rating_part);
  k_prepw6  <<<96, 256, 0, stream>>>(gv_w1, att_w1, gv_w2, att_w2, w_w, w1t, u1t, w2t, a1t, a2t, wwt);
  // dense precompute (MFMA)
  k_rowgemm<false><<<(I_N+255)/256, 256, 0, stream>>>(item_feat, (const uint4*)w1t, nullptr,
                                                      (uint4*)item_part, I_N);
  k_rowgemm<true> <<<NBLK_U, 256, 0, stream>>>(user_feat, (const uint4*)u1t, att_b1,
                                               (uint4*)user_part, U_N);
  k_combo_mfma<<<NBLK_C, 256, 0, stream>>>((const uint4*)item_part, (const float4*)rating_part,
                                           (const uint4*)w2t, (const uint4*)a1t, (const uint4*)wwt, gv_b2,
                                           (uint4*)y_t, xa1_8);
  // per-edge logits (MFMA, fp8 gather)
  k_edge_mfma<<<NBLK_E, 256, 0, stream>>>(u_s, c_s, xa1_8, (const uint4*)user_part,
                                          w2t, att_b2, att_w3, att_b3, wlog_s);
  // fused softmax + aggregate + projection
  k_aggf <<<(U_N/64)+1, 256, 0, stream>>>(start, u_s, c_s, wlog_s, (const u16*)y_t, w_b, out);
}

// Round 15
// 293.260 us; speedup vs baseline: 1.6780x; 1.0588x over previous
//
#include <hip/hip_runtime.h>
#include <hip/hip_bf16.h>
#include <hip/hip_fp8.h>

#define U_N 100000
#define I_N 50000
#define E_N 2000000
#define R_N 5
#define C_N (I_N*R_N)   // 250000 combos
#define NBLK_U 391      // ceil(100000/256)
#define NBLK_E 7813     // ceil(2000000/256)
#define NBLK_C 1954     // ceil(250000/128)
#define NBUCKC 196      // ceil(100000/512) coarse buckets

typedef __hip_bfloat16 bf16_t;
typedef unsigned short u16;
typedef unsigned char u8;
typedef __attribute__((ext_vector_type(8))) short bf16x8;
typedef __attribute__((ext_vector_type(4))) float f32x4;

__device__ __forceinline__ float blo(unsigned u){ return __uint_as_float(u<<16); }
__device__ __forceinline__ float bhi(unsigned u){ return __uint_as_float(u & 0xffff0000u); }
__device__ __forceinline__ unsigned pkbf(float a, float b){
  __hip_bfloat162 t = __float22bfloat162_rn(float2{a,b});
  union { __hip_bfloat162 h; unsigned u; } cv; cv.h = t; return cv.u;
}
__device__ __forceinline__ u16 f2b(float v){
  union { __hip_bfloat16 h; u16 u; } cv; cv.h = __float2bfloat16(v); return cv.u;
}
__device__ __forceinline__ float f8f(unsigned b){
  __hip_fp8_e4m3 h; h.__x = (u8)b; return (float)h;
}
__device__ __forceinline__ unsigned ff8(float f){
  __hip_fp8_e4m3 h(f); return (unsigned)h.__x;
}

// ================= CSR build =================
__global__ __launch_bounds__(256) void k_histQ(const int* __restrict__ cols, int* __restrict__ hist_g){
  __shared__ int histI[NBUCKC];
  int t = threadIdx.x, b = blockIdx.x;
  if(t < NBUCKC) histI[t] = 0;
  __syncthreads();
  int e = b*256 + t;
  if(e < E_N) atomicAdd(&histI[cols[e] >> 9], 1);
  __syncthreads();
  if(t < NBUCKC) hist_g[(size_t)b*NBUCKC + t] = histI[t];
}

__global__ __launch_bounds__(256) void k_scanQ(const int* __restrict__ hist_g, int* __restrict__ boff_g,
                                               int* __restrict__ qtot){
  __shared__ int wsum[4];
  int t = threadIdx.x, q = blockIdx.x;
  int lane = t & 63, wv = t >> 6;
  int running = 0;
  for(int c0=0; c0<NBLK_E; c0+=256){
    int b = c0 + t;
    int v = (b < NBLK_E) ? hist_g[(size_t)b*NBUCKC + q] : 0;
    int inc = v;
#pragma unroll
    for(int off=1; off<64; off<<=1){
      int x = __shfl(inc, lane-off);
      if(lane >= off) inc += x;
    }
    if(lane == 63) wsum[wv] = inc;
    __syncthreads();
    int w0=wsum[0], w1=wsum[1], w2=wsum[2], w3=wsum[3];
    int wpre = (wv>0?w0:0) + (wv>1?w1:0) + (wv>2?w2:0);
    if(b < NBLK_E) boff_g[(size_t)b*NBUCKC + q] = running + wpre + inc - v;
    running += w0 + w1 + w2 + w3;
    __syncthreads();
  }
  if(t == 0) qtot[q] = running;
}

__global__ void k_scanT(const int* __restrict__ qtot, int* __restrict__ qbase){
  __shared__ int s[256];
  int t = threadIdx.x;
  int v = (t < NBUCKC) ? qtot[t] : 0;
  s[t] = v; __syncthreads();
  for(int off=1; off<256; off<<=1){
    int x = (t>=off) ? s[t-off] : 0;
    __syncthreads();
    s[t] += x;
    __syncthreads();
  }
  if(t < NBUCKC) qbase[t] = s[t] - v;
  if(t == 255)   qbase[NBUCKC] = s[255];
}

// per-edge-block starting bucket (binary search)
__global__ __launch_bounds__(256) void k_blockq(const int* __restrict__ qbase, int* __restrict__ blockq){
  int b = blockIdx.x*256 + threadIdx.x; if(b >= NBLK_E) return;
  int e = b*256;
  int lo = 0, hi = NBUCKC-1;
  while(lo < hi){ int mid = (lo+hi+1)>>1; if(qbase[mid] <= e) lo = mid; else hi = mid-1; }
  blockq[b] = lo;
}

__global__ __launch_bounds__(256) void k_place2(const int* __restrict__ rows, const int* __restrict__ cols,
                                                const int* __restrict__ rats,
                                                const int* __restrict__ boff_g, const int* __restrict__ qbase,
                                                unsigned* __restrict__ uc2){
  __shared__ int rankI[NBUCKC];
  __shared__ int baseI[NBUCKC];
  int t = threadIdx.x, b = blockIdx.x;
  if(t < NBUCKC){
    rankI[t] = 0;
    baseI[t] = qbase[t] + boff_g[(size_t)b*NBUCKC + t];
  }
  __syncthreads();
  int e = b*256 + t;
  if(e < E_N){
    int u = cols[e];
    int c = rows[e]*5 + rats[e];
    int q = u >> 9;
    int r = atomicAdd(&rankI[q], 1);
    uc2[baseI[q] + r] = ((unsigned)(u & 16383) << 18) | (unsigned)c;
  }
}

__global__ __launch_bounds__(256) void k_fineB1(const unsigned* __restrict__ uc2, const int* __restrict__ qbase,
                                                int* __restrict__ cnt){
  __shared__ int hist[512];
  int t = threadIdx.x, q = blockIdx.x;
  hist[t] = 0; hist[t+256] = 0;
  __syncthreads();
  int r0 = qbase[q], r1 = qbase[q+1];
  for(int j=r0+t; j<r1; j+=256) atomicAdd(&hist[(uc2[j]>>18) & 511], 1);
  __syncthreads();
  cnt[q*512 + t]       = hist[t];
  cnt[q*512 + t + 256] = hist[t+256];
}

__global__ __launch_bounds__(256) void k_scanA(const int* __restrict__ cnt, int* __restrict__ start,
                                               int* __restrict__ bsum){
  __shared__ int s[256];
  int t = threadIdx.x, i = blockIdx.x*256 + t;
  int v = (i < U_N) ? cnt[i] : 0;
  s[t] = v; __syncthreads();
  for(int off=1; off<256; off<<=1){
    int x = (t>=off) ? s[t-off] : 0;
    __syncthreads();
    s[t] += x;
    __syncthreads();
  }
  start[i] = s[t] - v;
  if(t == 255) bsum[blockIdx.x] = s[255];
}

__global__ void k_scanB(int* bsum, int n){
  __shared__ int s[512];
  int t = threadIdx.x;
  int v = (t < n) ? bsum[t] : 0;
  s[t] = v; __syncthreads();
  for(int off=1; off<512; off<<=1){
    int x = (t>=off) ? s[t-off] : 0;
    __syncthreads();
    s[t] += x;
    __syncthreads();
  }
  if(t < n) bsum[t] = s[t] - v;
}

__global__ __launch_bounds__(256) void k_scanC(int* start, const int* __restrict__ bsum){
  int i = blockIdx.x*256 + threadIdx.x;
  start[i] += bsum[blockIdx.x];
}

__global__ __launch_bounds__(256) void k_fineB2(const unsigned* __restrict__ uc2, const int* __restrict__ qbase,
                                                const int* __restrict__ start,
                                                unsigned* __restrict__ uc3){
  __shared__ int fillb[512];
  __shared__ int startb[512];
  int t = threadIdx.x, q = blockIdx.x;
  fillb[t] = 0; fillb[t+256] = 0;
  startb[t]     = start[q*512 + t];
  startb[t+256] = start[q*512 + t + 256];
  __syncthreads();
  int r0 = qbase[q], r1 = qbase[q+1];
  for(int j=r0+t; j<r1; j+=256){
    unsigned v = uc2[j];
    int ul = (int)((v>>18) & 511);
    int off = atomicAdd(&fillb[ul], 1);
    uc3[startb[ul] + off] = v;
  }
}

// ---------------- tiny precompute ----------------
__global__ void k_ratpart(const float* __restrict__ rf, const float* __restrict__ w1,
                          const float* __restrict__ b1, float* __restrict__ out){
  int t = threadIdx.x; if(t >= R_N*64) return;
  int r = t>>6, d = t&63;
  float acc = b1[d];
  for(int k=0;k<64;k++) acc += rf[r*64 + k] * w1[(64+k)*64 + d];
  out[t] = acc;
}

__global__ __launch_bounds__(256) void k_prepw6(const float* __restrict__ w1, const float* __restrict__ a1,
                                                const float* __restrict__ w2, const float* __restrict__ a2,
                                                const float* __restrict__ ww,
                                                u16* w1t, u16* u1t, u16* w2t, u16* a1t, u16* a2t, u16* wwt){
  int idx = (blockIdx.x & 15)*256 + threadIdx.x;
  int sec = blockIdx.x >> 4;
  int d = idx >> 6, k = idx & 63;
  const float* src; u16* dst; int ko = 0;
  switch(sec){
    case 0: src=w1; dst=w1t; break;
    case 1: src=a1; dst=u1t; ko=64; break;
    case 2: src=w2; dst=w2t; break;
    case 3: src=a1; dst=a1t; break;
    case 4: src=a2; dst=a2t; break;
    default: src=ww; dst=wwt; break;
  }
  dst[idx] = f2b(src[(size_t)(ko+k)*64 + d]);
}

// ---------------- MFMA row-GEMM ----------------
template<bool BIAS>
__global__ __launch_bounds__(256) void k_rowgemm(const float4* __restrict__ in,
                                                 const uint4* __restrict__ wt,
                                                 const float* __restrict__ bias,
                                                 uint4* __restrict__ outp, int n){
  __shared__ uint4 A_u4[2048];
  __shared__ uint4 W_u4[512];
  __shared__ float bsh[64];
  u16* A16 = (u16*)A_u4;
  const int tid = threadIdx.x;
  for(int cid = tid; cid < 512; cid += 256){
    int dd = cid >> 3, ch = cid & 7;
    W_u4[dd*8 + (ch ^ (dd&7))] = wt[cid];
  }
  if(BIAS && tid < 64) bsh[tid] = bias[tid];
  const int base = blockIdx.x*256;
  const int ch = tid & 7;
#pragma unroll
  for(int it=0; it<8; ++it){
    int s = it*32 + (tid>>3);
    int r = base + s;
    uint4 o = {0,0,0,0};
    if(r < n){
      const float4* p = in + (size_t)r*16 + ch*2;
      float4 v0 = p[0], v1 = p[1];
      o.x = pkbf(v0.x, v0.y); o.y = pkbf(v0.z, v0.w);
      o.z = pkbf(v1.x, v1.y); o.w = pkbf(v1.z, v1.w);
    }
    A_u4[s*8 + (ch ^ (s&7))] = o;
  }
  __syncthreads();
  const int l = tid & 63, w = tid >> 6;
  const int lr = l & 15, g = l >> 4;
  bf16x8 bfr[4][2];
#pragma unroll
  for(int nt=0; nt<4; ++nt)
#pragma unroll
    for(int kk=0; kk<2; ++kk){
      int d = nt*16 + lr;
      bfr[nt][kk] = *(const bf16x8*)&W_u4[d*8 + ((kk*4+g) ^ (d&7))];
    }
  float bv[4];
#pragma unroll
  for(int nt=0; nt<4; ++nt) bv[nt] = BIAS ? bsh[nt*16 + lr] : 0.f;
#pragma unroll
  for(int t=0; t<4; ++t){
    int s = w*64 + t*16 + lr;
    bf16x8 af0 = *(const bf16x8*)&A_u4[s*8 + ((0*4+g) ^ (s&7))];
    bf16x8 af1 = *(const bf16x8*)&A_u4[s*8 + ((1*4+g) ^ (s&7))];
    f32x4 acc[4];
#pragma unroll
    for(int nt=0; nt<4; ++nt){
      f32x4 c0 = { bv[nt], bv[nt], bv[nt], bv[nt] };
      c0 = __builtin_amdgcn_mfma_f32_16x16x32_bf16(af0, bfr[nt][0], c0, 0, 0, 0);
      c0 = __builtin_amdgcn_mfma_f32_16x16x32_bf16(af1, bfr[nt][1], c0, 0, 0, 0);
      acc[nt] = c0;
    }
#pragma unroll
    for(int nt=0; nt<4; ++nt){
      int d = nt*16 + lr;
#pragma unroll
      for(int reg=0; reg<4; ++reg){
        int srow = w*64 + t*16 + g*4 + reg;
        A16[srow*64 + ((d>>3)^(srow&7))*8 + (d&7)] = f2b(acc[nt][reg]);
      }
    }
  }
#pragma unroll
  for(int it=0; it<8; ++it){
    int s = w*64 + it*8 + (l>>3);
    int c2 = l & 7;
    int r = base + s;
    if(r < n) outp[(size_t)r*8 + c2] = A_u4[s*8 + (c2 ^ (s&7))];
  }
}

// ---------------- combo: y_o (bf16) + xa1_o (fp8 e4m3) ----------------
__global__ __launch_bounds__(256) void k_combo_mfma(const uint4* __restrict__ itemp,
                                                    const float4* __restrict__ ratp,
                                                    const uint4* __restrict__ w2t_g, const uint4* __restrict__ a1t_g,
                                                    const uint4* __restrict__ wwt_g,
                                                    const float* __restrict__ b2,
                                                    uint4* __restrict__ y_o, u8* __restrict__ xa1_o8){
  __shared__ uint4 A_u4[1024];
  __shared__ uint4 X_u4[1024];
  __shared__ uint4 W2_u4[512];
  __shared__ uint4 A1_u4[512];
  __shared__ uint4 WW_u4[512];
  __shared__ float4 rsh4[80];
  __shared__ float b2sh[64];
  u16* A16 = (u16*)A_u4;
  u16* X16 = (u16*)X_u4;
  const int tid = threadIdx.x;
  for(int cid = tid; cid < 512; cid += 256){
    int dd = cid >> 3, ch = cid & 7;
    W2_u4[dd*8 + (ch ^ (dd&7))] = w2t_g[cid];
    A1_u4[dd*8 + (ch ^ (dd&7))] = a1t_g[cid];
    WW_u4[dd*8 + (ch ^ (dd&7))] = wwt_g[cid];
  }
  if(tid < 80) rsh4[tid] = ratp[tid];
  if(tid < 64) b2sh[tid] = b2[tid];
  __syncthreads();

  const int base = blockIdx.x*128;
  const int ch = tid & 7;
#pragma unroll
  for(int it=0; it<4; ++it){
    int s = it*32 + (tid>>3);
    int cidx = base + s;
    uint4 o = {0,0,0,0};
    if(cidx < C_N){
      int i = cidx/5, r = cidx - i*5;
      uint4 iv = itemp[(size_t)i*8 + ch];
      float4 r0 = rsh4[r*16 + ch*2], r1 = rsh4[r*16 + ch*2 + 1];
      o.x = pkbf(fmaxf(blo(iv.x)+r0.x,0.f), fmaxf(bhi(iv.x)+r0.y,0.f));
      o.y = pkbf(fmaxf(blo(iv.y)+r0.z,0.f), fmaxf(bhi(iv.y)+r0.w,0.f));
      o.z = pkbf(fmaxf(blo(iv.z)+r1.x,0.f), fmaxf(bhi(iv.z)+r1.y,0.f));
      o.w = pkbf(fmaxf(blo(iv.w)+r1.z,0.f), fmaxf(bhi(iv.w)+r1.w,0.f));
    }
    A_u4[s*8 + (ch ^ (s&7))] = o;
  }
  __syncthreads();

  const int l = tid & 63, w = tid >> 6;
  const int lr = l & 15, g = l >> 4;
  bf16x8 w2f[4][2], a1f[4][2], wwf[4][2];
#pragma unroll
  for(int nt=0; nt<4; ++nt)
#pragma unroll
    for(int kk=0; kk<2; ++kk){
      int d = nt*16 + lr;
      w2f[nt][kk] = *(const bf16x8*)&W2_u4[d*8 + ((kk*4+g) ^ (d&7))];
      a1f[nt][kk] = *(const bf16x8*)&A1_u4[d*8 + ((kk*4+g) ^ (d&7))];
      wwf[nt][kk] = *(const bf16x8*)&WW_u4[d*8 + ((kk*4+g) ^ (d&7))];
    }
  float b2v[4];
#pragma unroll
  for(int nt=0; nt<4; ++nt) b2v[nt] = b2sh[nt*16 + lr];

#pragma unroll
  for(int t=0; t<2; ++t){
    int s = w*32 + t*16 + lr;
    bf16x8 af0 = *(const bf16x8*)&A_u4[s*8 + ((0*4+g) ^ (s&7))];
    bf16x8 af1 = *(const bf16x8*)&A_u4[s*8 + ((1*4+g) ^ (s&7))];
#pragma unroll
    for(int nt=0; nt<4; ++nt){
      f32x4 c0 = { b2v[nt], b2v[nt], b2v[nt], b2v[nt] };
      c0 = __builtin_amdgcn_mfma_f32_16x16x32_bf16(af0, w2f[nt][0], c0, 0, 0, 0);
      c0 = __builtin_amdgcn_mfma_f32_16x16x32_bf16(af1, w2f[nt][1], c0, 0, 0, 0);
      int d = nt*16 + lr;
#pragma unroll
      for(int reg=0; reg<4; ++reg){
        int srow = w*32 + t*16 + g*4 + reg;
        X16[srow*64 + ((d>>3)^(srow&7))*8 + (d&7)] = f2b(fmaxf(c0[reg], 0.f));
      }
    }
    bf16x8 xf0 = *(const bf16x8*)&X_u4[s*8 + ((0*4+g) ^ (s&7))];
    bf16x8 xf1 = *(const bf16x8*)&X_u4[s*8 + ((1*4+g) ^ (s&7))];
#pragma unroll
    for(int nt=0; nt<4; ++nt){
      f32x4 c0 = { 0.f, 0.f, 0.f, 0.f };
      c0 = __builtin_amdgcn_mfma_f32_16x16x32_bf16(xf0, a1f[nt][0], c0, 0, 0, 0);
      c0 = __builtin_amdgcn_mfma_f32_16x16x32_bf16(xf1, a1f[nt][1], c0, 0, 0, 0);
      int d = nt*16 + lr;
#pragma unroll
      for(int reg=0; reg<4; ++reg){
        int srow = w*32 + t*16 + g*4 + reg;
        A16[srow*64 + ((d>>3)^(srow&7))*8 + (d&7)] = f2b(c0[reg]);
      }
    }
#pragma unroll
    for(int nt=0; nt<4; ++nt){
      f32x4 c0 = { 0.f, 0.f, 0.f, 0.f };
      c0 = __builtin_amdgcn_mfma_f32_16x16x32_bf16(xf0, wwf[nt][0], c0, 0, 0, 0);
      c0 = __builtin_amdgcn_mfma_f32_16x16x32_bf16(xf1, wwf[nt][1], c0, 0, 0, 0);
      int d = nt*16 + lr;
#pragma unroll
      for(int reg=0; reg<4; ++reg){
        int srow = w*32 + t*16 + g*4 + reg;
        X16[srow*64 + ((d>>3)^(srow&7))*8 + (d&7)] = f2b(c0[reg]);
      }
    }
  }
#pragma unroll
  for(int it=0; it<4; ++it){
    int s = w*32 + it*8 + (l>>3);
    int c2 = l & 7;
    int r = base + s;
    if(r < C_N) y_o[(size_t)r*8 + c2] = X_u4[s*8 + (c2 ^ (s&7))];
  }
#pragma unroll
  for(int it=0; it<2; ++it){
    int slot = it*64 + l;
    int rl = slot >> 2;
    int c4 = slot & 3;
    int s = w*32 + rl;
    int r = base + s;
    if(r < C_N){
      uint4 h0 = A_u4[s*8 + ((c4*2+0) ^ (s&7))];
      uint4 h1 = A_u4[s*8 + ((c4*2+1) ^ (s&7))];
      uint4 o;
      o.x = ff8(blo(h0.x)) | (ff8(bhi(h0.x))<<8) | (ff8(blo(h0.y))<<16) | (ff8(bhi(h0.y))<<24);
      o.y = ff8(blo(h0.z)) | (ff8(bhi(h0.z))<<8) | (ff8(blo(h0.w))<<16) | (ff8(bhi(h0.w))<<24);
      o.z = ff8(blo(h1.x)) | (ff8(bhi(h1.x))<<8) | (ff8(blo(h1.y))<<16) | (ff8(bhi(h1.y))<<24);
      o.w = ff8(blo(h1.z)) | (ff8(bhi(h1.z))<<8) | (ff8(blo(h1.w))<<16) | (ff8(bhi(h1.w))<<24);
      *(uint4*)(xa1_o8 + (size_t)r*64 + c4*16) = o;
    }
  }
}

// ---------------- MFMA edge-logit kernel: LDS-free, depth-2 pipelined, packed index ----------------
__global__ __launch_bounds__(256) void k_edge_mfma(const unsigned* __restrict__ uc3,
                                                   const int* __restrict__ qbase, const int* __restrict__ blockq,
                                                   const u8* __restrict__ xa1p8, const uint4* __restrict__ userp,
                                                   const u16* __restrict__ w2t_g,
                                                   const float* __restrict__ a2b,
                                                   const float* __restrict__ a3w, const float* __restrict__ a3b,
                                                   float* __restrict__ wlog){
  const int tid = threadIdx.x;
  const int base = blockIdx.x*256;
  const int l = tid & 63, w = tid >> 6;
  const int lr = l & 15;
  const int g  = l >> 4;
  bf16x8 bf[4][2];
#pragma unroll
  for(int nt=0; nt<4; ++nt)
#pragma unroll
    for(int kk=0; kk<2; ++kk){
      int d = nt*16 + lr;
      bf[nt][kk] = *(const bf16x8*)(w2t_g + d*64 + kk*32 + g*8);
    }
  float b2v[4], a3v[4];
#pragma unroll
  for(int nt=0; nt<4; ++nt){ b2v[nt] = a2b[nt*16 + lr]; a3v[nt] = a3w[nt*16 + lr]; }
  const float a3b0 = a3b[0];

  // hoisted index loads + bucket walk
  int cin[4], uin[4];
  int bq = blockq[blockIdx.x];
#pragma unroll
  for(int t=0; t<4; ++t){
    int s = base + w*64 + t*16 + lr;
    int sc = (s < E_N) ? s : (E_N-1);
    unsigned vv = (s < E_N) ? uc3[s] : 0u;
    int q = bq;
    while(sc >= qbase[q+1]) ++q;
    cin[t] = (int)(vv & 0x3FFFFu);
    uin[t] = (q<<9) | (int)((vv>>18) & 511u);
  }

  auto compute = [&](uint2 xq0, uint2 xq1, uint4 uv0, uint4 uv1, int t){
    union { uint4 u4; bf16x8 v; } a0, a1;
    a0.u4.x = pkbf(fmaxf(f8f(xq0.x&255u)+blo(uv0.x),0.f),       fmaxf(f8f((xq0.x>>8)&255u)+bhi(uv0.x),0.f));
    a0.u4.y = pkbf(fmaxf(f8f((xq0.x>>16)&255u)+blo(uv0.y),0.f), fmaxf(f8f(xq0.x>>24)+bhi(uv0.y),0.f));
    a0.u4.z = pkbf(fmaxf(f8f(xq0.y&255u)+blo(uv0.z),0.f),       fmaxf(f8f((xq0.y>>8)&255u)+bhi(uv0.z),0.f));
    a0.u4.w = pkbf(fmaxf(f8f((xq0.y>>16)&255u)+blo(uv0.w),0.f), fmaxf(f8f(xq0.y>>24)+bhi(uv0.w),0.f));
    a1.u4.x = pkbf(fmaxf(f8f(xq1.x&255u)+blo(uv1.x),0.f),       fmaxf(f8f((xq1.x>>8)&255u)+bhi(uv1.x),0.f));
    a1.u4.y = pkbf(fmaxf(f8f((xq1.x>>16)&255u)+blo(uv1.y),0.f), fmaxf(f8f(xq1.x>>24)+bhi(uv1.y),0.f));
    a1.u4.z = pkbf(fmaxf(f8f(xq1.y&255u)+blo(uv1.z),0.f),       fmaxf(f8f((xq1.y>>8)&255u)+bhi(uv1.z),0.f));
    a1.u4.w = pkbf(fmaxf(f8f((xq1.y>>16)&255u)+blo(uv1.w),0.f), fmaxf(f8f(xq1.y>>24)+bhi(uv1.w),0.f));
    f32x4 acc[4];
#pragma unroll
    for(int nt=0; nt<4; ++nt){
      f32x4 c0 = { b2v[nt], b2v[nt], b2v[nt], b2v[nt] };
      c0 = __builtin_amdgcn_mfma_f32_16x16x32_bf16(a0.v, bf[nt][0], c0, 0, 0, 0);
      c0 = __builtin_amdgcn_mfma_f32_16x16x32_bf16(a1.v, bf[nt][1], c0, 0, 0, 0);
      acc[nt] = c0;
    }
    float s0=0.f, s1=0.f, s2=0.f, s3=0.f;
#pragma unroll
    for(int nt=0; nt<4; ++nt){
      s0 += fmaxf(acc[nt][0], 0.f) * a3v[nt];
      s1 += fmaxf(acc[nt][1], 0.f) * a3v[nt];
      s2 += fmaxf(acc[nt][2], 0.f) * a3v[nt];
      s3 += fmaxf(acc[nt][3], 0.f) * a3v[nt];
    }
#pragma unroll
    for(int mask=1; mask<16; mask<<=1){
      s0 += __shfl_xor(s0, mask);
      s1 += __shfl_xor(s1, mask);
      s2 += __shfl_xor(s2, mask);
      s3 += __shfl_xor(s3, mask);
    }
    if(lr == 0){
      int e0 = base + w*64 + t*16 + g*4;
      if(e0+0 < E_N) wlog[e0+0] = s0 + a3b0;
      if(e0+1 < E_N) wlog[e0+1] = s1 + a3b0;
      if(e0+2 < E_N) wlog[e0+2] = s2 + a3b0;
      if(e0+3 < E_N) wlog[e0+3] = s3 + a3b0;
    }
  };

  // depth-2 software pipeline
  uint2 xA0 = *(const uint2*)(xa1p8 + (size_t)cin[0]*64 + g*8);
  uint2 xA1 = *(const uint2*)(xa1p8 + (size_t)cin[0]*64 + 32 + g*8);
  uint4 uA0 = userp[(size_t)uin[0]*8 + g];
  uint4 uA1 = userp[(size_t)uin[0]*8 + 4 + g];
  uint2 xB0 = *(const uint2*)(xa1p8 + (size_t)cin[1]*64 + g*8);
  uint2 xB1 = *(const uint2*)(xa1p8 + (size_t)cin[1]*64 + 32 + g*8);
  uint4 uB0 = userp[(size_t)uin[1]*8 + g];
  uint4 uB1 = userp[(size_t)uin[1]*8 + 4 + g];

  compute(xA0, xA1, uA0, uA1, 0);
  xA0 = *(const uint2*)(xa1p8 + (size_t)cin[2]*64 + g*8);
  xA1 = *(const uint2*)(xa1p8 + (size_t)cin[2]*64 + 32 + g*8);
  uA0 = userp[(size_t)uin[2]*8 + g];
  uA1 = userp[(size_t)uin[2]*8 + 4 + g];
  compute(xB0, xB1, uB0, uB1, 1);
  xB0 = *(const uint2*)(xa1p8 + (size_t)cin[3]*64 + g*8);
  xB1 = *(const uint2*)(xa1p8 + (size_t)cin[3]*64 + 32 + g*8);
  uB0 = userp[(size_t)uin[3]*8 + g];
  uB1 = userp[(size_t)uin[3]*8 + 4 + g];
  compute(xA0, xA1, uA0, uA1, 2);
  compute(xB0, xB1, uB0, uB1, 3);
}

// ---------------- fused softmax + MFMA aggregate (double-buffered Y staging) ----------------
__global__ __launch_bounds__(256) void k_aggf(const int* __restrict__ start,
                                              const unsigned* __restrict__ uc3,
                                              const float* __restrict__ wlog,
                                              const u16* __restrict__ Y,
                                              const float* __restrict__ wb,
                                              float* __restrict__ out){
  __shared__ uint4 Ysh[2][4][256];
  int w = threadIdx.x >> 6, l = threadIdx.x & 63;
  int lr = l & 15, g = l >> 4;
  int base = (blockIdx.x*4 + w) * 16;
  if(base >= U_N) return;
  int s0g = start[base];
  int s1g = start[base+16];
  unsigned ml = (unsigned)((base + lr) & 16383);
  int sA = s0g & ~31;
  int nch = (s1g - sA + 31) >> 5;
  const int kb = g*8;

  // phase 1: masked max
  float m = -1e30f;
  for(int ch=0; ch<nch; ++ch){
    int e0 = sA + ch*32;
    float4 wv0 = *(const float4*)(wlog + e0 + kb);
    float4 wv1 = *(const float4*)(wlog + e0 + kb + 4);
    uint4 v0 = *(const uint4*)(uc3 + e0 + kb);
    uint4 v1 = *(const uint4*)(uc3 + e0 + kb + 4);
    if((v0.x>>18)==ml) m = fmaxf(m, wv0.x);
    if((v0.y>>18)==ml) m = fmaxf(m, wv0.y);
    if((v0.z>>18)==ml) m = fmaxf(m, wv0.z);
    if((v0.w>>18)==ml) m = fmaxf(m, wv0.w);
    if((v1.x>>18)==ml) m = fmaxf(m, wv1.x);
    if((v1.y>>18)==ml) m = fmaxf(m, wv1.y);
    if((v1.z>>18)==ml) m = fmaxf(m, wv1.z);
    if((v1.w>>18)==ml) m = fmaxf(m, wv1.w);
  }
  m = fmaxf(m, __shfl_xor(m, 16));
  m = fmaxf(m, __shfl_xor(m, 32));

  // phase 2: double-buffered stage + MFMA with p=exp(x-m)
  f32x4 acc[4];
#pragma unroll
  for(int nt=0; nt<4; ++nt) acc[nt] = f32x4{0.f,0.f,0.f,0.f};
  float ssum = 0.f;
  int buf = 0;
  if(nch > 0){
    int rowe = sA + (l>>1);
    int crow = (int)(uc3[rowe] & 0x3FFFFu);
    const uint4* yp = (const uint4*)Y + (size_t)crow*8 + (l&1)*4;
    uint4 y0=yp[0], y1=yp[1], y2=yp[2], y3=yp[3];
    uint4* dst = &Ysh[0][w][(l>>1)*8 + (l&1)*4];
    dst[0]=y0; dst[1]=y1; dst[2]=y2; dst[3]=y3;
  }
  for(int ch=0; ch<nch; ++ch){
    int e0 = sA + ch*32;
    uint4 n0, n1, n2, n3;
    bool hasNext = (ch+1 < nch);
    if(hasNext){
      int rowe = e0 + 32 + (l>>1);
      int crowN = (int)(uc3[rowe] & 0x3FFFFu);
      const uint4* yp = (const uint4*)Y + (size_t)crowN*8 + (l&1)*4;
      n0=yp[0]; n1=yp[1]; n2=yp[2]; n3=yp[3];
    }
    float4 wv0 = *(const float4*)(wlog + e0 + kb);
    float4 wv1 = *(const float4*)(wlog + e0 + kb + 4);
    uint4 v0 = *(const uint4*)(uc3 + e0 + kb);
    uint4 v1 = *(const uint4*)(uc3 + e0 + kb + 4);
    bf16x8 af;
    {
      bool mt; float e;
      mt = ((v0.x>>18)==ml); e = __expf((mt?wv0.x:-1e30f) - m); ssum += mt?e:0.f; af[0] = mt?(short)f2b(e):(short)0;
      mt = ((v0.y>>18)==ml); e = __expf((mt?wv0.y:-1e30f) - m); ssum += mt?e:0.f; af[1] = mt?(short)f2b(e):(short)0;
      mt = ((v0.z>>18)==ml); e = __expf((mt?wv0.z:-1e30f) - m); ssum += mt?e:0.f; af[2] = mt?(short)f2b(e):(short)0;
      mt = ((v0.w>>18)==ml); e = __expf((mt?wv0.w:-1e30f) - m); ssum += mt?e:0.f; af[3] = mt?(short)f2b(e):(short)0;
      mt = ((v1.x>>18)==ml); e = __expf((mt?wv1.x:-1e30f) - m); ssum += mt?e:0.f; af[4] = mt?(short)f2b(e):(short)0;
      mt = ((v1.y>>18)==ml); e = __expf((mt?wv1.y:-1e30f) - m); ssum += mt?e:0.f; af[5] = mt?(short)f2b(e):(short)0;
      mt = ((v1.z>>18)==ml); e = __expf((mt?wv1.z:-1e30f) - m); ssum += mt?e:0.f; af[6] = mt?(short)f2b(e):(short)0;
      mt = ((v1.w>>18)==ml); e = __expf((mt?wv1.w:-1e30f) - m); ssum += mt?e:0.f; af[7] = mt?(short)f2b(e):(short)0;
    }
    u16* Ysh16 = (u16*)&Ysh[buf][w][0];
    bf16x8 b0, b1, b2, b3;
#pragma unroll
    for(int j=0; j<8; ++j){
      int r = (kb + j)*64 + lr;
      b0[j] = (short)Ysh16[r];
      b1[j] = (short)Ysh16[r+16];
      b2[j] = (short)Ysh16[r+32];
      b3[j] = (short)Ysh16[r+48];
    }
    acc[0] = __builtin_amdgcn_mfma_f32_16x16x32_bf16(af, b0, acc[0], 0, 0, 0);
    acc[1] = __builtin_amdgcn_mfma_f32_16x16x32_bf16(af, b1, acc[1], 0, 0, 0);
    acc[2] = __builtin_amdgcn_mfma_f32_16x16x32_bf16(af, b2, acc[2], 0, 0, 0);
    acc[3] = __builtin_amdgcn_mfma_f32_16x16x32_bf16(af, b3, acc[3], 0, 0, 0);
    if(hasNext){
      uint4* dst = &Ysh[buf^1][w][(l>>1)*8 + (l&1)*4];
      dst[0]=n0; dst[1]=n1; dst[2]=n2; dst[3]=n3;
    }
    buf ^= 1;
  }
  ssum += __shfl_xor(ssum, 16);
  ssum += __shfl_xor(ssum, 32);
  float inv = (ssum > 0.f) ? (1.f/ssum) : 0.f;
  float wbv[4];
#pragma unroll
  for(int nt=0; nt<4; ++nt) wbv[nt] = wb[nt*16 + lr];
#pragma unroll
  for(int reg=0; reg<4; ++reg){
    float sc = __shfl(inv, g*4 + reg);
    int u = base + g*4 + reg;
#pragma unroll
    for(int nt=0; nt<4; ++nt)
      out[(size_t)u*64 + nt*16 + lr] = acc[nt][reg]*sc + wbv[nt];
  }
}

extern "C" void kernel_launch(void* const* d_in, const int* in_sizes, int n_in,
                              void* d_out, int out_size, void* d_ws, size_t ws_size,
                              hipStream_t stream){
  (void)in_sizes; (void)n_in; (void)out_size; (void)ws_size;
  const float4* user_feat  = (const float4*)d_in[0];
  const float4* item_feat  = (const float4*)d_in[1];
  const float*  rating_feat= (const float*)d_in[2];
  const int*    rows       = (const int*)d_in[3];
  const int*    cols       = (const int*)d_in[4];
  const int*    rats       = (const int*)d_in[5];
  const float* gv_w1 = (const float*)d_in[6];
  const float* gv_b1 = (const float*)d_in[7];
  const float* gv_w2 = (const float*)d_in[8];
  const float* gv_b2 = (const float*)d_in[9];
  const float* att_w1= (const float*)d_in[10];
  const float* att_b1= (const float*)d_in[11];
  const float* att_w2= (const float*)d_in[12];
  const float* att_b2= (const float*)d_in[13];
  const float* att_w3= (const float*)d_in[14];
  const float* att_b3= (const float*)d_in[15];
  const float* w_w   = (const float*)d_in[16];
  const float* w_b   = (const float*)d_in[17];
  float* out = (float*)d_out;

  char* ws = (char*)d_ws; size_t off = 0;
  auto take = [&](size_t b)->char*{ char* p = ws + off; off = (off + b + 255) & ~(size_t)255; return p; };
  bf16_t*   item_part  = (bf16_t*)take((size_t)I_N*64*2);
  bf16_t*   user_part  = (bf16_t*)take((size_t)U_N*64*2);
  float*    rating_part= (float*) take((size_t)R_N*64*4);
  bf16_t*   y_t        = (bf16_t*)take((size_t)C_N*64*2);
  u8*       xa1_8      = (u8*)    take((size_t)C_N*64);
  float*    wlog_s     = (float*) take((size_t)E_N*4);
  unsigned* uc3        = (unsigned*)take((size_t)E_N*4);
  unsigned* uc2        = (unsigned*)take((size_t)E_N*4);
  int*      hist_g     = (int*)   take((size_t)NBLK_E*NBUCKC*4);
  int*      boff_g     = (int*)   take((size_t)NBLK_E*NBUCKC*4);
  int*      qtot       = (int*)   take((size_t)256*4);
  int*      qbase      = (int*)   take((size_t)256*4);
  int*      blockq     = (int*)   take((size_t)NBLK_E*4);
  int*      cnt        = (int*)   take((size_t)(NBUCKC*512+256)*4);
  int*      start      = (int*)   take((size_t)(NBUCKC*512+256)*4);
  int*      bsum       = (int*)   take((size_t)512*4);
  u16*      w1t        = (u16*)   take((size_t)4096*2);
  u16*      u1t        = (u16*)   take((size_t)4096*2);
  u16*      w2t        = (u16*)   take((size_t)4096*2);
  u16*      a1t        = (u16*)   take((size_t)4096*2);
  u16*      a2t        = (u16*)   take((size_t)4096*2);
  u16*      wwt        = (u16*)   take((size_t)4096*2);

  // CSR build
  k_histQ <<<NBLK_E, 256, 0, stream>>>(cols, hist_g);
  k_scanQ <<<NBUCKC, 256, 0, stream>>>(hist_g, boff_g, qtot);
  k_scanT <<<1, 256, 0, stream>>>(qtot, qbase);
  k_blockq<<<(NBLK_E+255)/256, 256, 0, stream>>>(qbase, blockq);
  k_place2<<<NBLK_E, 256, 0, stream>>>(rows, cols, rats, boff_g, qbase, uc2);
  k_fineB1<<<NBUCKC, 256, 0, stream>>>(uc2, qbase, cnt);
  k_scanA <<<NBLK_U, 256, 0, stream>>>(cnt, start, bsum);
  k_scanB <<<1, 512, 0, stream>>>(bsum, NBLK_U);
  k_scanC <<<NBLK_U, 256, 0, stream>>>(start, bsum);
  k_fineB2<<<NBUCKC, 256, 0, stream>>>(uc2, qbase, start, uc3);
  // weights + tiny GEMV
  k_ratpart <<<1, 320, 0, stream>>>(rating_feat, gv_w1, gv_b1, rating_part);
  k_prepw6  <<<96, 256, 0, stream>>>(gv_w1, att_w1, gv_w2, att_w2, w_w, w1t, u1t, w2t, a1t, a2t, wwt);
  // dense precompute (MFMA)
  k_rowgemm<false><<<(I_N+255)/256, 256, 0, stream>>>(item_feat, (const uint4*)w1t, nullptr,
                                                      (uint4*)item_part, I_N);
  k_rowgemm<true> <<<NBLK_U, 256, 0, stream>>>(user_feat, (const uint4*)u1t, att_b1,
                                               (uint4*)user_part, U_N);
  k_combo_mfma<<<NBLK_C, 256, 0, stream>>>((const uint4*)item_part, (const float4*)rating_part,
                                           (const uint4*)w2t, (const uint4*)a1t, (const uint4*)wwt, gv_b2,
                                           (uint4*)y_t, xa1_8);
  // per-edge logits
  k_edge_mfma<<<NBLK_E, 256, 0, stream>>>(uc3, qbase, blockq, xa1_8, (const uint4*)user_part,
                                          w2t, att_b2, att_w3, att_b3, wlog_s);
  // fused softmax + aggregate + projection
  k_aggf <<<(U_N/64)+1, 256, 0, stream>>>(start, uc3, wlog_s, (const u16*)y_t, w_b, out);
}

// Round 16
// 263.806 us; speedup vs baseline: 1.8653x; 1.1116x over previous
//
#include <hip/hip_runtime.h>
#include <hip/hip_bf16.h>
#include <hip/hip_fp8.h>

#define U_N 100000
#define I_N 50000
#define E_N 2000000
#define R_N 5
#define C_N (I_N*R_N)   // 250000 combos
#define NBLK_E 7813     // ceil(2000000/256)
#define NBLK_C 1954     // ceil(250000/128)
#define NBUCKC 196      // ceil(100000/512) coarse buckets

typedef __hip_bfloat16 bf16_t;
typedef unsigned short u16;
typedef unsigned char u8;
typedef __attribute__((ext_vector_type(8))) short bf16x8;
typedef __attribute__((ext_vector_type(4))) float f32x4;

__device__ __forceinline__ float blo(unsigned u){ return __uint_as_float(u<<16); }
__device__ __forceinline__ float bhi(unsigned u){ return __uint_as_float(u & 0xffff0000u); }
__device__ __forceinline__ unsigned pkbf(float a, float b){
  __hip_bfloat162 t = __float22bfloat162_rn(float2{a,b});
  union { __hip_bfloat162 h; unsigned u; } cv; cv.h = t; return cv.u;
}
__device__ __forceinline__ u16 f2b(float v){
  union { __hip_bfloat16 h; u16 u; } cv; cv.h = __float2bfloat16(v); return cv.u;
}
__device__ __forceinline__ unsigned ff8(float f){
  __hip_fp8_e4m3 h(f); return (unsigned)h.__x;
}
__device__ __forceinline__ float2 f8x2(u16 h){
  __hip_fp8x2_e4m3 v; v.__x = h; return (float2)v;
}

// ================= CSR build =================
__global__ __launch_bounds__(256) void k_histQ(const int* __restrict__ cols, int* __restrict__ hist_g){
  __shared__ int histI[NBUCKC];
  int t = threadIdx.x, b = blockIdx.x;
  if(t < NBUCKC) histI[t] = 0;
  __syncthreads();
  int e = b*256 + t;
  if(e < E_N) atomicAdd(&histI[cols[e] >> 9], 1);
  __syncthreads();
  if(t < NBUCKC) hist_g[(size_t)b*NBUCKC + t] = histI[t];
}

__global__ __launch_bounds__(256) void k_scanQ(const int* __restrict__ hist_g, int* __restrict__ boff_g,
                                               int* __restrict__ qtot){
  __shared__ int wsum[4];
  int t = threadIdx.x, q = blockIdx.x;
  int lane = t & 63, wv = t >> 6;
  int running = 0;
  for(int c0=0; c0<NBLK_E; c0+=256){
    int b = c0 + t;
    int v = (b < NBLK_E) ? hist_g[(size_t)b*NBUCKC + q] : 0;
    int inc = v;
#pragma unroll
    for(int off=1; off<64; off<<=1){
      int x = __shfl(inc, lane-off);
      if(lane >= off) inc += x;
    }
    if(lane == 63) wsum[wv] = inc;
    __syncthreads();
    int w0=wsum[0], w1=wsum[1], w2=wsum[2], w3=wsum[3];
    int wpre = (wv>0?w0:0) + (wv>1?w1:0) + (wv>2?w2:0);
    if(b < NBLK_E) boff_g[(size_t)b*NBUCKC + q] = running + wpre + inc - v;
    running += w0 + w1 + w2 + w3;
    __syncthreads();
  }
  if(t == 0) qtot[q] = running;
}

__global__ void k_scanT(const int* __restrict__ qtot, int* __restrict__ qbase){
  __shared__ int s[256];
  int t = threadIdx.x;
  int v = (t < NBUCKC) ? qtot[t] : 0;
  s[t] = v; __syncthreads();
  for(int off=1; off<256; off<<=1){
    int x = (t>=off) ? s[t-off] : 0;
    __syncthreads();
    s[t] += x;
    __syncthreads();
  }
  if(t < NBUCKC) qbase[t] = s[t] - v;
  if(t == 255)   qbase[NBUCKC] = s[255];
}

__global__ __launch_bounds__(256) void k_blockq(const int* __restrict__ qbase, int* __restrict__ blockq){
  int b = blockIdx.x*256 + threadIdx.x; if(b >= NBLK_E) return;
  int e = b*256;
  int lo = 0, hi = NBUCKC-1;
  while(lo < hi){ int mid = (lo+hi+1)>>1; if(qbase[mid] <= e) lo = mid; else hi = mid-1; }
  blockq[b] = lo;
}

__global__ __launch_bounds__(256) void k_place2(const int* __restrict__ rows, const int* __restrict__ cols,
                                                const int* __restrict__ rats,
                                                const int* __restrict__ boff_g, const int* __restrict__ qbase,
                                                unsigned* __restrict__ uc2){
  __shared__ int rankI[NBUCKC];
  __shared__ int baseI[NBUCKC];
  int t = threadIdx.x, b = blockIdx.x;
  if(t < NBUCKC){
    rankI[t] = 0;
    baseI[t] = qbase[t] + boff_g[(size_t)b*NBUCKC + t];
  }
  __syncthreads();
  int e = b*256 + t;
  if(e < E_N){
    int u = cols[e];
    int c = rows[e]*5 + rats[e];
    int q = u >> 9;
    int r = atomicAdd(&rankI[q], 1);
    uc2[baseI[q] + r] = ((unsigned)(u & 16383) << 18) | (unsigned)c;
  }
}

// fused fine sort: per-bucket 512-user histogram + LDS scan + start write + place (no global scans)
__global__ __launch_bounds__(256) void k_fine(const unsigned* __restrict__ uc2, const int* __restrict__ qbase,
                                              unsigned* __restrict__ uc3, int* __restrict__ start){
  __shared__ int histv[512];
  __shared__ int s[512];
  __shared__ int fillb[512];
  int t = threadIdx.x, q = blockIdx.x;
  histv[t]=0; histv[t+256]=0; fillb[t]=0; fillb[t+256]=0;
  __syncthreads();
  int r0 = qbase[q], r1 = qbase[q+1];
  for(int j=r0+t; j<r1; j+=256) atomicAdd(&histv[(uc2[j]>>18)&511], 1);
  __syncthreads();
  s[t]=histv[t]; s[t+256]=histv[t+256];
  __syncthreads();
  for(int off=1; off<512; off<<=1){
    int a0 = (t>=off)? s[t-off] : 0;
    int a1 = (t+256>=off)? s[t+256-off] : 0;
    __syncthreads();
    s[t]+=a0; s[t+256]+=a1;
    __syncthreads();
  }
  int e0 = s[t]-histv[t], e1 = s[t+256]-histv[t+256];   // exclusive local starts
  start[q*512+t]     = r0 + e0;
  start[q*512+t+256] = r0 + e1;
  s[t]=e0; s[t+256]=e1;
  __syncthreads();
  for(int j=r0+t; j<r1; j+=256){
    unsigned v = uc2[j];
    int ul = (int)((v>>18)&511);
    int off = atomicAdd(&fillb[ul], 1);
    uc3[r0 + s[ul] + off] = v;
  }
}

// ---------------- tiny precompute ----------------
__global__ void k_ratpart(const float* __restrict__ rf, const float* __restrict__ w1,
                          const float* __restrict__ b1, float* __restrict__ out){
  int t = threadIdx.x; if(t >= R_N*64) return;
  int r = t>>6, d = t&63;
  float acc = b1[d];
  for(int k=0;k<64;k++) acc += rf[r*64 + k] * w1[(64+k)*64 + d];
  out[t] = acc;
}

__global__ __launch_bounds__(256) void k_prepw6(const float* __restrict__ w1, const float* __restrict__ a1,
                                                const float* __restrict__ w2, const float* __restrict__ a2,
                                                const float* __restrict__ ww,
                                                u16* w1t, u16* u1t, u16* w2t, u16* a1t, u16* a2t, u16* wwt){
  int idx = (blockIdx.x & 15)*256 + threadIdx.x;
  int sec = blockIdx.x >> 4;
  int d = idx >> 6, k = idx & 63;
  const float* src; u16* dst; int ko = 0;
  switch(sec){
    case 0: src=w1; dst=w1t; break;
    case 1: src=a1; dst=u1t; ko=64; break;
    case 2: src=w2; dst=w2t; break;
    case 3: src=a1; dst=a1t; break;
    case 4: src=a2; dst=a2t; break;
    default: src=ww; dst=wwt; break;
  }
  dst[idx] = f2b(src[(size_t)(ko+k)*64 + d]);
}

// ---------------- MFMA row-GEMM ----------------
template<bool BIAS>
__global__ __launch_bounds__(256) void k_rowgemm(const float4* __restrict__ in,
                                                 const uint4* __restrict__ wt,
                                                 const float* __restrict__ bias,
                                                 uint4* __restrict__ outp, int n){
  __shared__ uint4 A_u4[2048];
  __shared__ uint4 W_u4[512];
  __shared__ float bsh[64];
  u16* A16 = (u16*)A_u4;
  const int tid = threadIdx.x;
  for(int cid = tid; cid < 512; cid += 256){
    int dd = cid >> 3, ch = cid & 7;
    W_u4[dd*8 + (ch ^ (dd&7))] = wt[cid];
  }
  if(BIAS && tid < 64) bsh[tid] = bias[tid];
  const int base = blockIdx.x*256;
  const int ch = tid & 7;
#pragma unroll
  for(int it=0; it<8; ++it){
    int s = it*32 + (tid>>3);
    int r = base + s;
    uint4 o = {0,0,0,0};
    if(r < n){
      const float4* p = in + (size_t)r*16 + ch*2;
      float4 v0 = p[0], v1 = p[1];
      o.x = pkbf(v0.x, v0.y); o.y = pkbf(v0.z, v0.w);
      o.z = pkbf(v1.x, v1.y); o.w = pkbf(v1.z, v1.w);
    }
    A_u4[s*8 + (ch ^ (s&7))] = o;
  }
  __syncthreads();
  const int l = tid & 63, w = tid >> 6;
  const int lr = l & 15, g = l >> 4;
  bf16x8 bfr[4][2];
#pragma unroll
  for(int nt=0; nt<4; ++nt)
#pragma unroll
    for(int kk=0; kk<2; ++kk){
      int d = nt*16 + lr;
      bfr[nt][kk] = *(const bf16x8*)&W_u4[d*8 + ((kk*4+g) ^ (d&7))];
    }
  float bv[4];
#pragma unroll
  for(int nt=0; nt<4; ++nt) bv[nt] = BIAS ? bsh[nt*16 + lr] : 0.f;
#pragma unroll
  for(int t=0; t<4; ++t){
    int s = w*64 + t*16 + lr;
    bf16x8 af0 = *(const bf16x8*)&A_u4[s*8 + ((0*4+g) ^ (s&7))];
    bf16x8 af1 = *(const bf16x8*)&A_u4[s*8 + ((1*4+g) ^ (s&7))];
    f32x4 acc[4];
#pragma unroll
    for(int nt=0; nt<4; ++nt){
      f32x4 c0 = { bv[nt], bv[nt], bv[nt], bv[nt] };
      c0 = __builtin_amdgcn_mfma_f32_16x16x32_bf16(af0, bfr[nt][0], c0, 0, 0, 0);
      c0 = __builtin_amdgcn_mfma_f32_16x16x32_bf16(af1, bfr[nt][1], c0, 0, 0, 0);
      acc[nt] = c0;
    }
#pragma unroll
    for(int nt=0; nt<4; ++nt){
      int d = nt*16 + lr;
#pragma unroll
      for(int reg=0; reg<4; ++reg){
        int srow = w*64 + t*16 + g*4 + reg;
        A16[srow*64 + ((d>>3)^(srow&7))*8 + (d&7)] = f2b(acc[nt][reg]);
      }
    }
  }
#pragma unroll
  for(int it=0; it<8; ++it){
    int s = w*64 + it*8 + (l>>3);
    int c2 = l & 7;
    int r = base + s;
    if(r < n) outp[(size_t)r*8 + c2] = A_u4[s*8 + (c2 ^ (s&7))];
  }
}

// ---------------- combo: y_o (bf16) + xa1_o (fp8 e4m3) ----------------
__global__ __launch_bounds__(256) void k_combo_mfma(const uint4* __restrict__ itemp,
                                                    const float4* __restrict__ ratp,
                                                    const uint4* __restrict__ w2t_g, const uint4* __restrict__ a1t_g,
                                                    const uint4* __restrict__ wwt_g,
                                                    const float* __restrict__ b2,
                                                    uint4* __restrict__ y_o, u8* __restrict__ xa1_o8){
  __shared__ uint4 A_u4[1024];
  __shared__ uint4 X_u4[1024];
  __shared__ uint4 W2_u4[512];
  __shared__ uint4 A1_u4[512];
  __shared__ uint4 WW_u4[512];
  __shared__ float4 rsh4[80];
  __shared__ float b2sh[64];
  u16* A16 = (u16*)A_u4;
  u16* X16 = (u16*)X_u4;
  const int tid = threadIdx.x;
  for(int cid = tid; cid < 512; cid += 256){
    int dd = cid >> 3, ch = cid & 7;
    W2_u4[dd*8 + (ch ^ (dd&7))] = w2t_g[cid];
    A1_u4[dd*8 + (ch ^ (dd&7))] = a1t_g[cid];
    WW_u4[dd*8 + (ch ^ (dd&7))] = wwt_g[cid];
  }
  if(tid < 80) rsh4[tid] = ratp[tid];
  if(tid < 64) b2sh[tid] = b2[tid];
  __syncthreads();

  const int base = blockIdx.x*128;
  const int ch = tid & 7;
#pragma unroll
  for(int it=0; it<4; ++it){
    int s = it*32 + (tid>>3);
    int cidx = base + s;
    uint4 o = {0,0,0,0};
    if(cidx < C_N){
      int i = cidx/5, r = cidx - i*5;
      uint4 iv = itemp[(size_t)i*8 + ch];
      float4 r0 = rsh4[r*16 + ch*2], r1 = rsh4[r*16 + ch*2 + 1];
      o.x = pkbf(fmaxf(blo(iv.x)+r0.x,0.f), fmaxf(bhi(iv.x)+r0.y,0.f));
      o.y = pkbf(fmaxf(blo(iv.y)+r0.z,0.f), fmaxf(bhi(iv.y)+r0.w,0.f));
      o.z = pkbf(fmaxf(blo(iv.z)+r1.x,0.f), fmaxf(bhi(iv.z)+r1.y,0.f));
      o.w = pkbf(fmaxf(blo(iv.w)+r1.z,0.f), fmaxf(bhi(iv.w)+r1.w,0.f));
    }
    A_u4[s*8 + (ch ^ (s&7))] = o;
  }
  __syncthreads();

  const int l = tid & 63, w = tid >> 6;
  const int lr = l & 15, g = l >> 4;
  bf16x8 w2f[4][2], a1f[4][2], wwf[4][2];
#pragma unroll
  for(int nt=0; nt<4; ++nt)
#pragma unroll
    for(int kk=0; kk<2; ++kk){
      int d = nt*16 + lr;
      w2f[nt][kk] = *(const bf16x8*)&W2_u4[d*8 + ((kk*4+g) ^ (d&7))];
      a1f[nt][kk] = *(const bf16x8*)&A1_u4[d*8 + ((kk*4+g) ^ (d&7))];
      wwf[nt][kk] = *(const bf16x8*)&WW_u4[d*8 + ((kk*4+g) ^ (d&7))];
    }
  float b2v[4];
#pragma unroll
  for(int nt=0; nt<4; ++nt) b2v[nt] = b2sh[nt*16 + lr];

#pragma unroll
  for(int t=0; t<2; ++t){
    int s = w*32 + t*16 + lr;
    bf16x8 af0 = *(const bf16x8*)&A_u4[s*8 + ((0*4+g) ^ (s&7))];
    bf16x8 af1 = *(const bf16x8*)&A_u4[s*8 + ((1*4+g) ^ (s&7))];
#pragma unroll
    for(int nt=0; nt<4; ++nt){
      f32x4 c0 = { b2v[nt], b2v[nt], b2v[nt], b2v[nt] };
      c0 = __builtin_amdgcn_mfma_f32_16x16x32_bf16(af0, w2f[nt][0], c0, 0, 0, 0);
      c0 = __builtin_amdgcn_mfma_f32_16x16x32_bf16(af1, w2f[nt][1], c0, 0, 0, 0);
      int d = nt*16 + lr;
#pragma unroll
      for(int reg=0; reg<4; ++reg){
        int srow = w*32 + t*16 + g*4 + reg;
        X16[srow*64 + ((d>>3)^(srow&7))*8 + (d&7)] = f2b(fmaxf(c0[reg], 0.f));
      }
    }
    bf16x8 xf0 = *(const bf16x8*)&X_u4[s*8 + ((0*4+g) ^ (s&7))];
    bf16x8 xf1 = *(const bf16x8*)&X_u4[s*8 + ((1*4+g) ^ (s&7))];
#pragma unroll
    for(int nt=0; nt<4; ++nt){
      f32x4 c0 = { 0.f, 0.f, 0.f, 0.f };
      c0 = __builtin_amdgcn_mfma_f32_16x16x32_bf16(xf0, a1f[nt][0], c0, 0, 0, 0);
      c0 = __builtin_amdgcn_mfma_f32_16x16x32_bf16(xf1, a1f[nt][1], c0, 0, 0, 0);
      int d = nt*16 + lr;
#pragma unroll
      for(int reg=0; reg<4; ++reg){
        int srow = w*32 + t*16 + g*4 + reg;
        A16[srow*64 + ((d>>3)^(srow&7))*8 + (d&7)] = f2b(c0[reg]);
      }
    }
#pragma unroll
    for(int nt=0; nt<4; ++nt){
      f32x4 c0 = { 0.f, 0.f, 0.f, 0.f };
      c0 = __builtin_amdgcn_mfma_f32_16x16x32_bf16(xf0, wwf[nt][0], c0, 0, 0, 0);
      c0 = __builtin_amdgcn_mfma_f32_16x16x32_bf16(xf1, wwf[nt][1], c0, 0, 0, 0);
      int d = nt*16 + lr;
#pragma unroll
      for(int reg=0; reg<4; ++reg){
        int srow = w*32 + t*16 + g*4 + reg;
        X16[srow*64 + ((d>>3)^(srow&7))*8 + (d&7)] = f2b(c0[reg]);
      }
    }
  }
#pragma unroll
  for(int it=0; it<4; ++it){
    int s = w*32 + it*8 + (l>>3);
    int c2 = l & 7;
    int r = base + s;
    if(r < C_N) y_o[(size_t)r*8 + c2] = X_u4[s*8 + (c2 ^ (s&7))];
  }
#pragma unroll
  for(int it=0; it<2; ++it){
    int slot = it*64 + l;
    int rl = slot >> 2;
    int c4 = slot & 3;
    int s = w*32 + rl;
    int r = base + s;
    if(r < C_N){
      uint4 h0 = A_u4[s*8 + ((c4*2+0) ^ (s&7))];
      uint4 h1 = A_u4[s*8 + ((c4*2+1) ^ (s&7))];
      uint4 o;
      o.x = ff8(blo(h0.x)) | (ff8(bhi(h0.x))<<8) | (ff8(blo(h0.y))<<16) | (ff8(bhi(h0.y))<<24);
      o.y = ff8(blo(h0.z)) | (ff8(bhi(h0.z))<<8) | (ff8(blo(h0.w))<<16) | (ff8(bhi(h0.w))<<24);
      o.z = ff8(blo(h1.x)) | (ff8(bhi(h1.x))<<8) | (ff8(blo(h1.y))<<16) | (ff8(bhi(h1.y))<<24);
      o.w = ff8(blo(h1.z)) | (ff8(bhi(h1.z))<<8) | (ff8(blo(h1.w))<<16) | (ff8(bhi(h1.w))<<24);
      *(uint4*)(xa1_o8 + (size_t)r*64 + c4*16) = o;
    }
  }
}

// ---------------- MFMA edge-logit kernel: LDS-free, depth-2, pk fp8 decode ----------------
__global__ __launch_bounds__(256) void k_edge_mfma(const unsigned* __restrict__ uc3,
                                                   const int* __restrict__ qbase, const int* __restrict__ blockq,
                                                   const u8* __restrict__ xa1p8, const uint4* __restrict__ userp,
                                                   const u16* __restrict__ w2t_g,
                                                   const float* __restrict__ a2b,
                                                   const float* __restrict__ a3w, const float* __restrict__ a3b,
                                                   float* __restrict__ wlog){
  const int tid = threadIdx.x;
  const int base = blockIdx.x*256;
  const int l = tid & 63, w = tid >> 6;
  const int lr = l & 15;
  const int g  = l >> 4;
  bf16x8 bf[4][2];
#pragma unroll
  for(int nt=0; nt<4; ++nt)
#pragma unroll
    for(int kk=0; kk<2; ++kk){
      int d = nt*16 + lr;
      bf[nt][kk] = *(const bf16x8*)(w2t_g + d*64 + kk*32 + g*8);
    }
  float b2v[4], a3v[4];
#pragma unroll
  for(int nt=0; nt<4; ++nt){ b2v[nt] = a2b[nt*16 + lr]; a3v[nt] = a3w[nt*16 + lr]; }
  const float a3b0 = a3b[0];

  int cin[4], uin[4];
  int bq = blockq[blockIdx.x];
#pragma unroll
  for(int t=0; t<4; ++t){
    int s = base + w*64 + t*16 + lr;
    int sc = (s < E_N) ? s : (E_N-1);
    unsigned vv = (s < E_N) ? uc3[s] : 0u;
    int q = bq;
    while(sc >= qbase[q+1]) ++q;
    cin[t] = (int)(vv & 0x3FFFFu);
    uin[t] = (q<<9) | (int)((vv>>18) & 511u);
  }

  auto compute = [&](uint2 xq0, uint2 xq1, uint4 uv0, uint4 uv1, int t){
    union { uint4 u4; bf16x8 v; } a0, a1;
    {
      float2 p01 = f8x2((u16)xq0.x), p23 = f8x2((u16)(xq0.x>>16));
      float2 p45 = f8x2((u16)xq0.y), p67 = f8x2((u16)(xq0.y>>16));
      a0.u4.x = pkbf(fmaxf(p01.x+blo(uv0.x),0.f), fmaxf(p01.y+bhi(uv0.x),0.f));
      a0.u4.y = pkbf(fmaxf(p23.x+blo(uv0.y),0.f), fmaxf(p23.y+bhi(uv0.y),0.f));
      a0.u4.z = pkbf(fmaxf(p45.x+blo(uv0.z),0.f), fmaxf(p45.y+bhi(uv0.z),0.f));
      a0.u4.w = pkbf(fmaxf(p67.x+blo(uv0.w),0.f), fmaxf(p67.y+bhi(uv0.w),0.f));
      p01 = f8x2((u16)xq1.x); p23 = f8x2((u16)(xq1.x>>16));
      p45 = f8x2((u16)xq1.y); p67 = f8x2((u16)(xq1.y>>16));
      a1.u4.x = pkbf(fmaxf(p01.x+blo(uv1.x),0.f), fmaxf(p01.y+bhi(uv1.x),0.f));
      a1.u4.y = pkbf(fmaxf(p23.x+blo(uv1.y),0.f), fmaxf(p23.y+bhi(uv1.y),0.f));
      a1.u4.z = pkbf(fmaxf(p45.x+blo(uv1.z),0.f), fmaxf(p45.y+bhi(uv1.z),0.f));
      a1.u4.w = pkbf(fmaxf(p67.x+blo(uv1.w),0.f), fmaxf(p67.y+bhi(uv1.w),0.f));
    }
    f32x4 acc[4];
#pragma unroll
    for(int nt=0; nt<4; ++nt){
      f32x4 c0 = { b2v[nt], b2v[nt], b2v[nt], b2v[nt] };
      c0 = __builtin_amdgcn_mfma_f32_16x16x32_bf16(a0.v, bf[nt][0], c0, 0, 0, 0);
      c0 = __builtin_amdgcn_mfma_f32_16x16x32_bf16(a1.v, bf[nt][1], c0, 0, 0, 0);
      acc[nt] = c0;
    }
    float s0=0.f, s1=0.f, s2=0.f, s3=0.f;
#pragma unroll
    for(int nt=0; nt<4; ++nt){
      s0 += fmaxf(acc[nt][0], 0.f) * a3v[nt];
      s1 += fmaxf(acc[nt][1], 0.f) * a3v[nt];
      s2 += fmaxf(acc[nt][2], 0.f) * a3v[nt];
      s3 += fmaxf(acc[nt][3], 0.f) * a3v[nt];
    }
#pragma unroll
    for(int mask=1; mask<16; mask<<=1){
      s0 += __shfl_xor(s0, mask);
      s1 += __shfl_xor(s1, mask);
      s2 += __shfl_xor(s2, mask);
      s3 += __shfl_xor(s3, mask);
    }
    if(lr == 0){
      int e0 = base + w*64 + t*16 + g*4;
      if(e0+0 < E_N) wlog[e0+0] = s0 + a3b0;
      if(e0+1 < E_N) wlog[e0+1] = s1 + a3b0;
      if(e0+2 < E_N) wlog[e0+2] = s2 + a3b0;
      if(e0+3 < E_N) wlog[e0+3] = s3 + a3b0;
    }
  };

  uint2 xA0 = *(const uint2*)(xa1p8 + (size_t)cin[0]*64 + g*8);
  uint2 xA1 = *(const uint2*)(xa1p8 + (size_t)cin[0]*64 + 32 + g*8);
  uint4 uA0 = userp[(size_t)uin[0]*8 + g];
  uint4 uA1 = userp[(size_t)uin[0]*8 + 4 + g];
  uint2 xB0 = *(const uint2*)(xa1p8 + (size_t)cin[1]*64 + g*8);
  uint2 xB1 = *(const uint2*)(xa1p8 + (size_t)cin[1]*64 + 32 + g*8);
  uint4 uB0 = userp[(size_t)uin[1]*8 + g];
  uint4 uB1 = userp[(size_t)uin[1]*8 + 4 + g];

  compute(xA0, xA1, uA0, uA1, 0);
  xA0 = *(const uint2*)(xa1p8 + (size_t)cin[2]*64 + g*8);
  xA1 = *(const uint2*)(xa1p8 + (size_t)cin[2]*64 + 32 + g*8);
  uA0 = userp[(size_t)uin[2]*8 + g];
  uA1 = userp[(size_t)uin[2]*8 + 4 + g];
  compute(xB0, xB1, uB0, uB1, 1);
  xB0 = *(const uint2*)(xa1p8 + (size_t)cin[3]*64 + g*8);
  xB1 = *(const uint2*)(xa1p8 + (size_t)cin[3]*64 + 32 + g*8);
  uB0 = userp[(size_t)uin[3]*8 + g];
  uB1 = userp[(size_t)uin[3]*8 + 4 + g];
  compute(xA0, xA1, uA0, uA1, 2);
  compute(xB0, xB1, uB0, uB1, 3);
}

// ---------------- fused softmax (no-max) + MFMA aggregate ----------------
__global__ __launch_bounds__(256) void k_aggf(const int* __restrict__ start,
                                              const unsigned* __restrict__ uc3,
                                              const float* __restrict__ wlog,
                                              const u16* __restrict__ Y,
                                              const float* __restrict__ wb,
                                              float* __restrict__ out){
  __shared__ uint4 Ysh[2][4][256];
  int w = threadIdx.x >> 6, l = threadIdx.x & 63;
  int lr = l & 15, g = l >> 4;
  int base = (blockIdx.x*4 + w) * 16;
  if(base >= U_N) return;
  int s0g = start[base];
  int s1g = start[base+16];
  unsigned ml = (unsigned)((base + lr) & 16383);
  int sA = s0g & ~31;
  int nch = (s1g - sA + 31) >> 5;
  const int kb = g*8;

  // single pass: p = exp(x) (logits are O(1); shift-free softmax is f32-safe)
  f32x4 acc[4];
#pragma unroll
  for(int nt=0; nt<4; ++nt) acc[nt] = f32x4{0.f,0.f,0.f,0.f};
  float ssum = 0.f;
  int buf = 0;
  if(nch > 0){
    int rowe = sA + (l>>1);
    int crow = (int)(uc3[rowe] & 0x3FFFFu);
    const uint4* yp = (const uint4*)Y + (size_t)crow*8 + (l&1)*4;
    uint4 y0=yp[0], y1=yp[1], y2=yp[2], y3=yp[3];
    uint4* dst = &Ysh[0][w][(l>>1)*8 + (l&1)*4];
    dst[0]=y0; dst[1]=y1; dst[2]=y2; dst[3]=y3;
  }
  for(int ch=0; ch<nch; ++ch){
    int e0 = sA + ch*32;
    uint4 n0, n1, n2, n3;
    bool hasNext = (ch+1 < nch);
    if(hasNext){
      int rowe = e0 + 32 + (l>>1);
      int crowN = (int)(uc3[rowe] & 0x3FFFFu);
      const uint4* yp = (const uint4*)Y + (size_t)crowN*8 + (l&1)*4;
      n0=yp[0]; n1=yp[1]; n2=yp[2]; n3=yp[3];
    }
    float4 wv0 = *(const float4*)(wlog + e0 + kb);
    float4 wv1 = *(const float4*)(wlog + e0 + kb + 4);
    uint4 v0 = *(const uint4*)(uc3 + e0 + kb);
    uint4 v1 = *(const uint4*)(uc3 + e0 + kb + 4);
    bf16x8 af;
    {
      bool mt; float e;
      mt = ((v0.x>>18)==ml); e = __expf(mt?wv0.x:-1e30f); ssum += e; af[0] = mt?(short)f2b(e):(short)0;
      mt = ((v0.y>>18)==ml); e = __expf(mt?wv0.y:-1e30f); ssum += e; af[1] = mt?(short)f2b(e):(short)0;
      mt = ((v0.z>>18)==ml); e = __expf(mt?wv0.z:-1e30f); ssum += e; af[2] = mt?(short)f2b(e):(short)0;
      mt = ((v0.w>>18)==ml); e = __expf(mt?wv0.w:-1e30f); ssum += e; af[3] = mt?(short)f2b(e):(short)0;
      mt = ((v1.x>>18)==ml); e = __expf(mt?wv1.x:-1e30f); ssum += e; af[4] = mt?(short)f2b(e):(short)0;
      mt = ((v1.y>>18)==ml); e = __expf(mt?wv1.y:-1e30f); ssum += e; af[5] = mt?(short)f2b(e):(short)0;
      mt = ((v1.z>>18)==ml); e = __expf(mt?wv1.z:-1e30f); ssum += e; af[6] = mt?(short)f2b(e):(short)0;
      mt = ((v1.w>>18)==ml); e = __expf(mt?wv1.w:-1e30f); ssum += e; af[7] = mt?(short)f2b(e):(short)0;
    }
    u16* Ysh16 = (u16*)&Ysh[buf][w][0];
    bf16x8 b0, b1, b2, b3;
#pragma unroll
    for(int j=0; j<8; ++j){
      int r = (kb + j)*64 + lr;
      b0[j] = (short)Ysh16[r];
      b1[j] = (short)Ysh16[r+16];
      b2[j] = (short)Ysh16[r+32];
      b3[j] = (short)Ysh16[r+48];
    }
    acc[0] = __builtin_amdgcn_mfma_f32_16x16x32_bf16(af, b0, acc[0], 0, 0, 0);
    acc[1] = __builtin_amdgcn_mfma_f32_16x16x32_bf16(af, b1, acc[1], 0, 0, 0);
    acc[2] = __builtin_amdgcn_mfma_f32_16x16x32_bf16(af, b2, acc[2], 0, 0, 0);
    acc[3] = __builtin_amdgcn_mfma_f32_16x16x32_bf16(af, b3, acc[3], 0, 0, 0);
    if(hasNext){
      uint4* dst = &Ysh[buf^1][w][(l>>1)*8 + (l&1)*4];
      dst[0]=n0; dst[1]=n1; dst[2]=n2; dst[3]=n3;
    }
    buf ^= 1;
  }
  ssum += __shfl_xor(ssum, 16);
  ssum += __shfl_xor(ssum, 32);
  float inv = (ssum > 0.f) ? (1.f/ssum) : 0.f;
  float wbv[4];
#pragma unroll
  for(int nt=0; nt<4; ++nt) wbv[nt] = wb[nt*16 + lr];
#pragma unroll
  for(int reg=0; reg<4; ++reg){
    float sc = __shfl(inv, g*4 + reg);
    int u = base + g*4 + reg;
#pragma unroll
    for(int nt=0; nt<4; ++nt)
      out[(size_t)u*64 + nt*16 + lr] = acc[nt][reg]*sc + wbv[nt];
  }
}

extern "C" void kernel_launch(void* const* d_in, const int* in_sizes, int n_in,
                              void* d_out, int out_size, void* d_ws, size_t ws_size,
                              hipStream_t stream){
  (void)in_sizes; (void)n_in; (void)out_size; (void)ws_size;
  const float4* user_feat  = (const float4*)d_in[0];
  const float4* item_feat  = (const float4*)d_in[1];
  const float*  rating_feat= (const float*)d_in[2];
  const int*    rows       = (const int*)d_in[3];
  const int*    cols       = (const int*)d_in[4];
  const int*    rats       = (const int*)d_in[5];
  const float* gv_w1 = (const float*)d_in[6];
  const float* gv_b1 = (const float*)d_in[7];
  const float* gv_w2 = (const float*)d_in[8];
  const float* gv_b2 = (const float*)d_in[9];
  const float* att_w1= (const float*)d_in[10];
  const float* att_b1= (const float*)d_in[11];
  const float* att_w2= (const float*)d_in[12];
  const float* att_b2= (const float*)d_in[13];
  const float* att_w3= (const float*)d_in[14];
  const float* att_b3= (const float*)d_in[15];
  const float* w_w   = (const float*)d_in[16];
  const float* w_b   = (const float*)d_in[17];
  float* out = (float*)d_out;

  char* ws = (char*)d_ws; size_t off = 0;
  auto take = [&](size_t b)->char*{ char* p = ws + off; off = (off + b + 255) & ~(size_t)255; return p; };
  bf16_t*   item_part  = (bf16_t*)take((size_t)I_N*64*2);
  bf16_t*   user_part  = (bf16_t*)take((size_t)U_N*64*2);
  float*    rating_part= (float*) take((size_t)R_N*64*4);
  bf16_t*   y_t        = (bf16_t*)take((size_t)C_N*64*2);
  u8*       xa1_8      = (u8*)    take((size_t)C_N*64);
  float*    wlog_s     = (float*) take((size_t)E_N*4);
  unsigned* uc3        = (unsigned*)take((size_t)E_N*4);
  unsigned* uc2        = (unsigned*)take((size_t)E_N*4);
  int*      hist_g     = (int*)   take((size_t)NBLK_E*NBUCKC*4);
  int*      boff_g     = (int*)   take((size_t)NBLK_E*NBUCKC*4);
  int*      qtot       = (int*)   take((size_t)256*4);
  int*      qbase      = (int*)   take((size_t)256*4);
  int*      blockq     = (int*)   take((size_t)NBLK_E*4);
  int*      start      = (int*)   take((size_t)(NBUCKC*512+64)*4);
  u16*      w1t        = (u16*)   take((size_t)4096*2);
  u16*      u1t        = (u16*)   take((size_t)4096*2);
  u16*      w2t        = (u16*)   take((size_t)4096*2);
  u16*      a1t        = (u16*)   take((size_t)4096*2);
  u16*      a2t        = (u16*)   take((size_t)4096*2);
  u16*      wwt        = (u16*)   take((size_t)4096*2);

  // CSR build
  k_histQ <<<NBLK_E, 256, 0, stream>>>(cols, hist_g);
  k_scanQ <<<NBUCKC, 256, 0, stream>>>(hist_g, boff_g, qtot);
  k_scanT <<<1, 256, 0, stream>>>(qtot, qbase);
  k_blockq<<<(NBLK_E+255)/256, 256, 0, stream>>>(qbase, blockq);
  k_place2<<<NBLK_E, 256, 0, stream>>>(rows, cols, rats, boff_g, qbase, uc2);
  k_fine  <<<NBUCKC, 256, 0, stream>>>(uc2, qbase, uc3, start);
  // weights + tiny GEMV
  k_ratpart <<<1, 320, 0, stream>>>(rating_feat, gv_w1, gv_b1, rating_part);
  k_prepw6  <<<96, 256, 0, stream>>>(gv_w1, att_w1, gv_w2, att_w2, w_w, w1t, u1t, w2t, a1t, a2t, wwt);
  // dense precompute (MFMA)
  k_rowgemm<false><<<(I_N+255)/256, 256, 0, stream>>>(item_feat, (const uint4*)w1t, nullptr,
                                                      (uint4*)item_part, I_N);
  k_rowgemm<true> <<<(U_N+255)/256, 256, 0, stream>>>(user_feat, (const uint4*)u1t, att_b1,
                                                      (uint4*)user_part, U_N);
  k_combo_mfma<<<NBLK_C, 256, 0, stream>>>((const uint4*)item_part, (const float4*)rating_part,
                                           (const uint4*)w2t, (const uint4*)a1t, (const uint4*)wwt, gv_b2,
                                           (uint4*)y_t, xa1_8);
  // per-edge logits
  k_edge_mfma<<<NBLK_E, 256, 0, stream>>>(uc3, qbase, blockq, xa1_8, (const uint4*)user_part,
                                          w2t, att_b2, att_w3, att_b3, wlog_s);
  // fused softmax + aggregate + projection
  k_aggf <<<(U_N/64)+1, 256, 0, stream>>>(start, uc3, wlog_s, (const u16*)y_t, w_b, out);
}